// Round 1
// baseline (529.136 us; speedup 1.0000x reference)
//
#include <hip/hip_runtime.h>
#include <hip/hip_bf16.h>

#define EPS_F 1e-5f

// ---------------- sb = latent @ lin^T (for both cbn layers) ----------------
__global__ void __launch_bounds__(256) sb_kernel(
    const float* __restrict__ latent,
    const float* __restrict__ lin_in,
    const float* __restrict__ lin_out,
    float* __restrict__ sb_in,
    float* __restrict__ sb_out) {
  int idx = blockIdx.x * 256 + threadIdx.x;   // 0..4095
  int which = idx >> 11;                      // 0: lin_in, 1: lin_out
  int r = idx & 2047;
  int b = r >> 9;                             // 0..3
  int k = r & 511;                            // 0..511
  const float* lin = which ? lin_out : lin_in;
  const float* lv = latent + b * 256;
  const float* lr = lin + k * 256;
  float acc = 0.f;
#pragma unroll 8
  for (int l = 0; l < 256; ++l) acc += lv[l] * lr[l];
  (which ? sb_out : sb_in)[b * 512 + k] = acc;
}

// ---------------- generic conv1x1 (channel matmul) ----------------
// Y[b,oc,p] = post( sum_c W[oc,c] * X[b,c,p] )
// MODE bits: 1 = bn affine (per oc), 2 = cbn (per b,oc from sb),
//            4 = add addbuf, 8 = prelu(alpha)
// grid: (P/128, Cout/128, B), block 256. Requires P%128==0, Cin%16==0, Cout%128==0.
template <int MODE>
__global__ void __launch_bounds__(256) conv1x1_kernel(
    const float* __restrict__ X, const float* __restrict__ Wm,
    float* __restrict__ Y, int Cin, int Cout, int P,
    const float* __restrict__ bn, const float* __restrict__ sb,
    const float* __restrict__ alpha, const float* __restrict__ addbuf) {
  const int tid = threadIdx.x;
  const int tx = tid & 15;   // pixel octet
  const int ty = tid >> 4;   // oc octet
  const int p0 = blockIdx.x * 128;
  const int o0 = blockIdx.y * 128;
  const int b  = blockIdx.z;

  __shared__ float Xs[16][132];  // [k][pixel], padded
  __shared__ float Wt[16][132];  // [k][oc],    padded (transposed W)

  float acc[8][8] = {};
  const float* Xb = X + (size_t)b * Cin * P;

  for (int k0 = 0; k0 < Cin; k0 += 16) {
#pragma unroll
    for (int r = 0; r < 8; ++r) {
      int e = tid + r * 256;
      int c = e >> 7, p = e & 127;
      Xs[c][p] = Xb[(size_t)(k0 + c) * P + p0 + p];
    }
#pragma unroll
    for (int r = 0; r < 8; ++r) {
      int e = tid + r * 256;
      int o = e >> 4, c = e & 15;
      Wt[c][o] = Wm[(size_t)(o0 + o) * Cin + k0 + c];
    }
    __syncthreads();
#pragma unroll
    for (int kk = 0; kk < 16; ++kk) {
      float4 w0 = *(const float4*)&Wt[kk][ty * 8];
      float4 w1 = *(const float4*)&Wt[kk][ty * 8 + 4];
      float4 x0 = *(const float4*)&Xs[kk][tx * 8];
      float4 x1 = *(const float4*)&Xs[kk][tx * 8 + 4];
      float wa[8] = {w0.x, w0.y, w0.z, w0.w, w1.x, w1.y, w1.z, w1.w};
      float xa[8] = {x0.x, x0.y, x0.z, x0.w, x1.x, x1.y, x1.z, x1.w};
#pragma unroll
      for (int i = 0; i < 8; ++i)
#pragma unroll
        for (int j = 0; j < 8; ++j) acc[i][j] += wa[i] * xa[j];
    }
    __syncthreads();
  }

#pragma unroll
  for (int i = 0; i < 8; ++i) {
    int oc = o0 + ty * 8 + i;
    float scale = 1.f, shift = 0.f;
    if (MODE & 1) {
      float sc = bn[oc] * rsqrtf(bn[3 * Cout + oc] + EPS_F);
      scale = sc;
      shift = bn[Cout + oc] - bn[2 * Cout + oc] * sc;
    }
    if (MODE & 2) {
      float s  = sb[b * 2 * Cout + oc];
      float bb = sb[b * 2 * Cout + Cout + oc];
      scale *= s;
      shift = shift * s + bb;
    }
    float a = (MODE & 8) ? *alpha : 0.f;
    size_t row = ((size_t)b * Cout + oc) * P + p0;
#pragma unroll
    for (int j = 0; j < 8; ++j) {
      int p = tx * 8 + j;
      float v = acc[i][j] * scale + shift;
      if (MODE & 4) v += addbuf[row + p];
      if (MODE & 8) v = v > 0.f ? v : a * v;
      Y[row + p] = v;
    }
  }
}

// ---------------- axial attention, one block per (bd, group) ----------------
// qkv: (B,512,64,64) fp32 (bn_qkv already applied as affine by the conv).
// DIM==0: attention along H at fixed w=d1 ; DIM==1: along W at fixed h=d1.
// out: (B,256,64,64)
template <int DIM>
__global__ void __launch_bounds__(256) axial_attn_kernel(
    const float* __restrict__ qkv, const float* __restrict__ rel,
    const float* __restrict__ bn_sim, const float* __restrict__ bn_out,
    float* __restrict__ out) {
  const int tid = threadIdx.x;
  const int bd = blockIdx.x;  // 0..255
  const int g  = blockIdx.y;  // 0..15
  const int b  = bd >> 6;
  const int d1 = bd & 63;

  __shared__ float rel_s[32][128];   // rel (32 x 127), padded
  __shared__ float qs[8][64];
  __shared__ float ks[8][64];
  __shared__ float vs[16][64];
  __shared__ float bufA[64][68];     // q_emb -> sim (stride 68: 16B-aligned rows, bank-spread)
  __shared__ float bufB[64][68];     // k_emb

  for (int e = tid; e < 32 * 127; e += 256)
    rel_s[e / 127][e % 127] = rel[e];

  for (int e = tid; e < 2048; e += 256) {
    int c = e >> 6, i = e & 63;
    int ch = g * 32 + c;
    size_t idx = (DIM == 0)
        ? (((size_t)b * 512 + ch) * 64 + i) * 64 + d1
        : (((size_t)b * 512 + ch) * 64 + d1) * 64 + i;
    float v = qkv[idx];
    if (c < 8)       qs[c][i] = v;
    else if (c < 16) ks[c - 8][i] = v;
    else             vs[c - 16][i] = v;
  }
  __syncthreads();

  // q_emb[i,j] = sum_c q[c,i]*rel[c, i-j+63] ; k_emb likewise with rel rows 8..15
#pragma unroll 4
  for (int n = 0; n < 16; ++n) {
    int e = tid + n * 256;
    int i = e >> 6, j = e & 63;
    int d = i - j + 63;
    float a = 0.f, bb = 0.f;
#pragma unroll
    for (int c = 0; c < 8; ++c) {
      a  += qs[c][i] * rel_s[c][d];
      bb += ks[c][i] * rel_s[8 + c][d];
    }
    bufA[i][j] = a;
    bufB[i][j] = bb;
  }
  __syncthreads();

  // BN(sim) folded: sim = s_qk*qk + s_qe*q_emb + s_ke*k_emb + sh   (channels g, 16+g, 32+g)
  float s_qk = bn_sim[g]      * rsqrtf(bn_sim[144 + g] + EPS_F);
  float s_qe = bn_sim[16 + g] * rsqrtf(bn_sim[160 + g] + EPS_F);
  float s_ke = bn_sim[32 + g] * rsqrtf(bn_sim[176 + g] + EPS_F);
  float sh   = (bn_sim[48 + g]  - bn_sim[96 + g]  * s_qk)
             + (bn_sim[64 + g]  - bn_sim[112 + g] * s_qe)
             + (bn_sim[80 + g]  - bn_sim[128 + g] * s_ke);

  // qk[i,j] = sum_k q_emb[k,i] * k_emb[k,j]  (contraction over FIRST axis)
  const int ti0 = (tid >> 4) * 4;
  const int tj0 = (tid & 15) * 4;
  float accq[4][4] = {};
  for (int k2 = 0; k2 < 64; ++k2) {
    float4 av = *(const float4*)&bufA[k2][ti0];
    float4 bv = *(const float4*)&bufB[k2][tj0];
    float aa[4] = {av.x, av.y, av.z, av.w};
    float bb[4] = {bv.x, bv.y, bv.z, bv.w};
#pragma unroll
    for (int ii = 0; ii < 4; ++ii)
#pragma unroll
      for (int jj = 0; jj < 4; ++jj) accq[ii][jj] += aa[ii] * bb[jj];
  }
  float simr[4][4];
#pragma unroll
  for (int ii = 0; ii < 4; ++ii)
#pragma unroll
    for (int jj = 0; jj < 4; ++jj)
      simr[ii][jj] = accq[ii][jj] * s_qk
                   + bufA[ti0 + ii][tj0 + jj] * s_qe
                   + bufB[ti0 + ii][tj0 + jj] * s_ke + sh;
  __syncthreads();
#pragma unroll
  for (int ii = 0; ii < 4; ++ii)
    *(float4*)&bufA[ti0 + ii][tj0] =
        make_float4(simr[ii][0], simr[ii][1], simr[ii][2], simr[ii][3]);
  __syncthreads();

  // softmax over j, 4 lanes per row
  {
    int r = tid >> 2, l = tid & 3;
    float mx = -3.0e38f;
#pragma unroll
    for (int m = 0; m < 16; ++m) mx = fmaxf(mx, bufA[r][l + 4 * m]);
    mx = fmaxf(mx, __shfl_xor(mx, 1));
    mx = fmaxf(mx, __shfl_xor(mx, 2));
    float ev[16];
    float sum = 0.f;
#pragma unroll
    for (int m = 0; m < 16; ++m) {
      ev[m] = __expf(bufA[r][l + 4 * m] - mx);
      sum += ev[m];
    }
    sum += __shfl_xor(sum, 1);
    sum += __shfl_xor(sum, 2);
    float inv = 1.f / sum;
#pragma unroll
    for (int m = 0; m < 16; ++m) bufA[r][l + 4 * m] = ev[m] * inv;
  }
  __syncthreads();

  // att[c,i] = sum_j sim[i,j]*v[c,j] ; att_e[c,i] = sum_j sim[i,j]*rel[16+c, i-j+63]
  // out_ch oc = g*16+c ; result = BN_{2oc}(att) + BN_{2oc+1}(att_e)
#pragma unroll
  for (int n = 0; n < 4; ++n) {
    int o = tid + n * 256;
    int c = o >> 6, i = o & 63;
    float att = 0.f, atte = 0.f;
#pragma unroll 8
    for (int j = 0; j < 64; ++j) {
      float s = bufA[i][j];
      att  += s * vs[c][j];
      atte += s * rel_s[16 + c][i - j + 63];
    }
    int oc = g * 16 + c;
    int c0 = 2 * oc, c1 = 2 * oc + 1;
    float sc0 = bn_out[c0] * rsqrtf(bn_out[1536 + c0] + EPS_F);
    float sh0 = bn_out[512 + c0] - bn_out[1024 + c0] * sc0;
    float sc1 = bn_out[c1] * rsqrtf(bn_out[1536 + c1] + EPS_F);
    float sh1 = bn_out[512 + c1] - bn_out[1024 + c1] * sc1;
    float v = att * sc0 + sh0 + atte * sc1 + sh1;
    size_t base = ((size_t)b * 256 + oc) * 4096;
    if (DIM == 0) out[base + (size_t)i * 64 + d1] = v;
    else          out[base + (size_t)d1 * 64 + i] = v;
  }
}

// ---------------- 2x2 mean pool: (N,64,64) -> (N,32,32) over trailing dims ----------------
__global__ void __launch_bounds__(256) pool_kernel(
    const float* __restrict__ in, float* __restrict__ out, int total) {
  int idx = blockIdx.x * 256 + threadIdx.x;
  if (idx >= total) return;
  int j = idx & 31, i = (idx >> 5) & 31, bc = idx >> 10;
  const float* p = in + (size_t)bc * 4096 + i * 128 + j * 2;
  out[idx] = 0.25f * (p[0] + p[1] + p[64] + p[65]);
}

extern "C" void kernel_launch(void* const* d_in, const int* in_sizes, int n_in,
                              void* d_out, int out_size, void* d_ws, size_t ws_size,
                              hipStream_t stream) {
  const float* x         = (const float*)d_in[0];
  const float* latent    = (const float*)d_in[1];
  const float* w_in      = (const float*)d_in[2];
  const float* bn_in     = (const float*)d_in[3];
  const float* lin_in    = (const float*)d_in[4];
  const float* alpha_in  = (const float*)d_in[5];
  const float* a0_wqkv   = (const float*)d_in[6];
  const float* a0_bn_qkv = (const float*)d_in[7];
  const float* a0_bn_sim = (const float*)d_in[8];
  const float* a0_bn_out = (const float*)d_in[9];
  const float* a0_rel    = (const float*)d_in[10];
  const float* a1_wqkv   = (const float*)d_in[11];
  const float* a1_bn_qkv = (const float*)d_in[12];
  const float* a1_bn_sim = (const float*)d_in[13];
  const float* a1_bn_out = (const float*)d_in[14];
  const float* a1_rel    = (const float*)d_in[15];
  const float* w_out     = (const float*)d_in[16];
  const float* bn_outp   = (const float*)d_in[17];
  const float* lin_out   = (const float*)d_in[18];
  const float* w_res     = (const float*)d_in[19];
  const float* alpha_fin = (const float*)d_in[20];

  float* ws     = (float*)d_ws;
  float* sb_in  = ws;                  // 2048 f
  float* sb_out = ws + 2048;           // 2048 f
  float* t0     = ws + 4096;           // 4,194,304 f  (B,256,64,64) - reused 3x
  float* qkvb   = t0 + 4194304;        // 8,388,608 f  (B,512,64,64)
  float* pool_o = qkvb + 8388608;      // 1,048,576 f
  float* pool_x = pool_o + 1048576;    //   524,288 f
  float* resb   = pool_x + 524288;     // 1,048,576 f
  // total ~61 MB of d_ws

  // sb for both cbn layers
  sb_kernel<<<16, 256, 0, stream>>>(latent, lin_in, lin_out, sb_in, sb_out);

  // conv_in + cbn + prelu -> t0
  conv1x1_kernel<11><<<dim3(32, 2, 4), 256, 0, stream>>>(
      x, w_in, t0, 128, 256, 4096, bn_in, sb_in, alpha_in, nullptr);

  // axial 0 (over H)
  conv1x1_kernel<1><<<dim3(32, 4, 4), 256, 0, stream>>>(
      t0, a0_wqkv, qkvb, 256, 512, 4096, a0_bn_qkv, nullptr, nullptr, nullptr);
  axial_attn_kernel<0><<<dim3(256, 16), 256, 0, stream>>>(
      qkvb, a0_rel, a0_bn_sim, a0_bn_out, t0);

  // axial 1 (over W)
  conv1x1_kernel<1><<<dim3(32, 4, 4), 256, 0, stream>>>(
      t0, a1_wqkv, qkvb, 256, 512, 4096, a1_bn_qkv, nullptr, nullptr, nullptr);
  axial_attn_kernel<1><<<dim3(256, 16), 256, 0, stream>>>(
      qkvb, a1_rel, a1_bn_sim, a1_bn_out, t0);

  // pools (pool is linear: pool(conv(w_res,x)) == conv(w_res, pool(x)))
  pool_kernel<<<4096, 256, 0, stream>>>(t0, pool_o, 1048576);
  pool_kernel<<<2048, 256, 0, stream>>>(x, pool_x, 524288);

  // residual conv (plain)
  conv1x1_kernel<0><<<dim3(8, 2, 4), 256, 0, stream>>>(
      pool_x, w_res, resb, 128, 256, 1024, nullptr, nullptr, nullptr, nullptr);

  // final conv + cbn + add res + prelu -> d_out
  conv1x1_kernel<15><<<dim3(8, 2, 4), 256, 0, stream>>>(
      pool_o, w_out, (float*)d_out, 256, 256, 1024, bn_outp, sb_out, alpha_fin, resb);
}

// Round 2
// 513.088 us; speedup vs baseline: 1.0313x; 1.0313x over previous
//
#include <hip/hip_runtime.h>
#include <hip/hip_bf16.h>

#define EPS_F 1e-5f

// ---------------- sb = latent @ lin^T (for both cbn layers) ----------------
__global__ void __launch_bounds__(256) sb_kernel(
    const float* __restrict__ latent,
    const float* __restrict__ lin_in,
    const float* __restrict__ lin_out,
    float* __restrict__ sb_in,
    float* __restrict__ sb_out) {
  int idx = blockIdx.x * 256 + threadIdx.x;   // 0..4095
  int which = idx >> 11;                      // 0: lin_in, 1: lin_out
  int r = idx & 2047;
  int b = r >> 9;                             // 0..3
  int k = r & 511;                            // 0..511
  const float* lin = which ? lin_out : lin_in;
  const float* lv = latent + b * 256;
  const float* lr = lin + k * 256;
  float acc = 0.f;
#pragma unroll 8
  for (int l = 0; l < 256; ++l) acc += lv[l] * lr[l];
  (which ? sb_out : sb_in)[b * 512 + k] = acc;
}

// ---------------- generic conv1x1 (channel matmul) ----------------
// Y[b,oc,p] = post( sum_c W[oc,c] * X[b,c,p] )
// MODE bits: 1 = bn affine (per oc), 2 = cbn (per b,oc from sb),
//            4 = add addbuf, 8 = prelu(alpha)
template <int MODE>
__global__ void __launch_bounds__(256) conv1x1_kernel(
    const float* __restrict__ X, const float* __restrict__ Wm,
    float* __restrict__ Y, int Cin, int Cout, int P,
    const float* __restrict__ bn, const float* __restrict__ sb,
    const float* __restrict__ alpha, const float* __restrict__ addbuf) {
  const int tid = threadIdx.x;
  const int tx = tid & 15;   // pixel octet
  const int ty = tid >> 4;   // oc octet
  const int p0 = blockIdx.x * 128;
  const int o0 = blockIdx.y * 128;
  const int b  = blockIdx.z;

  __shared__ float Xs[16][132];
  __shared__ float Wt[16][132];

  float acc[8][8] = {};
  const float* Xb = X + (size_t)b * Cin * P;

  for (int k0 = 0; k0 < Cin; k0 += 16) {
#pragma unroll
    for (int r = 0; r < 8; ++r) {
      int e = tid + r * 256;
      int c = e >> 7, p = e & 127;
      Xs[c][p] = Xb[(size_t)(k0 + c) * P + p0 + p];
    }
#pragma unroll
    for (int r = 0; r < 8; ++r) {
      int e = tid + r * 256;
      int o = e >> 4, c = e & 15;
      Wt[c][o] = Wm[(size_t)(o0 + o) * Cin + k0 + c];
    }
    __syncthreads();
#pragma unroll
    for (int kk = 0; kk < 16; ++kk) {
      float4 w0 = *(const float4*)&Wt[kk][ty * 8];
      float4 w1 = *(const float4*)&Wt[kk][ty * 8 + 4];
      float4 x0 = *(const float4*)&Xs[kk][tx * 8];
      float4 x1 = *(const float4*)&Xs[kk][tx * 8 + 4];
      float wa[8] = {w0.x, w0.y, w0.z, w0.w, w1.x, w1.y, w1.z, w1.w};
      float xa[8] = {x0.x, x0.y, x0.z, x0.w, x1.x, x1.y, x1.z, x1.w};
#pragma unroll
      for (int i = 0; i < 8; ++i)
#pragma unroll
        for (int j = 0; j < 8; ++j) acc[i][j] += wa[i] * xa[j];
    }
    __syncthreads();
  }

#pragma unroll
  for (int i = 0; i < 8; ++i) {
    int oc = o0 + ty * 8 + i;
    float scale = 1.f, shift = 0.f;
    if (MODE & 1) {
      float sc = bn[oc] * rsqrtf(bn[3 * Cout + oc] + EPS_F);
      scale = sc;
      shift = bn[Cout + oc] - bn[2 * Cout + oc] * sc;
    }
    if (MODE & 2) {
      float s  = sb[b * 2 * Cout + oc];
      float bb = sb[b * 2 * Cout + Cout + oc];
      scale *= s;
      shift = shift * s + bb;
    }
    float a = (MODE & 8) ? *alpha : 0.f;
    size_t row = ((size_t)b * Cout + oc) * P + p0;
#pragma unroll
    for (int j = 0; j < 8; ++j) {
      int p = tx * 8 + j;
      float v = acc[i][j] * scale + shift;
      if (MODE & 4) v += addbuf[row + p];
      if (MODE & 8) v = v > 0.f ? v : a * v;
      Y[row + p] = v;
    }
  }
}

// ---------------- axial attention, one block per (bd, group) ----------------
// Input qkv layout: (b, ch, pA, pB) with pA = attended dim (i), pB = fixed (d1).
//   axial0: input (b,c,h,w), i=h, d1=w.  axial1: input (b,c,w,h), i=w, d1=h.
// Output written TRANSPOSED relative to input: out[((b*256+oc)*64 + d1)*64 + i]
//   axial0 -> (b,c,w,h) ; axial1 -> (b,c,h,w) (back to standard). Contiguous over i.
__global__ void __launch_bounds__(256) axial_attn_kernel(
    const float* __restrict__ qkv, const float* __restrict__ rel,
    const float* __restrict__ bn_sim, const float* __restrict__ bn_out,
    float* __restrict__ out) {
  const int tid = threadIdx.x;
  // bijective XCD swizzle: 4096 blocks, 8 XCDs, 512 consecutive work items/XCD
  int lin = blockIdx.x;
  int w = ((lin & 7) << 9) + (lin >> 3);
  const int g  = w >> 8;
  const int bd = w & 255;
  const int b  = bd >> 6;
  const int d1 = bd & 63;

  __shared__ float qk_s[16][64];   // [c][i]  c:0-7 q, 8-15 k        (4.0 KB)
  __shared__ float vst[64][20];    // [j][c]  v transposed, pad 20   (5.0 KB)
  __shared__ float relT[127][18];  // [d][c]  transposed rel, reused (8.9 KB)
  __shared__ float bufA[64][68];   // q_emb -> sim                   (17 KB)
  __shared__ float bufB[64][68];   // k_emb -> out staging           (17 KB)
  // total 51.9 KB -> 3 blocks/CU

  // ---- P0: load qkv column + rel rows 0..15 (transposed) ----
  {
    const float* src = qkv + (((size_t)b * 512 + g * 32) * 64) * 64 + d1;
#pragma unroll
    for (int n = 0; n < 8; ++n) {
      int e = tid + n * 256;
      int c = e >> 6, i = e & 63;
      float v = src[(size_t)c * 4096 + i * 64];
      if (c < 16) qk_s[c][i] = v;
      else        vst[i][c - 16] = v;
    }
    for (int e = tid; e < 2032; e += 256) {
      int c = e / 127, d = e - c * 127;
      relT[d][c] = rel[e];
    }
  }
  __syncthreads();

  // ---- P1: q_emb / k_emb -> bufA/bufB ----
#pragma unroll
  for (int n = 0; n < 4; ++n) {
    int e = tid + n * 256;
    int i = e >> 4, j0 = (e & 15) << 2;
    float qv[8], kv[8];
#pragma unroll
    for (int c = 0; c < 8; ++c) {
      qv[c] = qk_s[c][i];
      kv[c] = qk_s[8 + c][i];
    }
    float qa[4], ka[4];
#pragma unroll
    for (int jj = 0; jj < 4; ++jj) {
      int d = i - (j0 + jj) + 63;
      float a = 0.f, kk2 = 0.f;
#pragma unroll
      for (int c = 0; c < 8; c += 2) {
        float2 rq = *(const float2*)&relT[d][c];
        a   += qv[c] * rq.x + qv[c + 1] * rq.y;
        float2 rk = *(const float2*)&relT[d][8 + c];
        kk2 += kv[c] * rk.x + kv[c + 1] * rk.y;
      }
      qa[jj] = a; ka[jj] = kk2;
    }
    *(float4*)&bufA[i][j0] = make_float4(qa[0], qa[1], qa[2], qa[3]);
    *(float4*)&bufB[i][j0] = make_float4(ka[0], ka[1], ka[2], ka[3]);
  }
  __syncthreads();

  // ---- P2: qk contraction (+ overlap: load rel rows 16..31 transposed) ----
  const int ti0 = (tid >> 4) << 2;
  const int tj0 = (tid & 15) << 2;
  float accq[4][4] = {};
#pragma unroll 8
  for (int k2 = 0; k2 < 64; ++k2) {
    float4 av = *(const float4*)&bufA[k2][ti0];
    float4 bv = *(const float4*)&bufB[k2][tj0];
    float aa[4] = {av.x, av.y, av.z, av.w};
    float bb[4] = {bv.x, bv.y, bv.z, bv.w};
#pragma unroll
    for (int ii = 0; ii < 4; ++ii)
#pragma unroll
      for (int jj = 0; jj < 4; ++jj) accq[ii][jj] += aa[ii] * bb[jj];
  }
  // overwrite relT with ve rows (emb reads finished at P1 barrier)
  for (int e = tid; e < 2032; e += 256) {
    int c = e / 127, d = e - c * 127;
    relT[d][c] = rel[2032 + e];
  }

  // folded BN(sim): sim = s_qk*qk + s_qe*q_emb + s_ke*k_emb + sh
  float s_qk = bn_sim[g]      * rsqrtf(bn_sim[144 + g] + EPS_F);
  float s_qe = bn_sim[16 + g] * rsqrtf(bn_sim[160 + g] + EPS_F);
  float s_ke = bn_sim[32 + g] * rsqrtf(bn_sim[176 + g] + EPS_F);
  float sh   = (bn_sim[48 + g] - bn_sim[96 + g]  * s_qk)
             + (bn_sim[64 + g] - bn_sim[112 + g] * s_qe)
             + (bn_sim[80 + g] - bn_sim[128 + g] * s_ke);

  float simr[4][4];
#pragma unroll
  for (int ii = 0; ii < 4; ++ii) {
    float4 ea = *(const float4*)&bufA[ti0 + ii][tj0];
    float4 eb = *(const float4*)&bufB[ti0 + ii][tj0];
    float eav[4] = {ea.x, ea.y, ea.z, ea.w};
    float ebv[4] = {eb.x, eb.y, eb.z, eb.w};
#pragma unroll
    for (int jj = 0; jj < 4; ++jj)
      simr[ii][jj] = accq[ii][jj] * s_qk + eav[jj] * s_qe + ebv[jj] * s_ke + sh;
  }
  __syncthreads();
#pragma unroll
  for (int ii = 0; ii < 4; ++ii)
    *(float4*)&bufA[ti0 + ii][tj0] =
        make_float4(simr[ii][0], simr[ii][1], simr[ii][2], simr[ii][3]);
  __syncthreads();

  // ---- P4: softmax, row r per 4-lane group; probs stay in registers ----
  const int r = tid >> 2, l = tid & 3;
  float p[16];
  float mx = -3.0e38f;
#pragma unroll
  for (int m = 0; m < 16; ++m) {
    p[m] = bufA[r][l + 4 * m];
    mx = fmaxf(mx, p[m]);
  }
  mx = fmaxf(mx, __shfl_xor(mx, 1));
  mx = fmaxf(mx, __shfl_xor(mx, 2));
  float sum = 0.f;
#pragma unroll
  for (int m = 0; m < 16; ++m) {
    p[m] = __expf(p[m] - mx);
    sum += p[m];
  }
  sum += __shfl_xor(sum, 1);
  sum += __shfl_xor(sum, 2);
  float inv = 1.f / sum;
#pragma unroll
  for (int m = 0; m < 16; ++m) p[m] *= inv;

  // ---- P5: att / att_e from registers ----
  float att[16] = {}, atte[16] = {};
#pragma unroll
  for (int m = 0; m < 16; ++m) {
    int j = l + 4 * m;
    int d = r - j + 63;
    float pv = p[m];
    float4 v0 = *(const float4*)&vst[j][0];
    float4 v1 = *(const float4*)&vst[j][4];
    float4 v2 = *(const float4*)&vst[j][8];
    float4 v3 = *(const float4*)&vst[j][12];
    att[0]  += pv * v0.x;  att[1]  += pv * v0.y;  att[2]  += pv * v0.z;  att[3]  += pv * v0.w;
    att[4]  += pv * v1.x;  att[5]  += pv * v1.y;  att[6]  += pv * v1.z;  att[7]  += pv * v1.w;
    att[8]  += pv * v2.x;  att[9]  += pv * v2.y;  att[10] += pv * v2.z;  att[11] += pv * v2.w;
    att[12] += pv * v3.x;  att[13] += pv * v3.y;  att[14] += pv * v3.z;  att[15] += pv * v3.w;
#pragma unroll
    for (int c = 0; c < 16; c += 2) {
      float2 rv = *(const float2*)&relT[d][c];
      atte[c]     += pv * rv.x;
      atte[c + 1] += pv * rv.y;
    }
  }

  // fold bn_out, reduce over the 4 lanes, stage into bufB rows 0..15
  float vout[16];
#pragma unroll
  for (int c = 0; c < 16; ++c) {
    int c0 = 2 * (g * 16 + c), c1 = c0 + 1;
    float sc0 = bn_out[c0] * rsqrtf(bn_out[1536 + c0] + EPS_F);
    float sc1 = bn_out[c1] * rsqrtf(bn_out[1536 + c1] + EPS_F);
    vout[c] = att[c] * sc0 + atte[c] * sc1;
  }
#pragma unroll
  for (int c = 0; c < 16; ++c) {
    vout[c] += __shfl_xor(vout[c], 1);
    vout[c] += __shfl_xor(vout[c], 2);
  }
  if (l == 0) {
#pragma unroll
    for (int c = 0; c < 16; ++c) {
      int c0 = 2 * (g * 16 + c), c1 = c0 + 1;
      float sc0 = bn_out[c0] * rsqrtf(bn_out[1536 + c0] + EPS_F);
      float sc1 = bn_out[c1] * rsqrtf(bn_out[1536 + c1] + EPS_F);
      float sh0 = bn_out[512 + c0] - bn_out[1024 + c0] * sc0;
      float sh1 = bn_out[512 + c1] - bn_out[1024 + c1] * sc1;
      bufB[c][r] = vout[c] + sh0 + sh1;
    }
  }
  __syncthreads();

  // ---- P6: coalesced transposed write ----
  {
    int c = tid >> 4, i4 = (tid & 15) << 2;
    float4 v = *(const float4*)&bufB[c][i4];
    size_t o = (((size_t)b * 256 + g * 16 + c) * 64 + d1) * 64 + i4;
    *(float4*)&out[o] = v;
  }
}

// ---------------- 2x2 mean pool: (N,64,64) -> (N,32,32) ----------------
__global__ void __launch_bounds__(256) pool_kernel(
    const float* __restrict__ in, float* __restrict__ out, int total) {
  int idx = blockIdx.x * 256 + threadIdx.x;
  if (idx >= total) return;
  int j = idx & 31, i = (idx >> 5) & 31, bc = idx >> 10;
  const float* p = in + (size_t)bc * 4096 + i * 128 + j * 2;
  out[idx] = 0.25f * (p[0] + p[1] + p[64] + p[65]);
}

extern "C" void kernel_launch(void* const* d_in, const int* in_sizes, int n_in,
                              void* d_out, int out_size, void* d_ws, size_t ws_size,
                              hipStream_t stream) {
  const float* x         = (const float*)d_in[0];
  const float* latent    = (const float*)d_in[1];
  const float* w_in      = (const float*)d_in[2];
  const float* bn_in     = (const float*)d_in[3];
  const float* lin_in    = (const float*)d_in[4];
  const float* alpha_in  = (const float*)d_in[5];
  const float* a0_wqkv   = (const float*)d_in[6];
  const float* a0_bn_qkv = (const float*)d_in[7];
  const float* a0_bn_sim = (const float*)d_in[8];
  const float* a0_bn_out = (const float*)d_in[9];
  const float* a0_rel    = (const float*)d_in[10];
  const float* a1_wqkv   = (const float*)d_in[11];
  const float* a1_bn_qkv = (const float*)d_in[12];
  const float* a1_bn_sim = (const float*)d_in[13];
  const float* a1_bn_out = (const float*)d_in[14];
  const float* a1_rel    = (const float*)d_in[15];
  const float* w_out     = (const float*)d_in[16];
  const float* bn_outp   = (const float*)d_in[17];
  const float* lin_out   = (const float*)d_in[18];
  const float* w_res     = (const float*)d_in[19];
  const float* alpha_fin = (const float*)d_in[20];

  float* ws     = (float*)d_ws;
  float* sb_in  = ws;                  // 2048 f
  float* sb_out = ws + 2048;           // 2048 f
  float* t0     = ws + 4096;           // 4,194,304 f  (B,256,64,64)
  float* qkvb   = t0 + 4194304;        // 8,388,608 f  (B,512,64,64)
  float* pool_o = qkvb + 8388608;      // 1,048,576 f
  float* pool_x = pool_o + 1048576;    //   524,288 f
  float* resb   = pool_x + 524288;     // 1,048,576 f

  sb_kernel<<<16, 256, 0, stream>>>(latent, lin_in, lin_out, sb_in, sb_out);

  // conv_in + cbn + prelu -> t0 (std layout b,c,h,w)
  conv1x1_kernel<11><<<dim3(32, 2, 4), 256, 0, stream>>>(
      x, w_in, t0, 128, 256, 4096, bn_in, sb_in, alpha_in, nullptr);

  // axial 0 over H: reads (b,c,h,w), writes (b,c,w,h)
  conv1x1_kernel<1><<<dim3(32, 4, 4), 256, 0, stream>>>(
      t0, a0_wqkv, qkvb, 256, 512, 4096, a0_bn_qkv, nullptr, nullptr, nullptr);
  axial_attn_kernel<<<4096, 256, 0, stream>>>(
      qkvb, a0_rel, a0_bn_sim, a0_bn_out, t0);

  // axial 1 over W: reads (b,c,w,h), writes (b,c,h,w)  [back to std]
  conv1x1_kernel<1><<<dim3(32, 4, 4), 256, 0, stream>>>(
      t0, a1_wqkv, qkvb, 256, 512, 4096, a1_bn_qkv, nullptr, nullptr, nullptr);
  axial_attn_kernel<<<4096, 256, 0, stream>>>(
      qkvb, a1_rel, a1_bn_sim, a1_bn_out, t0);

  // pools (pool is linear: pool(conv(w_res,x)) == conv(w_res, pool(x)))
  pool_kernel<<<4096, 256, 0, stream>>>(t0, pool_o, 1048576);
  pool_kernel<<<2048, 256, 0, stream>>>(x, pool_x, 524288);

  conv1x1_kernel<0><<<dim3(8, 2, 4), 256, 0, stream>>>(
      pool_x, w_res, resb, 128, 256, 1024, nullptr, nullptr, nullptr, nullptr);

  conv1x1_kernel<15><<<dim3(8, 2, 4), 256, 0, stream>>>(
      pool_o, w_out, (float*)d_out, 256, 256, 1024, bn_outp, sb_out, alpha_fin, resb);
}

// Round 4
// 405.082 us; speedup vs baseline: 1.3062x; 1.2666x over previous
//
#include <hip/hip_runtime.h>
#include <hip/hip_bf16.h>

#define EPS_F 1e-5f

typedef __attribute__((ext_vector_type(8))) _Float16 f16x8;
typedef __attribute__((ext_vector_type(4))) float f32x4;

union U16x8 { ushort u[8]; f16x8 v; };

static __device__ inline ushort f2h(float f) {  // RNE f32 -> f16 bits
  _Float16 h = (_Float16)f;
  return __builtin_bit_cast(ushort, h);
}
static __device__ inline float h2f(ushort u) {
  return (float)__builtin_bit_cast(_Float16, u);
}

// ---------------- sb = latent @ lin^T (for both cbn layers) ----------------
__global__ void __launch_bounds__(256) sb_kernel(
    const float* __restrict__ latent,
    const float* __restrict__ lin_in,
    const float* __restrict__ lin_out,
    float* __restrict__ sb_in,
    float* __restrict__ sb_out) {
  int idx = blockIdx.x * 256 + threadIdx.x;   // 0..4095
  int which = idx >> 11;
  int r = idx & 2047;
  int b = r >> 9;
  int k = r & 511;
  const float* lin = which ? lin_out : lin_in;
  const float* lv = latent + b * 256;
  const float* lr = lin + k * 256;
  float acc = 0.f;
#pragma unroll 8
  for (int l = 0; l < 256; ++l) acc += lv[l] * lr[l];
  (which ? sb_out : sb_in)[b * 512 + k] = acc;
}

// ---------------- generic conv1x1 (channel matmul, fp32) ----------------
// MODE bits: 1 = bn affine, 2 = cbn, 4 = add addbuf, 8 = prelu
template <int MODE>
__global__ void __launch_bounds__(256) conv1x1_kernel(
    const float* __restrict__ X, const float* __restrict__ Wm,
    float* __restrict__ Y, int Cin, int Cout, int P,
    const float* __restrict__ bn, const float* __restrict__ sb,
    const float* __restrict__ alpha, const float* __restrict__ addbuf) {
  const int tid = threadIdx.x;
  const int tx = tid & 15;
  const int ty = tid >> 4;
  const int p0 = blockIdx.x * 128;
  const int o0 = blockIdx.y * 128;
  const int b  = blockIdx.z;

  __shared__ float Xs[16][132];
  __shared__ float Wt[16][132];

  float acc[8][8] = {};
  const float* Xb = X + (size_t)b * Cin * P;

  for (int k0 = 0; k0 < Cin; k0 += 16) {
#pragma unroll
    for (int r = 0; r < 8; ++r) {
      int e = tid + r * 256;
      int c = e >> 7, p = e & 127;
      Xs[c][p] = Xb[(size_t)(k0 + c) * P + p0 + p];
    }
#pragma unroll
    for (int r = 0; r < 8; ++r) {
      int e = tid + r * 256;
      int o = e >> 4, c = e & 15;
      Wt[c][o] = Wm[(size_t)(o0 + o) * Cin + k0 + c];
    }
    __syncthreads();
#pragma unroll
    for (int kk = 0; kk < 16; ++kk) {
      float4 w0 = *(const float4*)&Wt[kk][ty * 8];
      float4 w1 = *(const float4*)&Wt[kk][ty * 8 + 4];
      float4 x0 = *(const float4*)&Xs[kk][tx * 8];
      float4 x1 = *(const float4*)&Xs[kk][tx * 8 + 4];
      float wa[8] = {w0.x, w0.y, w0.z, w0.w, w1.x, w1.y, w1.z, w1.w};
      float xa[8] = {x0.x, x0.y, x0.z, x0.w, x1.x, x1.y, x1.z, x1.w};
#pragma unroll
      for (int i = 0; i < 8; ++i)
#pragma unroll
        for (int j = 0; j < 8; ++j) acc[i][j] += wa[i] * xa[j];
    }
    __syncthreads();
  }

#pragma unroll
  for (int i = 0; i < 8; ++i) {
    int oc = o0 + ty * 8 + i;
    float scale = 1.f, shift = 0.f;
    if (MODE & 1) {
      float sc = bn[oc] * rsqrtf(bn[3 * Cout + oc] + EPS_F);
      scale = sc;
      shift = bn[Cout + oc] - bn[2 * Cout + oc] * sc;
    }
    if (MODE & 2) {
      float s  = sb[b * 2 * Cout + oc];
      float bb = sb[b * 2 * Cout + Cout + oc];
      scale *= s;
      shift = shift * s + bb;
    }
    float a = (MODE & 8) ? *alpha : 0.f;
    size_t row = ((size_t)b * Cout + oc) * P + p0;
#pragma unroll
    for (int j = 0; j < 8; ++j) {
      int p = tx * 8 + j;
      float v = acc[i][j] * scale + shift;
      if (MODE & 4) v += addbuf[row + p];
      if (MODE & 8) v = v > 0.f ? v : a * v;
      Y[row + p] = v;
    }
  }
}

// ---------------- axial attention, MFMA (f16) version ----------------
// One block per (bd, g). Input (b, ch, pA, pB): attended dim pA=i, fixed pB=d1.
// Output transposed: out[((b*256+oc)*64 + d1)*64 + i].
// Diagonal form: G_q[d][k] = sum_c q[c,k]*rel_q[c,d]; q_emb[a,b] = G_q[a-b+63][a].
__global__ void __launch_bounds__(256) axial_attn_kernel(
    const float* __restrict__ qkv, const float* __restrict__ rel,
    const float* __restrict__ bn_sim, const float* __restrict__ bn_out,
    float* __restrict__ out) {
  const int tid = threadIdx.x;
  int lin = blockIdx.x;                       // bijective XCD swizzle (4096 % 8 == 0)
  int wg = ((lin & 7) << 9) + (lin >> 3);
  const int g  = wg >> 8;
  const int bd = wg & 255;
  const int b  = bd >> 6;
  const int d1 = bd & 63;

  __shared__ __align__(16) char smem[44288];
  float*  qs = (float*)smem;                          // [16][64] fp32 (q rows 0-7, k rows 8-15)
  ushort* Gq = (ushort*)(smem + 4096);                // [127][66] f16
  ushort* Gk = Gq + 127 * 66;                         // [127][66]
  ushort* A2 = (ushort*)(smem + 4096);                // [64][136] f16, overlays G after sim
  ushort* VC = (ushort*)(smem + 4096 + 33536);        // [16][72]  v as [c][j]
  ushort* RV = (ushort*)(smem + 4096 + 33536 + 2304); // [16][136] rel_ve as [c][d], d=127..135 zero

  const int lane = tid & 63;
  const int wv   = tid >> 6;   // wave 0..3
  const int m    = lane & 15;
  const int h    = lane >> 4;

  // ---- P0: loads ----
  {
    const float* src = qkv + ((size_t)b * 512 + g * 32) * 4096 + d1;
#pragma unroll
    for (int n = 0; n < 8; ++n) {
      int e = tid + n * 256;
      int c = e >> 6, i = e & 63;
      float v = src[(size_t)c * 4096 + i * 64];
      if (c < 16) qs[c * 64 + i] = v;
      else        VC[(c - 16) * 72 + i] = f2h(v);
    }
    for (int e = tid; e < 16 * 136; e += 256) {
      int c = e / 136, d = e - c * 136;
      RV[e] = (d < 127) ? f2h(rel[(16 + c) * 127 + d]) : (ushort)0;
    }
  }
  __syncthreads();

  // ---- P1: G_q / G_k (rel via wave-uniform scalar loads) ----
  {
    const int wu = __builtin_amdgcn_readfirstlane(wv);
    float qr[8], kr[8];
#pragma unroll
    for (int c = 0; c < 8; ++c) {
      qr[c] = qs[c * 64 + lane];
      kr[c] = qs[(8 + c) * 64 + lane];
    }
#pragma unroll
    for (int dq = 0; dq < 8; ++dq) {
      int d0 = 4 * wu + 16 * dq;
      float aq[4] = {0.f, 0.f, 0.f, 0.f}, ak[4] = {0.f, 0.f, 0.f, 0.f};
#pragma unroll
      for (int c = 0; c < 8; ++c) {
        const float* rq = rel + c * 127 + d0;
        const float* rk = rel + (8 + c) * 127 + d0;
#pragma unroll
        for (int di = 0; di < 4; ++di) {
          aq[di] += qr[c] * rq[di];
          ak[di] += kr[c] * rk[di];
        }
      }
#pragma unroll
      for (int di = 0; di < 4; ++di) {
        int d = d0 + di;
        if (d < 127) {
          Gq[d * 66 + lane] = f2h(aq[di]);
          Gk[d * 66 + lane] = f2h(ak[di]);
        }
      }
    }
  }
  __syncthreads();

  // ---- P2: sim = s_qk*(q_emb^T k_emb) + s_qe*q_emb + s_ke*k_emb + sh ----
  // wave wv owns rows [16wv, 16wv+16). A[i][kk] = G_q[kk-i+63][kk]; B[kk][j] = G_k[kk-j+63][kk]
  f32x4 acc[4];
#pragma unroll
  for (int tj = 0; tj < 4; ++tj) acc[tj] = (f32x4){0.f, 0.f, 0.f, 0.f};
  {
    U16x8 afr[2];
    const int ia = 16 * wv + m;
#pragma unroll
    for (int ks = 0; ks < 2; ++ks)
#pragma unroll
      for (int e = 0; e < 8; ++e) {
        int kk = 32 * ks + 8 * h + e;
        afr[ks].u[e] = Gq[(kk - ia + 63) * 66 + kk];
      }
#pragma unroll
    for (int tj = 0; tj < 4; ++tj) {
      int j = 16 * tj + m;
#pragma unroll
      for (int ks = 0; ks < 2; ++ks) {
        U16x8 bfr;
#pragma unroll
        for (int e = 0; e < 8; ++e) {
          int kk = 32 * ks + 8 * h + e;
          bfr.u[e] = Gk[(kk - j + 63) * 66 + kk];
        }
        acc[tj] = __builtin_amdgcn_mfma_f32_16x16x32_f16(afr[ks].v, bfr.v, acc[tj], 0, 0, 0);
      }
    }
  }

  // folded BN(sim)
  float s_qk = bn_sim[g]      * rsqrtf(bn_sim[144 + g] + EPS_F);
  float s_qe = bn_sim[16 + g] * rsqrtf(bn_sim[160 + g] + EPS_F);
  float s_ke = bn_sim[32 + g] * rsqrtf(bn_sim[176 + g] + EPS_F);
  float sh   = (bn_sim[48 + g] - bn_sim[96 + g]  * s_qk)
             + (bn_sim[64 + g] - bn_sim[112 + g] * s_qe)
             + (bn_sim[80 + g] - bn_sim[128 + g] * s_ke);

  // emb add (D layout: row = 16wv + 4h + r, col = 16tj + m)
  const int ib = 16 * wv + 4 * h;
  float sv[4][4];
#pragma unroll
  for (int tj = 0; tj < 4; ++tj) {
    int j = 16 * tj + m;
#pragma unroll
    for (int r = 0; r < 4; ++r) {
      int i = ib + r;
      int d = i - j + 63;
      float qe = h2f(Gq[d * 66 + i]);
      float ke = h2f(Gk[d * 66 + i]);
      sv[tj][r] = acc[tj][r] * s_qk + qe * s_qe + ke * s_ke + sh;
    }
  }

  // ---- P3: softmax over j (16 lanes sharing h hold a full row) ----
  float p[4][4];
  {
    float mx[4], sum[4];
#pragma unroll
    for (int r = 0; r < 4; ++r) {
      float v = fmaxf(fmaxf(sv[0][r], sv[1][r]), fmaxf(sv[2][r], sv[3][r]));
      v = fmaxf(v, __shfl_xor(v, 1));
      v = fmaxf(v, __shfl_xor(v, 2));
      v = fmaxf(v, __shfl_xor(v, 4));
      v = fmaxf(v, __shfl_xor(v, 8));
      mx[r] = v;
    }
#pragma unroll
    for (int r = 0; r < 4; ++r) {
      float s = 0.f;
#pragma unroll
      for (int tj = 0; tj < 4; ++tj) {
        p[tj][r] = __expf(sv[tj][r] - mx[r]);
        s += p[tj][r];
      }
      s += __shfl_xor(s, 1);
      s += __shfl_xor(s, 2);
      s += __shfl_xor(s, 4);
      s += __shfl_xor(s, 8);
      sum[r] = 1.f / s;
    }
#pragma unroll
    for (int tj = 0; tj < 4; ++tj)
#pragma unroll
      for (int r = 0; r < 4; ++r) p[tj][r] *= sum[r];
  }

  // ---- P4: zero A2 (overlays G; all G reads done), then scatter P ----
  __syncthreads();
  {
    uint4 z = make_uint4(0u, 0u, 0u, 0u);
    for (int u2 = tid; u2 < 1088; u2 += 256) ((uint4*)A2)[u2] = z;
  }
  __syncthreads();
#pragma unroll
  for (int tj = 0; tj < 4; ++tj) {
    int j = 16 * tj + m;
#pragma unroll
    for (int r = 0; r < 4; ++r) {
      int i = ib + r;
      A2[i * 136 + (i - j + 63)] = f2h(p[tj][r]);  // A2[i][d] = P[i][i-d+63]
    }
  }
  // wave reads only its own rows below -> no extra barrier needed

  // ---- P5: att = P V (diag A-frag), att_e = A2 @ rel_ve^T (b128 A-frag) ----
  f32x4 accA = (f32x4){0.f, 0.f, 0.f, 0.f};
  f32x4 accE = (f32x4){0.f, 0.f, 0.f, 0.f};
  {
    const int ia = 16 * wv + m;
#pragma unroll
    for (int ks = 0; ks < 2; ++ks) {
      U16x8 pa;
#pragma unroll
      for (int e = 0; e < 8; ++e) {
        int j = 32 * ks + 8 * h + e;
        pa.u[e] = A2[ia * 136 + (ia - j + 63)];
      }
      f16x8 vb = *(const f16x8*)&VC[m * 72 + 32 * ks + 8 * h];
      accA = __builtin_amdgcn_mfma_f32_16x16x32_f16(pa.v, vb, accA, 0, 0, 0);
    }
#pragma unroll
    for (int ks = 0; ks < 4; ++ks) {
      f16x8 pe = *(const f16x8*)&A2[ia * 136 + 32 * ks + 8 * h];
      f16x8 rv = *(const f16x8*)&RV[m * 136 + 32 * ks + 8 * h];
      accE = __builtin_amdgcn_mfma_f32_16x16x32_f16(pe, rv, accE, 0, 0, 0);
    }
  }

  // ---- P6: fold bn_out, write float4 (D: row i = 16wv+4h+r, col c = m) ----
  {
    int oc = g * 16 + m;
    int c0 = 2 * oc, c1 = c0 + 1;
    float sc0 = bn_out[c0] * rsqrtf(bn_out[1536 + c0] + EPS_F);
    float sh0 = bn_out[512 + c0] - bn_out[1024 + c0] * sc0;
    float sc1 = bn_out[c1] * rsqrtf(bn_out[1536 + c1] + EPS_F);
    float sh1 = bn_out[512 + c1] - bn_out[1024 + c1] * sc1;
    float4 vo;
    vo.x = accA[0] * sc0 + accE[0] * sc1 + sh0 + sh1;
    vo.y = accA[1] * sc0 + accE[1] * sc1 + sh0 + sh1;
    vo.z = accA[2] * sc0 + accE[2] * sc1 + sh0 + sh1;
    vo.w = accA[3] * sc0 + accE[3] * sc1 + sh0 + sh1;
    size_t o = (((size_t)b * 256 + oc) * 64 + d1) * 64 + 16 * wv + 4 * h;
    *(float4*)&out[o] = vo;
  }
}

// ---------------- 2x2 mean pool ----------------
__global__ void __launch_bounds__(256) pool_kernel(
    const float* __restrict__ in, float* __restrict__ out, int total) {
  int idx = blockIdx.x * 256 + threadIdx.x;
  if (idx >= total) return;
  int j = idx & 31, i = (idx >> 5) & 31, bc = idx >> 10;
  const float* p = in + (size_t)bc * 4096 + i * 128 + j * 2;
  out[idx] = 0.25f * (p[0] + p[1] + p[64] + p[65]);
}

extern "C" void kernel_launch(void* const* d_in, const int* in_sizes, int n_in,
                              void* d_out, int out_size, void* d_ws, size_t ws_size,
                              hipStream_t stream) {
  const float* x         = (const float*)d_in[0];
  const float* latent    = (const float*)d_in[1];
  const float* w_in      = (const float*)d_in[2];
  const float* bn_in     = (const float*)d_in[3];
  const float* lin_in    = (const float*)d_in[4];
  const float* alpha_in  = (const float*)d_in[5];
  const float* a0_wqkv   = (const float*)d_in[6];
  const float* a0_bn_qkv = (const float*)d_in[7];
  const float* a0_bn_sim = (const float*)d_in[8];
  const float* a0_bn_out = (const float*)d_in[9];
  const float* a0_rel    = (const float*)d_in[10];
  const float* a1_wqkv   = (const float*)d_in[11];
  const float* a1_bn_qkv = (const float*)d_in[12];
  const float* a1_bn_sim = (const float*)d_in[13];
  const float* a1_bn_out = (const float*)d_in[14];
  const float* a1_rel    = (const float*)d_in[15];
  const float* w_out     = (const float*)d_in[16];
  const float* bn_outp   = (const float*)d_in[17];
  const float* lin_out   = (const float*)d_in[18];
  const float* w_res     = (const float*)d_in[19];
  const float* alpha_fin = (const float*)d_in[20];

  float* ws     = (float*)d_ws;
  float* sb_in  = ws;                  // 2048 f
  float* sb_out = ws + 2048;           // 2048 f
  float* t0     = ws + 4096;           // (B,256,64,64)
  float* qkvb   = t0 + 4194304;        // (B,512,64,64)
  float* pool_o = qkvb + 8388608;
  float* pool_x = pool_o + 1048576;
  float* resb   = pool_x + 524288;

  sb_kernel<<<16, 256, 0, stream>>>(latent, lin_in, lin_out, sb_in, sb_out);

  // conv_in + cbn + prelu -> t0 (std layout b,c,h,w)
  conv1x1_kernel<11><<<dim3(32, 2, 4), 256, 0, stream>>>(
      x, w_in, t0, 128, 256, 4096, bn_in, sb_in, alpha_in, nullptr);

  // axial 0 over H: reads (b,c,h,w), writes (b,c,w,h)
  conv1x1_kernel<1><<<dim3(32, 4, 4), 256, 0, stream>>>(
      t0, a0_wqkv, qkvb, 256, 512, 4096, a0_bn_qkv, nullptr, nullptr, nullptr);
  axial_attn_kernel<<<4096, 256, 0, stream>>>(
      qkvb, a0_rel, a0_bn_sim, a0_bn_out, t0);

  // axial 1 over W: reads (b,c,w,h), writes (b,c,h,w)  [back to std]
  conv1x1_kernel<1><<<dim3(32, 4, 4), 256, 0, stream>>>(
      t0, a1_wqkv, qkvb, 256, 512, 4096, a1_bn_qkv, nullptr, nullptr, nullptr);
  axial_attn_kernel<<<4096, 256, 0, stream>>>(
      qkvb, a1_rel, a1_bn_sim, a1_bn_out, t0);

  // pools (pool(conv(w_res,x)) == conv(w_res, pool(x)))
  pool_kernel<<<4096, 256, 0, stream>>>(t0, pool_o, 1048576);
  pool_kernel<<<2048, 256, 0, stream>>>(x, pool_x, 524288);

  conv1x1_kernel<0><<<dim3(8, 2, 4), 256, 0, stream>>>(
      pool_x, w_res, resb, 128, 256, 1024, nullptr, nullptr, nullptr, nullptr);

  conv1x1_kernel<15><<<dim3(8, 2, 4), 256, 0, stream>>>(
      pool_o, w_out, (float*)d_out, 256, 256, 1024, bn_outp, sb_out, alpha_fin, resb);
}

// Round 5
// 285.599 us; speedup vs baseline: 1.8527x; 1.4184x over previous
//
#include <hip/hip_runtime.h>
#include <hip/hip_bf16.h>

#define EPS_F 1e-5f

typedef __attribute__((ext_vector_type(8))) _Float16 f16x8;
typedef __attribute__((ext_vector_type(4))) float f32x4;

union U16x8 { ushort u[8]; f16x8 v; };

static __device__ inline ushort f2h(float f) {
  _Float16 h = (_Float16)f;
  return __builtin_bit_cast(ushort, h);
}
static __device__ inline float h2f(ushort u) {
  return (float)__builtin_bit_cast(_Float16, u);
}

// ---------------- prep: convert weights to f16 + sb = latent @ lin^T ----------------
// grid 1552 x 256: first 393216 threads convert weights, last 4096 compute sb.
__global__ void __launch_bounds__(256) prep_kernel(
    const float* __restrict__ w_in, const float* __restrict__ a0w,
    const float* __restrict__ a1w, const float* __restrict__ w_out,
    const float* __restrict__ w_res,
    const float* __restrict__ latent, const float* __restrict__ lin_in,
    const float* __restrict__ lin_out,
    ushort* __restrict__ w16, float* __restrict__ sb_in, float* __restrict__ sb_out) {
  int idx = blockIdx.x * 256 + threadIdx.x;
  if (idx < 393216) {
    const float* src; int off;
    if (idx < 32768)       { src = w_in;  off = 0; }
    else if (idx < 163840) { src = a0w;   off = 32768; }
    else if (idx < 294912) { src = a1w;   off = 163840; }
    else if (idx < 360448) { src = w_out; off = 294912; }
    else                   { src = w_res; off = 360448; }
    w16[idx] = f2h(src[idx - off]);
  } else {
    int r = idx - 393216;            // 0..4095
    int which = r >> 11;
    int rr = r & 2047;
    int b = rr >> 9, k = rr & 511;
    const float* lin = which ? lin_out : lin_in;
    const float* lv = latent + b * 256;
    const float* lr = lin + k * 256;
    float acc = 0.f;
#pragma unroll 8
    for (int l = 0; l < 256; ++l) acc += lv[l] * lr[l];
    (which ? sb_out : sb_in)[b * 512 + k] = acc;
  }
}

// ---------------- cvt: f32 -> f16, float4-vectorized ----------------
__global__ void __launch_bounds__(256) cvt_kernel(
    const float* __restrict__ in, ushort* __restrict__ out, int n4) {
  int idx = blockIdx.x * 256 + threadIdx.x;
  if (idx >= n4) return;
  float4 v = ((const float4*)in)[idx];
  ushort4 o;
  o.x = f2h(v.x); o.y = f2h(v.y); o.z = f2h(v.z); o.w = f2h(v.w);
  ((ushort4*)out)[idx] = o;
}

// ---------------- MFMA f16 conv1x1 ----------------
// Y[b,oc,p] = post( sum_c W[oc,c] * X[b,c,p] ), X/W f16, accumulate f32.
// MODE bits: 1 = bn affine, 2 = cbn, 4 = add addbuf(f32), 8 = prelu
// OUT32: write f32 (direct scattered), else f16 (LDS-restaged coalesced).
// grid (P/128, Cout/128, B), 256 threads. Cin % 32 == 0.
template <int MODE, bool OUT32>
__global__ void __launch_bounds__(256) conv_mfma_kernel(
    const ushort* __restrict__ X, const ushort* __restrict__ W16,
    void* __restrict__ Yv, int Cin, int Cout, int P,
    const float* __restrict__ bn, const float* __restrict__ sb,
    const float* __restrict__ alpha, const float* __restrict__ addbuf) {
  const int tid = threadIdx.x;
  const int p0 = blockIdx.x * 128;
  const int o0 = blockIdx.y * 128;
  const int b  = blockIdx.z;
  const int lane = tid & 63;
  const int wv = tid >> 6;
  const int m = lane & 15, h = lane >> 4;
  const int wr = wv >> 1, wc = wv & 1;   // wave tile: oc base 64*wr, p base 64*wc

  __shared__ __align__(16) char smem[20480];
  ushort (*Xs)[40] = (ushort(*)[40])smem;            // [p][k]  10240 B
  ushort (*Ws)[40] = (ushort(*)[40])(smem + 10240);  // [oc][k] 10240 B
  ushort (*Es)[136] = (ushort(*)[136])smem;          // epilogue overlay [64][136]

  f32x4 acc[4][4];
#pragma unroll
  for (int i = 0; i < 4; ++i)
#pragma unroll
    for (int j = 0; j < 4; ++j) acc[i][j] = (f32x4){0.f, 0.f, 0.f, 0.f};

  const ushort* Xb = X + (size_t)b * Cin * P;
  const int s = tid & 15;
  const int cb = tid >> 4;

  for (int k0 = 0; k0 < Cin; k0 += 32) {
    __syncthreads();
    // stage X transposed -> Xs[p][k]; bank-rotated b16 writes
#pragma unroll
    for (int half = 0; half < 2; ++half) {
      int c = cb + 16 * half;
      U16x8 xv;
      xv.v = *(const f16x8*)&Xb[(size_t)(k0 + c) * P + p0 + 8 * s];
#pragma unroll
      for (int t = 0; t < 8; ++t) {
        int j = (t + s) & 7;
        Xs[8 * s + j][c] = xv.u[j];
      }
    }
    // stage W -> Ws[oc][k]
    {
      int oc = tid >> 1, hh = (tid & 1) << 4;
      const ushort* wsrc = W16 + (size_t)(o0 + oc) * Cin + k0 + hh;
      *(f16x8*)&Ws[oc][hh]     = *(const f16x8*)wsrc;
      *(f16x8*)&Ws[oc][hh + 8] = *(const f16x8*)(wsrc + 8);
    }
    __syncthreads();
    // fragments + 16 MFMA
    f16x8 af[4], bf[4];
#pragma unroll
    for (int t = 0; t < 4; ++t) {
      af[t] = *(const f16x8*)&Ws[64 * wr + 16 * t + m][8 * h];
      bf[t] = *(const f16x8*)&Xs[64 * wc + 16 * t + m][8 * h];
    }
#pragma unroll
    for (int ta = 0; ta < 4; ++ta)
#pragma unroll
      for (int tb = 0; tb < 4; ++tb)
        acc[ta][tb] = __builtin_amdgcn_mfma_f32_16x16x32_f16(af[ta], bf[tb], acc[ta][tb], 0, 0, 0);
  }

  // per-(ta,r) affine
  float scl[4][4], shf[4][4];
#pragma unroll
  for (int ta = 0; ta < 4; ++ta)
#pragma unroll
    for (int r = 0; r < 4; ++r) {
      int oc = o0 + 64 * wr + 16 * ta + 4 * h + r;
      float scale = 1.f, shift = 0.f;
      if (MODE & 1) {
        float sc = bn[oc] * rsqrtf(bn[3 * Cout + oc] + EPS_F);
        scale = sc;
        shift = bn[Cout + oc] - bn[2 * Cout + oc] * sc;
      }
      if (MODE & 2) {
        float ss = sb[b * 2 * Cout + oc];
        float bb = sb[b * 2 * Cout + Cout + oc];
        scale *= ss;
        shift = shift * ss + bb;
      }
      scl[ta][r] = scale; shf[ta][r] = shift;
    }
  float al = (MODE & 8) ? *alpha : 0.f;

  if (OUT32) {
    float* Y32 = (float*)Yv;
#pragma unroll
    for (int ta = 0; ta < 4; ++ta)
#pragma unroll
      for (int tb = 0; tb < 4; ++tb)
#pragma unroll
        for (int r = 0; r < 4; ++r) {
          int oc = o0 + 64 * wr + 16 * ta + 4 * h + r;
          int p  = p0 + 64 * wc + 16 * tb + m;
          float v = acc[ta][tb][r] * scl[ta][r] + shf[ta][r];
          size_t o = ((size_t)b * Cout + oc) * P + p;
          if (MODE & 4) v += addbuf[o];
          if (MODE & 8) v = v > 0.f ? v : al * v;
          Y32[o] = v;
        }
  } else {
    ushort* Y16 = (ushort*)Yv;
#pragma unroll
    for (int ohalf = 0; ohalf < 2; ++ohalf) {
      __syncthreads();
      if (wr == ohalf) {
#pragma unroll
        for (int ta = 0; ta < 4; ++ta)
#pragma unroll
          for (int tb = 0; tb < 4; ++tb)
#pragma unroll
            for (int r = 0; r < 4; ++r) {
              float v = acc[ta][tb][r] * scl[ta][r] + shf[ta][r];
              if (MODE & 8) v = v > 0.f ? v : al * v;
              Es[16 * ta + 4 * h + r][64 * wc + 16 * tb + m] = f2h(v);
            }
      }
      __syncthreads();
      int row = tid >> 2, q = tid & 3;
      size_t g = ((size_t)b * Cout + o0 + 64 * ohalf + row) * P + p0 + 32 * q;
#pragma unroll
      for (int u = 0; u < 4; ++u)
        *(f16x8*)&Y16[g + 8 * u] = *(const f16x8*)&Es[row][32 * q + 8 * u];
    }
  }
}

// ---------------- axial attention, MFMA f16 (f16 in/out) ----------------
// One block per (bd, g). Input (b, ch, pA, pB): attended dim pA=i, fixed pB=d1.
// Output transposed: out[((b*256+oc)*64 + d1)*64 + i].
__global__ void __launch_bounds__(256) axial_attn_kernel(
    const ushort* __restrict__ qkv, const float* __restrict__ rel,
    const float* __restrict__ bn_sim, const float* __restrict__ bn_out,
    ushort* __restrict__ out) {
  const int tid = threadIdx.x;
  int lin = blockIdx.x;                       // bijective XCD swizzle (4096 % 8 == 0)
  int wg = ((lin & 7) << 9) + (lin >> 3);
  const int g  = wg >> 8;
  const int bd = wg & 255;
  const int b  = bd >> 6;
  const int d1 = bd & 63;

  __shared__ __align__(16) char smem[44288];
  float*  qs = (float*)smem;                          // [16][64] fp32
  ushort* Gq = (ushort*)(smem + 4096);                // [127][66] f16
  ushort* Gk = Gq + 127 * 66;                         // [127][66]
  ushort* A2 = (ushort*)(smem + 4096);                // [64][136] f16, overlays G
  ushort* VC = (ushort*)(smem + 4096 + 33536);        // [16][72]  v as [c][j]
  ushort* RV = (ushort*)(smem + 4096 + 33536 + 2304); // [16][136] rel_ve as [c][d]

  const int lane = tid & 63;
  const int wv   = tid >> 6;
  const int m    = lane & 15;
  const int h    = lane >> 4;

  // ---- P0: loads ----
  {
    const ushort* src = qkv + ((size_t)b * 512 + g * 32) * 4096 + d1;
#pragma unroll
    for (int n = 0; n < 8; ++n) {
      int e = tid + n * 256;
      int c = e >> 6, i = e & 63;
      ushort raw = src[(size_t)c * 4096 + i * 64];
      if (c < 16) qs[c * 64 + i] = h2f(raw);
      else        VC[(c - 16) * 72 + i] = raw;
    }
    for (int e = tid; e < 16 * 136; e += 256) {
      int c = e / 136, d = e - c * 136;
      RV[e] = (d < 127) ? f2h(rel[(16 + c) * 127 + d]) : (ushort)0;
    }
  }
  __syncthreads();

  // ---- P1: G_q / G_k ----
  {
    const int wu = __builtin_amdgcn_readfirstlane(wv);
    float qr[8], kr[8];
#pragma unroll
    for (int c = 0; c < 8; ++c) {
      qr[c] = qs[c * 64 + lane];
      kr[c] = qs[(8 + c) * 64 + lane];
    }
#pragma unroll
    for (int dq = 0; dq < 8; ++dq) {
      int d0 = 4 * wu + 16 * dq;
      float aq[4] = {0.f, 0.f, 0.f, 0.f}, ak[4] = {0.f, 0.f, 0.f, 0.f};
#pragma unroll
      for (int c = 0; c < 8; ++c) {
        const float* rq = rel + c * 127 + d0;
        const float* rk = rel + (8 + c) * 127 + d0;
#pragma unroll
        for (int di = 0; di < 4; ++di) {
          aq[di] += qr[c] * rq[di];
          ak[di] += kr[c] * rk[di];
        }
      }
#pragma unroll
      for (int di = 0; di < 4; ++di) {
        int d = d0 + di;
        if (d < 127) {
          Gq[d * 66 + lane] = f2h(aq[di]);
          Gk[d * 66 + lane] = f2h(ak[di]);
        }
      }
    }
  }
  __syncthreads();

  // ---- P2: sim ----
  f32x4 acc[4];
#pragma unroll
  for (int tj = 0; tj < 4; ++tj) acc[tj] = (f32x4){0.f, 0.f, 0.f, 0.f};
  {
    U16x8 afr[2];
    const int ia = 16 * wv + m;
#pragma unroll
    for (int ks = 0; ks < 2; ++ks)
#pragma unroll
      for (int e = 0; e < 8; ++e) {
        int kk = 32 * ks + 8 * h + e;
        afr[ks].u[e] = Gq[(kk - ia + 63) * 66 + kk];
      }
#pragma unroll
    for (int tj = 0; tj < 4; ++tj) {
      int j = 16 * tj + m;
#pragma unroll
      for (int ks = 0; ks < 2; ++ks) {
        U16x8 bfr;
#pragma unroll
        for (int e = 0; e < 8; ++e) {
          int kk = 32 * ks + 8 * h + e;
          bfr.u[e] = Gk[(kk - j + 63) * 66 + kk];
        }
        acc[tj] = __builtin_amdgcn_mfma_f32_16x16x32_f16(afr[ks].v, bfr.v, acc[tj], 0, 0, 0);
      }
    }
  }

  float s_qk = bn_sim[g]      * rsqrtf(bn_sim[144 + g] + EPS_F);
  float s_qe = bn_sim[16 + g] * rsqrtf(bn_sim[160 + g] + EPS_F);
  float s_ke = bn_sim[32 + g] * rsqrtf(bn_sim[176 + g] + EPS_F);
  float sh   = (bn_sim[48 + g] - bn_sim[96 + g]  * s_qk)
             + (bn_sim[64 + g] - bn_sim[112 + g] * s_qe)
             + (bn_sim[80 + g] - bn_sim[128 + g] * s_ke);

  const int ib = 16 * wv + 4 * h;
  float sv[4][4];
#pragma unroll
  for (int tj = 0; tj < 4; ++tj) {
    int j = 16 * tj + m;
#pragma unroll
    for (int r = 0; r < 4; ++r) {
      int i = ib + r;
      int d = i - j + 63;
      float qe = h2f(Gq[d * 66 + i]);
      float ke = h2f(Gk[d * 66 + i]);
      sv[tj][r] = acc[tj][r] * s_qk + qe * s_qe + ke * s_ke + sh;
    }
  }

  // ---- P3: softmax ----
  float p[4][4];
  {
    float mx[4];
#pragma unroll
    for (int r = 0; r < 4; ++r) {
      float v = fmaxf(fmaxf(sv[0][r], sv[1][r]), fmaxf(sv[2][r], sv[3][r]));
      v = fmaxf(v, __shfl_xor(v, 1));
      v = fmaxf(v, __shfl_xor(v, 2));
      v = fmaxf(v, __shfl_xor(v, 4));
      v = fmaxf(v, __shfl_xor(v, 8));
      mx[r] = v;
    }
#pragma unroll
    for (int r = 0; r < 4; ++r) {
      float ssum = 0.f;
#pragma unroll
      for (int tj = 0; tj < 4; ++tj) {
        p[tj][r] = __expf(sv[tj][r] - mx[r]);
        ssum += p[tj][r];
      }
      ssum += __shfl_xor(ssum, 1);
      ssum += __shfl_xor(ssum, 2);
      ssum += __shfl_xor(ssum, 4);
      ssum += __shfl_xor(ssum, 8);
      float inv = 1.f / ssum;
#pragma unroll
      for (int tj = 0; tj < 4; ++tj) p[tj][r] *= inv;
    }
  }

  // ---- P4: zero A2, scatter P ----
  __syncthreads();
  {
    uint4 z = make_uint4(0u, 0u, 0u, 0u);
    for (int u2 = tid; u2 < 1088; u2 += 256) ((uint4*)A2)[u2] = z;
  }
  __syncthreads();
#pragma unroll
  for (int tj = 0; tj < 4; ++tj) {
    int j = 16 * tj + m;
#pragma unroll
    for (int r = 0; r < 4; ++r) {
      int i = ib + r;
      A2[i * 136 + (i - j + 63)] = f2h(p[tj][r]);
    }
  }

  // ---- P5: att / att_e ----
  f32x4 accA = (f32x4){0.f, 0.f, 0.f, 0.f};
  f32x4 accE = (f32x4){0.f, 0.f, 0.f, 0.f};
  {
    const int ia = 16 * wv + m;
#pragma unroll
    for (int ks = 0; ks < 2; ++ks) {
      U16x8 pa;
#pragma unroll
      for (int e = 0; e < 8; ++e) {
        int j = 32 * ks + 8 * h + e;
        pa.u[e] = A2[ia * 136 + (ia - j + 63)];
      }
      f16x8 vb = *(const f16x8*)&VC[m * 72 + 32 * ks + 8 * h];
      accA = __builtin_amdgcn_mfma_f32_16x16x32_f16(pa.v, vb, accA, 0, 0, 0);
    }
#pragma unroll
    for (int ks = 0; ks < 4; ++ks) {
      f16x8 pe = *(const f16x8*)&A2[ia * 136 + 32 * ks + 8 * h];
      f16x8 rv = *(const f16x8*)&RV[m * 136 + 32 * ks + 8 * h];
      accE = __builtin_amdgcn_mfma_f32_16x16x32_f16(pe, rv, accE, 0, 0, 0);
    }
  }

  // ---- P6: fold bn_out, f16 write ----
  {
    int oc = g * 16 + m;
    int c0 = 2 * oc, c1 = c0 + 1;
    float sc0 = bn_out[c0] * rsqrtf(bn_out[1536 + c0] + EPS_F);
    float sh0 = bn_out[512 + c0] - bn_out[1024 + c0] * sc0;
    float sc1 = bn_out[c1] * rsqrtf(bn_out[1536 + c1] + EPS_F);
    float sh1 = bn_out[512 + c1] - bn_out[1024 + c1] * sc1;
    ushort4 vo;
    vo.x = f2h(accA[0] * sc0 + accE[0] * sc1 + sh0 + sh1);
    vo.y = f2h(accA[1] * sc0 + accE[1] * sc1 + sh0 + sh1);
    vo.z = f2h(accA[2] * sc0 + accE[2] * sc1 + sh0 + sh1);
    vo.w = f2h(accA[3] * sc0 + accE[3] * sc1 + sh0 + sh1);
    size_t o = (((size_t)b * 256 + oc) * 64 + d1) * 64 + 16 * wv + 4 * h;
    *(ushort4*)&out[o] = vo;
  }
}

// ---------------- pools ----------------
__global__ void __launch_bounds__(256) pool16_kernel(
    const ushort* __restrict__ in, ushort* __restrict__ out, int total) {
  int idx = blockIdx.x * 256 + threadIdx.x;
  if (idx >= total) return;
  int j = idx & 31, i = (idx >> 5) & 31, bc = idx >> 10;
  const ushort* p = in + (size_t)bc * 4096 + i * 128 + j * 2;
  out[idx] = f2h(0.25f * (h2f(p[0]) + h2f(p[1]) + h2f(p[64]) + h2f(p[65])));
}

__global__ void __launch_bounds__(256) poolx_kernel(
    const float* __restrict__ in, ushort* __restrict__ out, int total) {
  int idx = blockIdx.x * 256 + threadIdx.x;
  if (idx >= total) return;
  int j = idx & 31, i = (idx >> 5) & 31, bc = idx >> 10;
  const float* p = in + (size_t)bc * 4096 + i * 128 + j * 2;
  out[idx] = f2h(0.25f * (p[0] + p[1] + p[64] + p[65]));
}

extern "C" void kernel_launch(void* const* d_in, const int* in_sizes, int n_in,
                              void* d_out, int out_size, void* d_ws, size_t ws_size,
                              hipStream_t stream) {
  const float* x         = (const float*)d_in[0];
  const float* latent    = (const float*)d_in[1];
  const float* w_in      = (const float*)d_in[2];
  const float* bn_in     = (const float*)d_in[3];
  const float* lin_in    = (const float*)d_in[4];
  const float* alpha_in  = (const float*)d_in[5];
  const float* a0_wqkv   = (const float*)d_in[6];
  const float* a0_bn_qkv = (const float*)d_in[7];
  const float* a0_bn_sim = (const float*)d_in[8];
  const float* a0_bn_out = (const float*)d_in[9];
  const float* a0_rel    = (const float*)d_in[10];
  const float* a1_wqkv   = (const float*)d_in[11];
  const float* a1_bn_qkv = (const float*)d_in[12];
  const float* a1_bn_sim = (const float*)d_in[13];
  const float* a1_bn_out = (const float*)d_in[14];
  const float* a1_rel    = (const float*)d_in[15];
  const float* w_out     = (const float*)d_in[16];
  const float* bn_outp   = (const float*)d_in[17];
  const float* lin_out   = (const float*)d_in[18];
  const float* w_res     = (const float*)d_in[19];
  const float* alpha_fin = (const float*)d_in[20];

  float* ws = (float*)d_ws;
  float* sb_in  = ws;                         // 2048 f
  float* sb_out = ws + 2048;                  // 2048 f
  ushort* w16   = (ushort*)(ws + 4096);       // 393216 u16
  ushort* x16   = w16 + 393216;               // 2097152 u16
  ushort* t0    = x16 + 2097152;              // 4194304 u16
  ushort* qkvb  = t0 + 4194304;               // 8388608 u16
  ushort* pool_o = qkvb + 8388608;            // 1048576 u16
  ushort* pool_x = pool_o + 1048576;          // 524288 u16
  float* resb   = (float*)(pool_x + 524288);  // 1048576 f

  ushort* w_in16  = w16;
  ushort* a0w16   = w16 + 32768;
  ushort* a1w16   = w16 + 163840;
  ushort* w_out16 = w16 + 294912;
  ushort* w_res16 = w16 + 360448;

  prep_kernel<<<1552, 256, 0, stream>>>(w_in, a0_wqkv, a1_wqkv, w_out, w_res,
                                        latent, lin_in, lin_out, w16, sb_in, sb_out);
  cvt_kernel<<<2048, 256, 0, stream>>>(x, x16, 524288);

  // conv_in + cbn + prelu -> t0 (f16, std layout)
  conv_mfma_kernel<11, false><<<dim3(32, 2, 4), 256, 0, stream>>>(
      x16, w_in16, t0, 128, 256, 4096, bn_in, sb_in, alpha_in, nullptr);

  // axial 0 over H
  conv_mfma_kernel<1, false><<<dim3(32, 4, 4), 256, 0, stream>>>(
      t0, a0w16, qkvb, 256, 512, 4096, a0_bn_qkv, nullptr, nullptr, nullptr);
  axial_attn_kernel<<<4096, 256, 0, stream>>>(
      qkvb, a0_rel, a0_bn_sim, a0_bn_out, t0);

  // axial 1 over W
  conv_mfma_kernel<1, false><<<dim3(32, 4, 4), 256, 0, stream>>>(
      t0, a1w16, qkvb, 256, 512, 4096, a1_bn_qkv, nullptr, nullptr, nullptr);
  axial_attn_kernel<<<4096, 256, 0, stream>>>(
      qkvb, a1_rel, a1_bn_sim, a1_bn_out, t0);

  // pools
  pool16_kernel<<<4096, 256, 0, stream>>>(t0, pool_o, 1048576);
  poolx_kernel<<<2048, 256, 0, stream>>>(x, pool_x, 524288);

  // residual conv (f32 out)
  conv_mfma_kernel<0, true><<<dim3(8, 2, 4), 256, 0, stream>>>(
      pool_x, w_res16, resb, 128, 256, 1024, nullptr, nullptr, nullptr, nullptr);

  // final conv + cbn + add res + prelu -> d_out (f32)
  conv_mfma_kernel<15, true><<<dim3(8, 2, 4), 256, 0, stream>>>(
      pool_o, w_out16, d_out, 256, 256, 1024, bn_outp, sb_out, alpha_fin, resb);
}

// Round 6
// 282.694 us; speedup vs baseline: 1.8718x; 1.0103x over previous
//
#include <hip/hip_runtime.h>
#include <hip/hip_bf16.h>

#define EPS_F 1e-5f

typedef __attribute__((ext_vector_type(8))) _Float16 f16x8;
typedef __attribute__((ext_vector_type(4))) float f32x4;

union U16x8 { ushort u[8]; f16x8 v; };

static __device__ inline ushort f2h(float f) {
  _Float16 h = (_Float16)f;
  return __builtin_bit_cast(ushort, h);
}
static __device__ inline float h2f(ushort u) {
  return (float)__builtin_bit_cast(_Float16, u);
}

// ---------------- prep: weights -> f16, sb = latent @ lin^T ----------------
__global__ void __launch_bounds__(256) prep_kernel(
    const float* __restrict__ w_in, const float* __restrict__ a0w,
    const float* __restrict__ a1w, const float* __restrict__ w_out,
    const float* __restrict__ w_res,
    const float* __restrict__ latent, const float* __restrict__ lin_in,
    const float* __restrict__ lin_out,
    ushort* __restrict__ w16, float* __restrict__ sb_in, float* __restrict__ sb_out) {
  int idx = blockIdx.x * 256 + threadIdx.x;
  if (idx < 393216) {
    const float* src; int off;
    if (idx < 32768)       { src = w_in;  off = 0; }
    else if (idx < 163840) { src = a0w;   off = 32768; }
    else if (idx < 294912) { src = a1w;   off = 163840; }
    else if (idx < 360448) { src = w_out; off = 294912; }
    else                   { src = w_res; off = 360448; }
    w16[idx] = f2h(src[idx - off]);
  } else {
    int r = idx - 393216;
    int which = r >> 11;
    int rr = r & 2047;
    int b = rr >> 9, k = rr & 511;
    const float* lin = which ? lin_out : lin_in;
    const float* lv = latent + b * 256;
    const float* lr = lin + k * 256;
    float acc = 0.f;
#pragma unroll 8
    for (int l = 0; l < 256; ++l) acc += lv[l] * lr[l];
    (which ? sb_out : sb_in)[b * 512 + k] = acc;
  }
}

// ---------------- cvt: f32 -> f16 ----------------
__global__ void __launch_bounds__(256) cvt_kernel(
    const float* __restrict__ in, ushort* __restrict__ out, int n4) {
  int idx = blockIdx.x * 256 + threadIdx.x;
  if (idx >= n4) return;
  float4 v = ((const float4*)in)[idx];
  ushort4 o;
  o.x = f2h(v.x); o.y = f2h(v.y); o.z = f2h(v.z); o.w = f2h(v.w);
  ((ushort4*)out)[idx] = o;
}

// ---------------- spatial 64x64 transpose per (b,ch) plane, f16 ----------------
__global__ void __launch_bounds__(256) transpose_kernel(
    const ushort* __restrict__ in, ushort* __restrict__ out) {
  __shared__ ushort T[64][72];
  int plane = blockIdx.x;
  const ushort* src = in + (size_t)plane * 4096;
  ushort* dst = out + (size_t)plane * 4096;
  int t = threadIdx.x;
  int r = t >> 2, s = t & 3;
  *(f16x8*)&T[r][16 * s]     = *(const f16x8*)&src[r * 64 + 16 * s];
  *(f16x8*)&T[r][16 * s + 8] = *(const f16x8*)&src[r * 64 + 16 * s + 8];
  __syncthreads();
  U16x8 o1, o2;
#pragma unroll
  for (int e = 0; e < 8; ++e) {
    o1.u[e] = T[16 * s + e][r];
    o2.u[e] = T[16 * s + 8 + e][r];
  }
  *(f16x8*)&dst[r * 64 + 16 * s]     = o1.v;
  *(f16x8*)&dst[r * 64 + 16 * s + 8] = o2.v;
}

// ---------------- MFMA f16 conv1x1 (BM=64 oc x BN=128 p, BK=32) ----------------
// MODE bits: 1 = bn affine, 2 = cbn, 4 = add addbuf(f32), 8 = prelu
template <int MODE, bool OUT32>
__global__ void __launch_bounds__(256) conv_mfma_kernel(
    const ushort* __restrict__ X, const ushort* __restrict__ W16,
    void* __restrict__ Yv, int Cin, int Cout, int P,
    const float* __restrict__ bn, const float* __restrict__ sb,
    const float* __restrict__ alpha, const float* __restrict__ addbuf) {
  const int tid = threadIdx.x;
  const int p0 = blockIdx.x * 128;
  const int o0 = blockIdx.y * 64;
  const int b  = blockIdx.z;
  const int lane = tid & 63;
  const int wv = tid >> 6;
  const int m = lane & 15, h = lane >> 4;
  const int wr = wv >> 1, wc = wv & 1;

  __shared__ __align__(16) char smem[17408];
  ushort (*Xs)[40] = (ushort(*)[40])smem;             // [128][40]
  ushort (*Ws)[40] = (ushort(*)[40])(smem + 10240);   // [64][40]
  ushort (*Es)[136] = (ushort(*)[136])smem;           // epilogue overlay [64][136]

  f32x4 acc[2][4];
#pragma unroll
  for (int i = 0; i < 2; ++i)
#pragma unroll
    for (int j = 0; j < 4; ++j) acc[i][j] = (f32x4){0.f, 0.f, 0.f, 0.f};

  const ushort* Xb = X + (size_t)b * Cin * P;
  const int s = tid & 15;
  const int cb = tid >> 4;

  for (int k0 = 0; k0 < Cin; k0 += 32) {
    __syncthreads();
#pragma unroll
    for (int half = 0; half < 2; ++half) {
      int c = cb + 16 * half;
      U16x8 xv;
      xv.v = *(const f16x8*)&Xb[(size_t)(k0 + c) * P + p0 + 8 * s];
#pragma unroll
      for (int t = 0; t < 8; ++t) {
        int j = (t + s) & 7;
        Xs[8 * s + j][c] = xv.u[j];
      }
    }
    {
      int oc = tid >> 2, sg = (tid & 3) * 8;
      *(f16x8*)&Ws[oc][sg] = *(const f16x8*)&W16[(size_t)(o0 + oc) * Cin + k0 + sg];
    }
    __syncthreads();
    f16x8 af[2], bf[4];
#pragma unroll
    for (int t = 0; t < 2; ++t) af[t] = *(const f16x8*)&Ws[32 * wr + 16 * t + m][8 * h];
#pragma unroll
    for (int t = 0; t < 4; ++t) bf[t] = *(const f16x8*)&Xs[64 * wc + 16 * t + m][8 * h];
#pragma unroll
    for (int ta = 0; ta < 2; ++ta)
#pragma unroll
      for (int tb = 0; tb < 4; ++tb)
        acc[ta][tb] = __builtin_amdgcn_mfma_f32_16x16x32_f16(af[ta], bf[tb], acc[ta][tb], 0, 0, 0);
  }

  float scl[2][4], shf[2][4];
#pragma unroll
  for (int ta = 0; ta < 2; ++ta)
#pragma unroll
    for (int r = 0; r < 4; ++r) {
      int oc = o0 + 32 * wr + 16 * ta + 4 * h + r;
      float scale = 1.f, shift = 0.f;
      if (MODE & 1) {
        float sc = bn[oc] * rsqrtf(bn[3 * Cout + oc] + EPS_F);
        scale = sc;
        shift = bn[Cout + oc] - bn[2 * Cout + oc] * sc;
      }
      if (MODE & 2) {
        float ss = sb[b * 2 * Cout + oc];
        float bb = sb[b * 2 * Cout + Cout + oc];
        scale *= ss;
        shift = shift * ss + bb;
      }
      scl[ta][r] = scale; shf[ta][r] = shift;
    }
  float al = (MODE & 8) ? *alpha : 0.f;

  if (OUT32) {
    float* Y32 = (float*)Yv;
#pragma unroll
    for (int ta = 0; ta < 2; ++ta)
#pragma unroll
      for (int tb = 0; tb < 4; ++tb)
#pragma unroll
        for (int r = 0; r < 4; ++r) {
          int oc = o0 + 32 * wr + 16 * ta + 4 * h + r;
          int p  = p0 + 64 * wc + 16 * tb + m;
          float v = acc[ta][tb][r] * scl[ta][r] + shf[ta][r];
          size_t o = ((size_t)b * Cout + oc) * P + p;
          if (MODE & 4) v += addbuf[o];
          if (MODE & 8) v = v > 0.f ? v : al * v;
          Y32[o] = v;
        }
  } else {
    ushort* Y16 = (ushort*)Yv;
    __syncthreads();
#pragma unroll
    for (int ta = 0; ta < 2; ++ta)
#pragma unroll
      for (int tb = 0; tb < 4; ++tb)
#pragma unroll
        for (int r = 0; r < 4; ++r) {
          float v = acc[ta][tb][r] * scl[ta][r] + shf[ta][r];
          if (MODE & 8) v = v > 0.f ? v : al * v;
          Es[32 * wr + 16 * ta + 4 * h + r][64 * wc + 16 * tb + m] = f2h(v);
        }
    __syncthreads();
    int row = tid >> 2, q = tid & 3;
    size_t gofs = ((size_t)b * Cout + o0 + row) * P + p0 + 32 * q;
#pragma unroll
    for (int u = 0; u < 4; ++u)
      *(f16x8*)&Y16[gofs + 8 * u] = *(const f16x8*)&Es[row][32 * q + 8 * u];
  }
}

// ---------------- axial attention, MFMA f16, transposed input ----------------
// Input qkvT layout: (b, ch, d1, i) — i (attended dim) contiguous.
// Output: out[((b*256+oc)*64 + d1)*64 + i] (i contiguous).
__global__ void __launch_bounds__(256) axial_attn_kernel(
    const ushort* __restrict__ qkvT, const float* __restrict__ rel,
    const float* __restrict__ bn_sim, const float* __restrict__ bn_out,
    ushort* __restrict__ out) {
  const int tid = threadIdx.x;
  int lin = blockIdx.x;                       // bijective XCD swizzle
  int wg = ((lin & 7) << 9) + (lin >> 3);
  const int g  = wg >> 8;
  const int bd = wg & 255;
  const int b  = bd >> 6;
  const int d1 = bd & 63;

  __shared__ __align__(16) char smem[40704];
  // qs: [16][64] u16 @0 | Gq: [127][64] swz @2048 | Gk: @18304
  // A2: [64][136] @2048 (overlay after P4) | VC: [16][64] swz @34560 | RV: [16][128] swz @36608
#define QSA(c, i)  (smem + (c) * 128 + (i) * 2)
#define GQA(d, k)  (smem + 2048  + ((((d) * 128 + (k) * 2)) ^ (((d) & 7) << 3)))
#define GKA(d, k)  (smem + 18304 + ((((d) * 128 + (k) * 2)) ^ (((d) & 7) << 3)))
#define VCA(c, j)  (smem + 34560 + ((((c) * 128 + (j) * 2)) ^ (((c) & 7) << 4)))
#define RVA(c, d)  (smem + 36608 + ((((c) * 256 + (d) * 2)) ^ (((c) & 7) << 4)))
#define A2A(i, d)  (smem + 2048 + (i) * 272 + (d) * 2)

  const int lane = tid & 63;
  const int wv   = tid >> 6;
  const int m    = lane & 15;
  const int h    = lane >> 4;

  // ---- P0: coalesced loads ----
  {
    const ushort* src = qkvT + ((size_t)b * 512 + g * 32) * 4096 + d1 * 64;
    int c = tid >> 3, i0 = (tid & 7) * 8;
    f16x8 v = *(const f16x8*)&src[(size_t)c * 4096 + i0];
    if (c < 16) *(f16x8*)QSA(c, i0) = v;
    else        *(f16x8*)VCA(c - 16, i0) = v;
#pragma unroll
    for (int n = 0; n < 8; ++n) {
      int e = tid + n * 256;
      int cc = e >> 7, d = e & 127;
      *(ushort*)RVA(cc, d) = (d < 127) ? f2h(rel[(16 + cc) * 127 + d]) : (ushort)0;
    }
  }
  __syncthreads();

  // ---- P1: G_q / G_k ----
  {
    const int wu = __builtin_amdgcn_readfirstlane(wv);
    float qr[8], kr[8];
#pragma unroll
    for (int c = 0; c < 8; ++c) {
      qr[c] = h2f(*(ushort*)QSA(c, lane));
      kr[c] = h2f(*(ushort*)QSA(8 + c, lane));
    }
#pragma unroll
    for (int dq = 0; dq < 8; ++dq) {
      int d0 = 4 * wu + 16 * dq;
      float aq[4] = {0.f, 0.f, 0.f, 0.f}, ak[4] = {0.f, 0.f, 0.f, 0.f};
#pragma unroll
      for (int c = 0; c < 8; ++c) {
        const float* rq = rel + c * 127 + d0;
        const float* rk = rel + (8 + c) * 127 + d0;
#pragma unroll
        for (int di = 0; di < 4; ++di) {
          aq[di] += qr[c] * rq[di];
          ak[di] += kr[c] * rk[di];
        }
      }
#pragma unroll
      for (int di = 0; di < 4; ++di) {
        int d = d0 + di;
        if (d < 127) {
          *(ushort*)GQA(d, lane) = f2h(aq[di]);
          *(ushort*)GKA(d, lane) = f2h(ak[di]);
        }
      }
    }
  }
  __syncthreads();

  // ---- P2: sim = s_qk*(q_emb^T k_emb) + s_qe*q_emb + s_ke*k_emb + sh ----
  f32x4 acc[4];
#pragma unroll
  for (int tj = 0; tj < 4; ++tj) acc[tj] = (f32x4){0.f, 0.f, 0.f, 0.f};
  {
    U16x8 afr[2];
    const int ia = 16 * wv + m;
#pragma unroll
    for (int ks = 0; ks < 2; ++ks)
#pragma unroll
      for (int e = 0; e < 8; ++e) {
        int kk = 32 * ks + 8 * h + e;
        afr[ks].u[e] = *(ushort*)GQA(kk - ia + 63, kk);
      }
#pragma unroll
    for (int tj = 0; tj < 4; ++tj) {
      int j = 16 * tj + m;
#pragma unroll
      for (int ks = 0; ks < 2; ++ks) {
        U16x8 bfr;
#pragma unroll
        for (int e = 0; e < 8; ++e) {
          int kk = 32 * ks + 8 * h + e;
          bfr.u[e] = *(ushort*)GKA(kk - j + 63, kk);
        }
        acc[tj] = __builtin_amdgcn_mfma_f32_16x16x32_f16(afr[ks].v, bfr.v, acc[tj], 0, 0, 0);
      }
    }
  }

  float s_qk = bn_sim[g]      * rsqrtf(bn_sim[144 + g] + EPS_F);
  float s_qe = bn_sim[16 + g] * rsqrtf(bn_sim[160 + g] + EPS_F);
  float s_ke = bn_sim[32 + g] * rsqrtf(bn_sim[176 + g] + EPS_F);
  float sh   = (bn_sim[48 + g] - bn_sim[96 + g]  * s_qk)
             + (bn_sim[64 + g] - bn_sim[112 + g] * s_qe)
             + (bn_sim[80 + g] - bn_sim[128 + g] * s_ke);

  const int ib = 16 * wv + 4 * h;
  float sv[4][4];
#pragma unroll
  for (int tj = 0; tj < 4; ++tj) {
    int j = 16 * tj + m;
#pragma unroll
    for (int r = 0; r < 4; ++r) {
      int i = ib + r;
      int d = i - j + 63;
      float qe = h2f(*(ushort*)GQA(d, i));
      float ke = h2f(*(ushort*)GKA(d, i));
      sv[tj][r] = acc[tj][r] * s_qk + qe * s_qe + ke * s_ke + sh;
    }
  }

  // ---- P3: softmax over j ----
  float p[4][4];
  {
    float mx[4];
#pragma unroll
    for (int r = 0; r < 4; ++r) {
      float v = fmaxf(fmaxf(sv[0][r], sv[1][r]), fmaxf(sv[2][r], sv[3][r]));
      v = fmaxf(v, __shfl_xor(v, 1));
      v = fmaxf(v, __shfl_xor(v, 2));
      v = fmaxf(v, __shfl_xor(v, 4));
      v = fmaxf(v, __shfl_xor(v, 8));
      mx[r] = v;
    }
#pragma unroll
    for (int r = 0; r < 4; ++r) {
      float ssum = 0.f;
#pragma unroll
      for (int tj = 0; tj < 4; ++tj) {
        p[tj][r] = __expf(sv[tj][r] - mx[r]);
        ssum += p[tj][r];
      }
      ssum += __shfl_xor(ssum, 1);
      ssum += __shfl_xor(ssum, 2);
      ssum += __shfl_xor(ssum, 4);
      ssum += __shfl_xor(ssum, 8);
      float inv = 1.f / ssum;
#pragma unroll
      for (int tj = 0; tj < 4; ++tj) p[tj][r] *= inv;
    }
  }

  // ---- P4: zero A2 (overlays dead G), scatter P ----
  __syncthreads();
  {
    uint4 z = make_uint4(0u, 0u, 0u, 0u);
    for (int u2 = tid; u2 < 1088; u2 += 256) ((uint4*)(smem + 2048))[u2] = z;
  }
  __syncthreads();
#pragma unroll
  for (int tj = 0; tj < 4; ++tj) {
    int j = 16 * tj + m;
#pragma unroll
    for (int r = 0; r < 4; ++r) {
      int i = ib + r;
      *(ushort*)A2A(i, i - j + 63) = f2h(p[tj][r]);
    }
  }

  // ---- P5: att / att_e (wave reads only its own rows) ----
  f32x4 accA = (f32x4){0.f, 0.f, 0.f, 0.f};
  f32x4 accE = (f32x4){0.f, 0.f, 0.f, 0.f};
  {
    const int ia = 16 * wv + m;
#pragma unroll
    for (int ks = 0; ks < 2; ++ks) {
      U16x8 pa;
#pragma unroll
      for (int e = 0; e < 8; ++e) {
        int j = 32 * ks + 8 * h + e;
        pa.u[e] = *(ushort*)A2A(ia, ia - j + 63);
      }
      f16x8 vb = *(const f16x8*)VCA(m, 32 * ks + 8 * h);
      accA = __builtin_amdgcn_mfma_f32_16x16x32_f16(pa.v, vb, accA, 0, 0, 0);
    }
#pragma unroll
    for (int ks = 0; ks < 4; ++ks) {
      f16x8 pe = *(const f16x8*)A2A(ia, 32 * ks + 8 * h);
      f16x8 rv = *(const f16x8*)RVA(m, 32 * ks + 8 * h);
      accE = __builtin_amdgcn_mfma_f32_16x16x32_f16(pe, rv, accE, 0, 0, 0);
    }
  }

  // ---- P6: fold bn_out, f16 write ----
  {
    int oc = g * 16 + m;
    int c0 = 2 * oc, c1 = c0 + 1;
    float sc0 = bn_out[c0] * rsqrtf(bn_out[1536 + c0] + EPS_F);
    float sh0 = bn_out[512 + c0] - bn_out[1024 + c0] * sc0;
    float sc1 = bn_out[c1] * rsqrtf(bn_out[1536 + c1] + EPS_F);
    float sh1 = bn_out[512 + c1] - bn_out[1024 + c1] * sc1;
    ushort4 vo;
    vo.x = f2h(accA[0] * sc0 + accE[0] * sc1 + sh0 + sh1);
    vo.y = f2h(accA[1] * sc0 + accE[1] * sc1 + sh0 + sh1);
    vo.z = f2h(accA[2] * sc0 + accE[2] * sc1 + sh0 + sh1);
    vo.w = f2h(accA[3] * sc0 + accE[3] * sc1 + sh0 + sh1);
    size_t o = (((size_t)b * 256 + oc) * 64 + d1) * 64 + 16 * wv + 4 * h;
    *(ushort4*)&out[o] = vo;
  }
#undef QSA
#undef GQA
#undef GKA
#undef VCA
#undef RVA
#undef A2A
}

// ---------------- pools ----------------
__global__ void __launch_bounds__(256) pool16_kernel(
    const ushort* __restrict__ in, ushort* __restrict__ out, int total) {
  int idx = blockIdx.x * 256 + threadIdx.x;
  if (idx >= total) return;
  int j = idx & 31, i = (idx >> 5) & 31, bc = idx >> 10;
  const ushort* p = in + (size_t)bc * 4096 + i * 128 + j * 2;
  out[idx] = f2h(0.25f * (h2f(p[0]) + h2f(p[1]) + h2f(p[64]) + h2f(p[65])));
}

__global__ void __launch_bounds__(256) poolx_kernel(
    const float* __restrict__ in, ushort* __restrict__ out, int total) {
  int idx = blockIdx.x * 256 + threadIdx.x;
  if (idx >= total) return;
  int j = idx & 31, i = (idx >> 5) & 31, bc = idx >> 10;
  const float* p = in + (size_t)bc * 4096 + i * 128 + j * 2;
  out[idx] = f2h(0.25f * (p[0] + p[1] + p[64] + p[65]));
}

extern "C" void kernel_launch(void* const* d_in, const int* in_sizes, int n_in,
                              void* d_out, int out_size, void* d_ws, size_t ws_size,
                              hipStream_t stream) {
  const float* x         = (const float*)d_in[0];
  const float* latent    = (const float*)d_in[1];
  const float* w_in      = (const float*)d_in[2];
  const float* bn_in     = (const float*)d_in[3];
  const float* lin_in    = (const float*)d_in[4];
  const float* alpha_in  = (const float*)d_in[5];
  const float* a0_wqkv   = (const float*)d_in[6];
  const float* a0_bn_qkv = (const float*)d_in[7];
  const float* a0_bn_sim = (const float*)d_in[8];
  const float* a0_bn_out = (const float*)d_in[9];
  const float* a0_rel    = (const float*)d_in[10];
  const float* a1_wqkv   = (const float*)d_in[11];
  const float* a1_bn_qkv = (const float*)d_in[12];
  const float* a1_bn_sim = (const float*)d_in[13];
  const float* a1_bn_out = (const float*)d_in[14];
  const float* a1_rel    = (const float*)d_in[15];
  const float* w_out     = (const float*)d_in[16];
  const float* bn_outp   = (const float*)d_in[17];
  const float* lin_out   = (const float*)d_in[18];
  const float* w_res     = (const float*)d_in[19];
  const float* alpha_fin = (const float*)d_in[20];

  float* ws = (float*)d_ws;
  float* sb_in  = ws;                          // 2048 f
  float* sb_out = ws + 2048;                   // 2048 f
  ushort* w16   = (ushort*)(ws + 4096);        // 393216 u16
  ushort* x16   = w16 + 393216;                // 2097152 u16
  ushort* t0    = x16 + 2097152;               // 4194304 u16
  ushort* qkvb  = t0 + 4194304;                // 8388608 u16
  ushort* qkvT  = qkvb + 8388608;              // 8388608 u16
  ushort* pool_o = qkvT + 8388608;             // 1048576 u16
  ushort* pool_x = pool_o + 1048576;           // 524288 u16
  float* resb   = (float*)(pool_x + 524288);   // 1048576 f

  ushort* w_in16  = w16;
  ushort* a0w16   = w16 + 32768;
  ushort* a1w16   = w16 + 163840;
  ushort* w_out16 = w16 + 294912;
  ushort* w_res16 = w16 + 360448;

  prep_kernel<<<1552, 256, 0, stream>>>(w_in, a0_wqkv, a1_wqkv, w_out, w_res,
                                        latent, lin_in, lin_out, w16, sb_in, sb_out);
  cvt_kernel<<<2048, 256, 0, stream>>>(x, x16, 524288);

  // conv_in + cbn + prelu -> t0 (f16, std (b,c,h,w))
  conv_mfma_kernel<11, false><<<dim3(32, 4, 4), 256, 0, stream>>>(
      x16, w_in16, t0, 128, 256, 4096, bn_in, sb_in, alpha_in, nullptr);

  // axial 0 over H: conv -> transpose -> attn (out (b,c,w,h))
  conv_mfma_kernel<1, false><<<dim3(32, 8, 4), 256, 0, stream>>>(
      t0, a0w16, qkvb, 256, 512, 4096, a0_bn_qkv, nullptr, nullptr, nullptr);
  transpose_kernel<<<2048, 256, 0, stream>>>(qkvb, qkvT);
  axial_attn_kernel<<<4096, 256, 0, stream>>>(
      qkvT, a0_rel, a0_bn_sim, a0_bn_out, t0);

  // axial 1 over W: conv -> transpose -> attn (out (b,c,h,w) std)
  conv_mfma_kernel<1, false><<<dim3(32, 8, 4), 256, 0, stream>>>(
      t0, a1w16, qkvb, 256, 512, 4096, a1_bn_qkv, nullptr, nullptr, nullptr);
  transpose_kernel<<<2048, 256, 0, stream>>>(qkvb, qkvT);
  axial_attn_kernel<<<4096, 256, 0, stream>>>(
      qkvT, a1_rel, a1_bn_sim, a1_bn_out, t0);

  // pools
  pool16_kernel<<<4096, 256, 0, stream>>>(t0, pool_o, 1048576);
  poolx_kernel<<<2048, 256, 0, stream>>>(x, pool_x, 524288);

  // residual conv (f32 out)
  conv_mfma_kernel<0, true><<<dim3(8, 4, 4), 256, 0, stream>>>(
      pool_x, w_res16, resb, 128, 256, 1024, nullptr, nullptr, nullptr, nullptr);

  // final conv + cbn + add res + prelu -> d_out (f32)
  conv_mfma_kernel<15, true><<<dim3(8, 4, 4), 256, 0, stream>>>(
      pool_o, w_out16, d_out, 256, 256, 1024, bn_outp, sb_out, alpha_fin, resb);
}

// Round 7
// 277.460 us; speedup vs baseline: 1.9071x; 1.0189x over previous
//
#include <hip/hip_runtime.h>
#include <hip/hip_bf16.h>

#define EPS_F 1e-5f

typedef __attribute__((ext_vector_type(8))) _Float16 f16x8;
typedef __attribute__((ext_vector_type(4))) _Float16 f16x4;
typedef __attribute__((ext_vector_type(4))) float f32x4;

union U16x8 { ushort u[8]; f16x8 v; };

static __device__ inline ushort f2h(float f) {
  _Float16 h = (_Float16)f;
  return __builtin_bit_cast(ushort, h);
}
static __device__ inline float h2f(ushort u) {
  return (float)__builtin_bit_cast(_Float16, u);
}

// ---------------- prep: weights+rel -> f16, sb = latent @ lin^T ----------------
__global__ void __launch_bounds__(256) prep_kernel(
    const float* __restrict__ w_in, const float* __restrict__ a0w,
    const float* __restrict__ a1w, const float* __restrict__ w_out,
    const float* __restrict__ w_res,
    const float* __restrict__ latent, const float* __restrict__ lin_in,
    const float* __restrict__ lin_out,
    const float* __restrict__ a0_rel, const float* __restrict__ a1_rel,
    ushort* __restrict__ w16, ushort* __restrict__ rel16,
    float* __restrict__ sb_in, float* __restrict__ sb_out) {
  int idx = blockIdx.x * 256 + threadIdx.x;
  if (idx < 393216) {
    const float* src; int off;
    if (idx < 32768)       { src = w_in;  off = 0; }
    else if (idx < 163840) { src = a0w;   off = 32768; }
    else if (idx < 294912) { src = a1w;   off = 163840; }
    else if (idx < 360448) { src = w_out; off = 294912; }
    else                   { src = w_res; off = 360448; }
    w16[idx] = f2h(src[idx - off]);
  } else if (idx < 397312) {
    int r = idx - 393216;
    int which = r >> 11;
    int rr = r & 2047;
    int b = rr >> 9, k = rr & 511;
    const float* lin = which ? lin_out : lin_in;
    const float* lv = latent + b * 256;
    const float* lr = lin + k * 256;
    float acc = 0.f;
#pragma unroll 8
    for (int l = 0; l < 256; ++l) acc += lv[l] * lr[l];
    (which ? sb_out : sb_in)[b * 512 + k] = acc;
  } else if (idx < 405440) {
    int r = idx - 397312;          // 0..8127
    int which = r >= 4064;
    int e = which ? r - 4064 : r;  // 0..4063
    rel16[which * 4064 + e] = f2h((which ? a1_rel : a0_rel)[e]);
  }
}

// ---------------- cvt: f32 -> f16 ----------------
__global__ void __launch_bounds__(256) cvt_kernel(
    const float* __restrict__ in, ushort* __restrict__ out, int n4) {
  int idx = blockIdx.x * 256 + threadIdx.x;
  if (idx >= n4) return;
  float4 v = ((const float4*)in)[idx];
  ushort4 o;
  o.x = f2h(v.x); o.y = f2h(v.y); o.z = f2h(v.z); o.w = f2h(v.w);
  ((ushort4*)out)[idx] = o;
}

// ---------------- spatial 64x64 transpose per (b,ch) plane, f16 ----------------
__global__ void __launch_bounds__(256) transpose_kernel(
    const ushort* __restrict__ in, ushort* __restrict__ out) {
  __shared__ ushort T[64][72];
  int plane = blockIdx.x;
  const ushort* src = in + (size_t)plane * 4096;
  ushort* dst = out + (size_t)plane * 4096;
  int t = threadIdx.x;
  int r = t >> 2, s = t & 3;
  *(f16x8*)&T[r][16 * s]     = *(const f16x8*)&src[r * 64 + 16 * s];
  *(f16x8*)&T[r][16 * s + 8] = *(const f16x8*)&src[r * 64 + 16 * s + 8];
  __syncthreads();
  U16x8 o1, o2;
#pragma unroll
  for (int e = 0; e < 8; ++e) {
    o1.u[e] = T[16 * s + e][r];
    o2.u[e] = T[16 * s + 8 + e][r];
  }
  *(f16x8*)&dst[r * 64 + 16 * s]     = o1.v;
  *(f16x8*)&dst[r * 64 + 16 * s + 8] = o2.v;
}

// ---------------- MFMA f16 conv1x1 (BM=64 oc x BN=128 p, BK=32) ----------------
// MODE bits: 1 = bn affine, 2 = cbn, 4 = add addbuf(f32), 8 = prelu
template <int MODE, bool OUT32>
__global__ void __launch_bounds__(256) conv_mfma_kernel(
    const ushort* __restrict__ X, const ushort* __restrict__ W16,
    void* __restrict__ Yv, int Cin, int Cout, int P,
    const float* __restrict__ bn, const float* __restrict__ sb,
    const float* __restrict__ alpha, const float* __restrict__ addbuf) {
  const int tid = threadIdx.x;
  const int p0 = blockIdx.x * 128;
  const int o0 = blockIdx.y * 64;
  const int b  = blockIdx.z;
  const int lane = tid & 63;
  const int wv = tid >> 6;
  const int m = lane & 15, h = lane >> 4;
  const int wr = wv >> 1, wc = wv & 1;

  __shared__ __align__(16) char smem[17408];
  ushort (*Xs)[40] = (ushort(*)[40])smem;             // [128][40]
  ushort (*Ws)[40] = (ushort(*)[40])(smem + 10240);   // [64][40]
  ushort (*Es)[136] = (ushort(*)[136])smem;           // epilogue overlay [64][136]

  f32x4 acc[2][4];
#pragma unroll
  for (int i = 0; i < 2; ++i)
#pragma unroll
    for (int j = 0; j < 4; ++j) acc[i][j] = (f32x4){0.f, 0.f, 0.f, 0.f};

  const ushort* Xb = X + (size_t)b * Cin * P;
  const int s = tid & 15;
  const int cb = tid >> 4;

  for (int k0 = 0; k0 < Cin; k0 += 32) {
    __syncthreads();
#pragma unroll
    for (int half = 0; half < 2; ++half) {
      int c = cb + 16 * half;
      U16x8 xv;
      xv.v = *(const f16x8*)&Xb[(size_t)(k0 + c) * P + p0 + 8 * s];
#pragma unroll
      for (int t = 0; t < 8; ++t) {
        int j = (t + s) & 7;
        Xs[8 * s + j][c] = xv.u[j];
      }
    }
    {
      int oc = tid >> 2, sg = (tid & 3) * 8;
      *(f16x8*)&Ws[oc][sg] = *(const f16x8*)&W16[(size_t)(o0 + oc) * Cin + k0 + sg];
    }
    __syncthreads();
    f16x8 af[2], bf[4];
#pragma unroll
    for (int t = 0; t < 2; ++t) af[t] = *(const f16x8*)&Ws[32 * wr + 16 * t + m][8 * h];
#pragma unroll
    for (int t = 0; t < 4; ++t) bf[t] = *(const f16x8*)&Xs[64 * wc + 16 * t + m][8 * h];
#pragma unroll
    for (int ta = 0; ta < 2; ++ta)
#pragma unroll
      for (int tb = 0; tb < 4; ++tb)
        acc[ta][tb] = __builtin_amdgcn_mfma_f32_16x16x32_f16(af[ta], bf[tb], acc[ta][tb], 0, 0, 0);
  }

  float scl[2][4], shf[2][4];
#pragma unroll
  for (int ta = 0; ta < 2; ++ta)
#pragma unroll
    for (int r = 0; r < 4; ++r) {
      int oc = o0 + 32 * wr + 16 * ta + 4 * h + r;
      float scale = 1.f, shift = 0.f;
      if (MODE & 1) {
        float sc = bn[oc] * rsqrtf(bn[3 * Cout + oc] + EPS_F);
        scale = sc;
        shift = bn[Cout + oc] - bn[2 * Cout + oc] * sc;
      }
      if (MODE & 2) {
        float ss = sb[b * 2 * Cout + oc];
        float bb = sb[b * 2 * Cout + Cout + oc];
        scale *= ss;
        shift = shift * ss + bb;
      }
      scl[ta][r] = scale; shf[ta][r] = shift;
    }
  float al = (MODE & 8) ? *alpha : 0.f;

  if (OUT32) {
    float* Y32 = (float*)Yv;
#pragma unroll
    for (int ta = 0; ta < 2; ++ta)
#pragma unroll
      for (int tb = 0; tb < 4; ++tb)
#pragma unroll
        for (int r = 0; r < 4; ++r) {
          int oc = o0 + 32 * wr + 16 * ta + 4 * h + r;
          int p  = p0 + 64 * wc + 16 * tb + m;
          float v = acc[ta][tb][r] * scl[ta][r] + shf[ta][r];
          size_t o = ((size_t)b * Cout + oc) * P + p;
          if (MODE & 4) v += addbuf[o];
          if (MODE & 8) v = v > 0.f ? v : al * v;
          Y32[o] = v;
        }
  } else {
    ushort* Y16 = (ushort*)Yv;
    __syncthreads();
#pragma unroll
    for (int ta = 0; ta < 2; ++ta)
#pragma unroll
      for (int tb = 0; tb < 4; ++tb)
#pragma unroll
        for (int r = 0; r < 4; ++r) {
          float v = acc[ta][tb][r] * scl[ta][r] + shf[ta][r];
          if (MODE & 8) v = v > 0.f ? v : al * v;
          Es[32 * wr + 16 * ta + 4 * h + r][64 * wc + 16 * tb + m] = f2h(v);
        }
    __syncthreads();
    int row = tid >> 2, q = tid & 3;
    size_t gofs = ((size_t)b * Cout + o0 + row) * P + p0 + 32 * q;
#pragma unroll
    for (int u = 0; u < 4; ++u)
      *(f16x8*)&Y16[gofs + 8 * u] = *(const f16x8*)&Es[row][32 * q + 8 * u];
  }
}

// ---------------- axial attention, all-MFMA f16 ----------------
// Input qkvT layout: (b, ch, d1, i) — i (attended dim) contiguous.
// Output: out[((b*256+oc)*64 + d1)*64 + i].
__global__ void __launch_bounds__(256) axial_attn_kernel(
    const ushort* __restrict__ qkvT, const ushort* __restrict__ rel16,
    const float* __restrict__ bn_sim, const float* __restrict__ bn_out,
    ushort* __restrict__ out) {
  const int tid = threadIdx.x;
  int lin = blockIdx.x;                       // bijective XCD swizzle
  int wg = ((lin & 7) << 9) + (lin >> 3);
  const int g  = wg >> 8;
  const int bd = wg & 255;
  const int b  = bd >> 6;
  const int d1 = bd & 63;

  __shared__ __align__(16) char smem[49152];
  // relT [128][20] @0 (c0-7 relq, c8-15 relk; row127=0)      5120
  // QT   [64][20]  @5120  (c0-7 = q, c8-15 = 0)              2560
  // KT   [64][20]  @7680  (c0-7 = 0, c8-15 = k)              2560
  // Gq   [128][64] @10240 swz                                16384
  // Gk   [128][64] @26624 swz                                16384
  // A2   [64][136] @10240 (overlays G after P2)              17408
  // VC   [16][64]  @43008 swz                                2048
  // RV   [16][128] @45056 swz                                4096
#define RTA(d, c)  (smem + (d) * 40 + (c) * 2)
#define QTA(k2, c) (smem + 5120 + (k2) * 40 + (c) * 2)
#define KTA(k2, c) (smem + 7680 + (k2) * 40 + (c) * 2)
#define GQA(d, k)  (smem + 10240 + ((((d) * 128 + (k) * 2)) ^ (((d) & 7) << 3)))
#define GKA(d, k)  (smem + 26624 + ((((d) * 128 + (k) * 2)) ^ (((d) & 7) << 3)))
#define A2A(i, d)  (smem + 10240 + (i) * 272 + (d) * 2)
#define VCA(c, j)  (smem + 43008 + ((((c) * 128 + (j) * 2)) ^ (((c) & 7) << 4)))
#define RVA(c, d)  (smem + 45056 + ((((c) * 256 + (d) * 2)) ^ (((c) & 7) << 4)))

  const int lane = tid & 63;
  const int wv   = tid >> 6;
  const int m    = lane & 15;
  const int h    = lane >> 4;

  // ---- P0a: issue qkv load early; zero QT/KT; fill relT + RV from rel16 ----
  const int c_ld = tid >> 3, i0_ld = (tid & 7) * 8;
  f16x8 vld = *(const f16x8*)&qkvT[((size_t)b * 512 + g * 32 + c_ld) * 4096 + d1 * 64 + i0_ld];
  {
    uint4 z = make_uint4(0u, 0u, 0u, 0u);
    ((uint4*)(smem + 5120))[tid] = z;                 // 256 * 16B = 4096
    if (tid < 64) ((uint4*)(smem + 5120 + 4096))[tid] = z;  // remaining 1024
#pragma unroll
    for (int n = 0; n < 16; ++n) {
      int e = tid + n * 256;
      int c = e >> 7, d = e & 127;
      ushort val = (d < 127) ? rel16[c * 127 + d] : (ushort)0;
      if (c < 16) *(ushort*)RTA(d, c) = val;
      else        *(ushort*)RVA(c - 16, d) = val;
    }
  }
  __syncthreads();

  // ---- P0b: scatter q/k into QT/KT, v into VC ----
  {
    U16x8 u; u.v = vld;
    if (c_ld < 16) {
      char* base = (c_ld < 8) ? QTA(i0_ld, c_ld) : KTA(i0_ld, c_ld);
#pragma unroll
      for (int e = 0; e < 8; ++e) *(ushort*)(base + e * 40) = u.u[e];
    } else {
      *(f16x8*)VCA(c_ld - 16, i0_ld) = vld;
    }
  }
  __syncthreads();

  // ---- P1: G_q = relT(c0-7)@QT, G_k = relT(c8-15)@KT via 16x16x16 MFMA ----
  {
#pragma unroll
    for (int t = 0; t < 2; ++t) {
      int dt = wv + 4 * t;                     // d-tile 0..7
      f16x4 ar = *(const f16x4*)RTA(16 * dt + m, 4 * h);
#pragma unroll
      for (int nt = 0; nt < 4; ++nt) {
        f16x4 bq = *(const f16x4*)QTA(16 * nt + m, 4 * h);
        f16x4 bk = *(const f16x4*)KTA(16 * nt + m, 4 * h);
        f32x4 dq = __builtin_amdgcn_mfma_f32_16x16x16f16(ar, bq, (f32x4){0.f,0.f,0.f,0.f}, 0, 0, 0);
        f32x4 dk = __builtin_amdgcn_mfma_f32_16x16x16f16(ar, bk, (f32x4){0.f,0.f,0.f,0.f}, 0, 0, 0);
#pragma unroll
        for (int r = 0; r < 4; ++r) {
          int d = 16 * dt + 4 * h + r;
          *(ushort*)GQA(d, 16 * nt + m) = f2h(dq[r]);
          *(ushort*)GKA(d, 16 * nt + m) = f2h(dk[r]);
        }
      }
    }
  }
  __syncthreads();

  // ---- P2: sim = s_qk*(q_emb^T k_emb) + s_qe*q_emb + s_ke*k_emb + sh ----
  f32x4 acc[4];
#pragma unroll
  for (int tj = 0; tj < 4; ++tj) acc[tj] = (f32x4){0.f, 0.f, 0.f, 0.f};
  {
    U16x8 afr[2];
    const int ia = 16 * wv + m;
#pragma unroll
    for (int ks = 0; ks < 2; ++ks)
#pragma unroll
      for (int e = 0; e < 8; ++e) {
        int kk = 32 * ks + 8 * h + e;
        afr[ks].u[e] = *(ushort*)GQA(kk - ia + 63, kk);
      }
#pragma unroll
    for (int tj = 0; tj < 4; ++tj) {
      int j = 16 * tj + m;
#pragma unroll
      for (int ks = 0; ks < 2; ++ks) {
        U16x8 bfr;
#pragma unroll
        for (int e = 0; e < 8; ++e) {
          int kk = 32 * ks + 8 * h + e;
          bfr.u[e] = *(ushort*)GKA(kk - j + 63, kk);
        }
        acc[tj] = __builtin_amdgcn_mfma_f32_16x16x32_f16(afr[ks].v, bfr.v, acc[tj], 0, 0, 0);
      }
    }
  }

  float s_qk = bn_sim[g]      * rsqrtf(bn_sim[144 + g] + EPS_F);
  float s_qe = bn_sim[16 + g] * rsqrtf(bn_sim[160 + g] + EPS_F);
  float s_ke = bn_sim[32 + g] * rsqrtf(bn_sim[176 + g] + EPS_F);
  float sh   = (bn_sim[48 + g] - bn_sim[96 + g]  * s_qk)
             + (bn_sim[64 + g] - bn_sim[112 + g] * s_qe)
             + (bn_sim[80 + g] - bn_sim[128 + g] * s_ke);

  const int ib = 16 * wv + 4 * h;
  float sv[4][4];
#pragma unroll
  for (int tj = 0; tj < 4; ++tj) {
    int j = 16 * tj + m;
#pragma unroll
    for (int r = 0; r < 4; ++r) {
      int i = ib + r;
      int d = i - j + 63;
      float qe = h2f(*(ushort*)GQA(d, i));
      float ke = h2f(*(ushort*)GKA(d, i));
      sv[tj][r] = acc[tj][r] * s_qk + qe * s_qe + ke * s_ke + sh;
    }
  }

  // ---- P3: softmax over j ----
  float p[4][4];
  {
    float mx[4];
#pragma unroll
    for (int r = 0; r < 4; ++r) {
      float v = fmaxf(fmaxf(sv[0][r], sv[1][r]), fmaxf(sv[2][r], sv[3][r]));
      v = fmaxf(v, __shfl_xor(v, 1));
      v = fmaxf(v, __shfl_xor(v, 2));
      v = fmaxf(v, __shfl_xor(v, 4));
      v = fmaxf(v, __shfl_xor(v, 8));
      mx[r] = v;
    }
#pragma unroll
    for (int r = 0; r < 4; ++r) {
      float ssum = 0.f;
#pragma unroll
      for (int tj = 0; tj < 4; ++tj) {
        p[tj][r] = __expf(sv[tj][r] - mx[r]);
        ssum += p[tj][r];
      }
      ssum += __shfl_xor(ssum, 1);
      ssum += __shfl_xor(ssum, 2);
      ssum += __shfl_xor(ssum, 4);
      ssum += __shfl_xor(ssum, 8);
      float inv = 1.f / ssum;
#pragma unroll
      for (int tj = 0; tj < 4; ++tj) p[tj][r] *= inv;
    }
  }

  // ---- P4: zero A2 (overlays dead G), scatter P ----
  __syncthreads();
  {
    uint4 z = make_uint4(0u, 0u, 0u, 0u);
    for (int u2 = tid; u2 < 1088; u2 += 256) ((uint4*)(smem + 10240))[u2] = z;
  }
  __syncthreads();
#pragma unroll
  for (int tj = 0; tj < 4; ++tj) {
    int j = 16 * tj + m;
#pragma unroll
    for (int r = 0; r < 4; ++r) {
      int i = ib + r;
      *(ushort*)A2A(i, i - j + 63) = f2h(p[tj][r]);
    }
  }

  // ---- P5: att / att_e (wave reads only its own rows) ----
  f32x4 accA = (f32x4){0.f, 0.f, 0.f, 0.f};
  f32x4 accE = (f32x4){0.f, 0.f, 0.f, 0.f};
  {
    const int ia = 16 * wv + m;
#pragma unroll
    for (int ks = 0; ks < 2; ++ks) {
      U16x8 pa;
#pragma unroll
      for (int e = 0; e < 8; ++e) {
        int j = 32 * ks + 8 * h + e;
        pa.u[e] = *(ushort*)A2A(ia, ia - j + 63);
      }
      f16x8 vb = *(const f16x8*)VCA(m, 32 * ks + 8 * h);
      accA = __builtin_amdgcn_mfma_f32_16x16x32_f16(pa.v, vb, accA, 0, 0, 0);
    }
#pragma unroll
    for (int ks = 0; ks < 4; ++ks) {
      f16x8 pe = *(const f16x8*)A2A(ia, 32 * ks + 8 * h);
      f16x8 rv = *(const f16x8*)RVA(m, 32 * ks + 8 * h);
      accE = __builtin_amdgcn_mfma_f32_16x16x32_f16(pe, rv, accE, 0, 0, 0);
    }
  }

  // ---- P6: fold bn_out, f16 write ----
  {
    int oc = g * 16 + m;
    int c0 = 2 * oc, c1 = c0 + 1;
    float sc0 = bn_out[c0] * rsqrtf(bn_out[1536 + c0] + EPS_F);
    float sh0 = bn_out[512 + c0] - bn_out[1024 + c0] * sc0;
    float sc1 = bn_out[c1] * rsqrtf(bn_out[1536 + c1] + EPS_F);
    float sh1 = bn_out[512 + c1] - bn_out[1024 + c1] * sc1;
    ushort4 vo;
    vo.x = f2h(accA[0] * sc0 + accE[0] * sc1 + sh0 + sh1);
    vo.y = f2h(accA[1] * sc0 + accE[1] * sc1 + sh0 + sh1);
    vo.z = f2h(accA[2] * sc0 + accE[2] * sc1 + sh0 + sh1);
    vo.w = f2h(accA[3] * sc0 + accE[3] * sc1 + sh0 + sh1);
    size_t o = (((size_t)b * 256 + oc) * 64 + d1) * 64 + 16 * wv + 4 * h;
    *(ushort4*)&out[o] = vo;
  }
#undef RTA
#undef QTA
#undef KTA
#undef GQA
#undef GKA
#undef A2A
#undef VCA
#undef RVA
}

// ---------------- pools ----------------
__global__ void __launch_bounds__(256) pool16_kernel(
    const ushort* __restrict__ in, ushort* __restrict__ out, int total) {
  int idx = blockIdx.x * 256 + threadIdx.x;
  if (idx >= total) return;
  int j = idx & 31, i = (idx >> 5) & 31, bc = idx >> 10;
  const ushort* p = in + (size_t)bc * 4096 + i * 128 + j * 2;
  out[idx] = f2h(0.25f * (h2f(p[0]) + h2f(p[1]) + h2f(p[64]) + h2f(p[65])));
}

__global__ void __launch_bounds__(256) poolx_kernel(
    const float* __restrict__ in, ushort* __restrict__ out, int total) {
  int idx = blockIdx.x * 256 + threadIdx.x;
  if (idx >= total) return;
  int j = idx & 31, i = (idx >> 5) & 31, bc = idx >> 10;
  const float* p = in + (size_t)bc * 4096 + i * 128 + j * 2;
  out[idx] = f2h(0.25f * (p[0] + p[1] + p[64] + p[65]));
}

extern "C" void kernel_launch(void* const* d_in, const int* in_sizes, int n_in,
                              void* d_out, int out_size, void* d_ws, size_t ws_size,
                              hipStream_t stream) {
  const float* x         = (const float*)d_in[0];
  const float* latent    = (const float*)d_in[1];
  const float* w_in      = (const float*)d_in[2];
  const float* bn_in     = (const float*)d_in[3];
  const float* lin_in    = (const float*)d_in[4];
  const float* alpha_in  = (const float*)d_in[5];
  const float* a0_wqkv   = (const float*)d_in[6];
  const float* a0_bn_qkv = (const float*)d_in[7];
  const float* a0_bn_sim = (const float*)d_in[8];
  const float* a0_bn_out = (const float*)d_in[9];
  const float* a0_rel    = (const float*)d_in[10];
  const float* a1_wqkv   = (const float*)d_in[11];
  const float* a1_bn_qkv = (const float*)d_in[12];
  const float* a1_bn_sim = (const float*)d_in[13];
  const float* a1_bn_out = (const float*)d_in[14];
  const float* a1_rel    = (const float*)d_in[15];
  const float* w_out     = (const float*)d_in[16];
  const float* bn_outp   = (const float*)d_in[17];
  const float* lin_out   = (const float*)d_in[18];
  const float* w_res     = (const float*)d_in[19];
  const float* alpha_fin = (const float*)d_in[20];

  float* ws = (float*)d_ws;
  float* sb_in  = ws;                          // 2048 f
  float* sb_out = ws + 2048;                   // 2048 f
  ushort* w16   = (ushort*)(ws + 4096);        // 393216 u16
  ushort* rel16 = w16 + 393216;                // 8192 u16 (2 x 4064 + pad)
  ushort* x16   = rel16 + 8192;                // 524288*... 2097152 u16
  ushort* t0    = x16 + 2097152;               // 4194304 u16
  ushort* qkvb  = t0 + 4194304;                // 8388608 u16
  ushort* qkvT  = qkvb + 8388608;              // 8388608 u16
  ushort* pool_o = qkvT + 8388608;             // 1048576 u16
  ushort* pool_x = pool_o + 1048576;           // 524288 u16
  float* resb   = (float*)(pool_x + 524288);   // 1048576 f

  ushort* w_in16  = w16;
  ushort* a0w16   = w16 + 32768;
  ushort* a1w16   = w16 + 163840;
  ushort* w_out16 = w16 + 294912;
  ushort* w_res16 = w16 + 360448;
  ushort* rel16a  = rel16;
  ushort* rel16b  = rel16 + 4064;

  prep_kernel<<<1584, 256, 0, stream>>>(w_in, a0_wqkv, a1_wqkv, w_out, w_res,
                                        latent, lin_in, lin_out, a0_rel, a1_rel,
                                        w16, rel16, sb_in, sb_out);
  cvt_kernel<<<2048, 256, 0, stream>>>(x, x16, 524288);

  // conv_in + cbn + prelu -> t0 (f16, std (b,c,h,w))
  conv_mfma_kernel<11, false><<<dim3(32, 4, 4), 256, 0, stream>>>(
      x16, w_in16, t0, 128, 256, 4096, bn_in, sb_in, alpha_in, nullptr);

  // axial 0 over H: conv -> transpose -> attn (out (b,c,w,h))
  conv_mfma_kernel<1, false><<<dim3(32, 8, 4), 256, 0, stream>>>(
      t0, a0w16, qkvb, 256, 512, 4096, a0_bn_qkv, nullptr, nullptr, nullptr);
  transpose_kernel<<<2048, 256, 0, stream>>>(qkvb, qkvT);
  axial_attn_kernel<<<4096, 256, 0, stream>>>(
      qkvT, rel16a, a0_bn_sim, a0_bn_out, t0);

  // axial 1 over W: conv -> transpose -> attn (out (b,c,h,w) std)
  conv_mfma_kernel<1, false><<<dim3(32, 8, 4), 256, 0, stream>>>(
      t0, a1w16, qkvb, 256, 512, 4096, a1_bn_qkv, nullptr, nullptr, nullptr);
  transpose_kernel<<<2048, 256, 0, stream>>>(qkvb, qkvT);
  axial_attn_kernel<<<4096, 256, 0, stream>>>(
      qkvT, rel16b, a1_bn_sim, a1_bn_out, t0);

  // pools
  pool16_kernel<<<4096, 256, 0, stream>>>(t0, pool_o, 1048576);
  poolx_kernel<<<2048, 256, 0, stream>>>(x, pool_x, 524288);

  // residual conv (f32 out)
  conv_mfma_kernel<0, true><<<dim3(8, 4, 4), 256, 0, stream>>>(
      pool_x, w_res16, resb, 128, 256, 1024, nullptr, nullptr, nullptr, nullptr);

  // final conv + cbn + add res + prelu -> d_out (f32)
  conv_mfma_kernel<15, true><<<dim3(8, 4, 4), 256, 0, stream>>>(
      pool_o, w_out16, d_out, 256, 256, 1024, bn_outp, sb_out, alpha_fin, resb);
}

// Round 8
// 236.297 us; speedup vs baseline: 2.2393x; 1.1742x over previous
//
#include <hip/hip_runtime.h>
#include <hip/hip_bf16.h>

#define EPS_F 1e-5f

typedef __attribute__((ext_vector_type(8))) _Float16 f16x8;
typedef __attribute__((ext_vector_type(4))) _Float16 f16x4;
typedef __attribute__((ext_vector_type(4))) float f32x4;

union U16x8 { ushort u[8]; f16x8 v; };

static __device__ inline ushort f2h(float f) {
  _Float16 h = (_Float16)f;
  return __builtin_bit_cast(ushort, h);
}
static __device__ inline float h2f(ushort u) {
  return (float)__builtin_bit_cast(_Float16, u);
}

// ---------------- prep: weights+rel -> f16, sb = latent @ lin^T ----------------
__global__ void __launch_bounds__(256) prep_kernel(
    const float* __restrict__ w_in, const float* __restrict__ a0w,
    const float* __restrict__ a1w, const float* __restrict__ w_out,
    const float* __restrict__ w_res,
    const float* __restrict__ latent, const float* __restrict__ lin_in,
    const float* __restrict__ lin_out,
    const float* __restrict__ a0_rel, const float* __restrict__ a1_rel,
    ushort* __restrict__ w16, ushort* __restrict__ rel16,
    float* __restrict__ sb_in, float* __restrict__ sb_out) {
  int idx = blockIdx.x * 256 + threadIdx.x;
  if (idx < 393216) {
    const float* src; int off;
    if (idx < 32768)       { src = w_in;  off = 0; }
    else if (idx < 163840) { src = a0w;   off = 32768; }
    else if (idx < 294912) { src = a1w;   off = 163840; }
    else if (idx < 360448) { src = w_out; off = 294912; }
    else                   { src = w_res; off = 360448; }
    w16[idx] = f2h(src[idx - off]);
  } else if (idx < 397312) {
    int r = idx - 393216;
    int which = r >> 11;
    int rr = r & 2047;
    int b = rr >> 9, k = rr & 511;
    const float* lin = which ? lin_out : lin_in;
    const float* lv = latent + b * 256;
    const float* lr = lin + k * 256;
    float acc = 0.f;
#pragma unroll 8
    for (int l = 0; l < 256; ++l) acc += lv[l] * lr[l];
    (which ? sb_out : sb_in)[b * 512 + k] = acc;
  } else if (idx < 405440) {
    int r = idx - 397312;          // 0..8127
    int which = r >= 4064;
    int e = which ? r - 4064 : r;  // 0..4063
    rel16[which * 4064 + e] = f2h((which ? a1_rel : a0_rel)[e]);
  }
}

// ---------------- cvt: f32 -> f16 ----------------
__global__ void __launch_bounds__(256) cvt_kernel(
    const float* __restrict__ in, ushort* __restrict__ out, int n4) {
  int idx = blockIdx.x * 256 + threadIdx.x;
  if (idx >= n4) return;
  float4 v = ((const float4*)in)[idx];
  ushort4 o;
  o.x = f2h(v.x); o.y = f2h(v.y); o.z = f2h(v.z); o.w = f2h(v.w);
  ((ushort4*)out)[idx] = o;
}

// ---------------- spatial 64x64 transpose per (b,ch) plane, f16 ----------------
__global__ void __launch_bounds__(256) transpose_kernel(
    const ushort* __restrict__ in, ushort* __restrict__ out) {
  __shared__ ushort T[64][72];
  int plane = blockIdx.x;
  const ushort* src = in + (size_t)plane * 4096;
  ushort* dst = out + (size_t)plane * 4096;
  int t = threadIdx.x;
  int r = t >> 2, s = t & 3;
  *(f16x8*)&T[r][16 * s]     = *(const f16x8*)&src[r * 64 + 16 * s];
  *(f16x8*)&T[r][16 * s + 8] = *(const f16x8*)&src[r * 64 + 16 * s + 8];
  __syncthreads();
  U16x8 o1, o2;
#pragma unroll
  for (int e = 0; e < 8; ++e) {
    o1.u[e] = T[16 * s + e][r];
    o2.u[e] = T[16 * s + 8 + e][r];
  }
  *(f16x8*)&dst[r * 64 + 16 * s]     = o1.v;
  *(f16x8*)&dst[r * 64 + 16 * s + 8] = o2.v;
}

// ---------------- MFMA f16 conv1x1 (BM=64 oc x BN=128 p, BK=32) ----------------
// MODE bits: 1 = bn affine, 2 = cbn, 4 = add addbuf(f32), 8 = prelu
template <int MODE, bool OUT32>
__global__ void __launch_bounds__(256) conv_mfma_kernel(
    const ushort* __restrict__ X, const ushort* __restrict__ W16,
    void* __restrict__ Yv, int Cin, int Cout, int P,
    const float* __restrict__ bn, const float* __restrict__ sb,
    const float* __restrict__ alpha, const float* __restrict__ addbuf) {
  const int tid = threadIdx.x;
  const int p0 = blockIdx.x * 128;
  const int o0 = blockIdx.y * 64;
  const int b  = blockIdx.z;
  const int lane = tid & 63;
  const int wv = tid >> 6;
  const int m = lane & 15, h = lane >> 4;
  const int wr = wv >> 1, wc = wv & 1;

  __shared__ __align__(16) char smem[17408];
  ushort (*Xs)[40] = (ushort(*)[40])smem;             // [128][40]
  ushort (*Ws)[40] = (ushort(*)[40])(smem + 10240);   // [64][40]
  ushort (*Es)[136] = (ushort(*)[136])smem;           // epilogue overlay [64][136]

  f32x4 acc[2][4];
#pragma unroll
  for (int i = 0; i < 2; ++i)
#pragma unroll
    for (int j = 0; j < 4; ++j) acc[i][j] = (f32x4){0.f, 0.f, 0.f, 0.f};

  const ushort* Xb = X + (size_t)b * Cin * P;
  const int s = tid & 15;
  const int cb = tid >> 4;

  for (int k0 = 0; k0 < Cin; k0 += 32) {
    __syncthreads();
#pragma unroll
    for (int half = 0; half < 2; ++half) {
      int c = cb + 16 * half;
      U16x8 xv;
      xv.v = *(const f16x8*)&Xb[(size_t)(k0 + c) * P + p0 + 8 * s];
#pragma unroll
      for (int t = 0; t < 8; ++t) {
        int j = (t + s) & 7;
        Xs[8 * s + j][c] = xv.u[j];
      }
    }
    {
      int oc = tid >> 2, sg = (tid & 3) * 8;
      *(f16x8*)&Ws[oc][sg] = *(const f16x8*)&W16[(size_t)(o0 + oc) * Cin + k0 + sg];
    }
    __syncthreads();
    f16x8 af[2], bf[4];
#pragma unroll
    for (int t = 0; t < 2; ++t) af[t] = *(const f16x8*)&Ws[32 * wr + 16 * t + m][8 * h];
#pragma unroll
    for (int t = 0; t < 4; ++t) bf[t] = *(const f16x8*)&Xs[64 * wc + 16 * t + m][8 * h];
#pragma unroll
    for (int ta = 0; ta < 2; ++ta)
#pragma unroll
      for (int tb = 0; tb < 4; ++tb)
        acc[ta][tb] = __builtin_amdgcn_mfma_f32_16x16x32_f16(af[ta], bf[tb], acc[ta][tb], 0, 0, 0);
  }

  float scl[2][4], shf[2][4];
#pragma unroll
  for (int ta = 0; ta < 2; ++ta)
#pragma unroll
    for (int r = 0; r < 4; ++r) {
      int oc = o0 + 32 * wr + 16 * ta + 4 * h + r;
      float scale = 1.f, shift = 0.f;
      if (MODE & 1) {
        float sc = bn[oc] * rsqrtf(bn[3 * Cout + oc] + EPS_F);
        scale = sc;
        shift = bn[Cout + oc] - bn[2 * Cout + oc] * sc;
      }
      if (MODE & 2) {
        float ss = sb[b * 2 * Cout + oc];
        float bb = sb[b * 2 * Cout + Cout + oc];
        scale *= ss;
        shift = shift * ss + bb;
      }
      scl[ta][r] = scale; shf[ta][r] = shift;
    }
  float al = (MODE & 8) ? *alpha : 0.f;

  if (OUT32) {
    float* Y32 = (float*)Yv;
#pragma unroll
    for (int ta = 0; ta < 2; ++ta)
#pragma unroll
      for (int tb = 0; tb < 4; ++tb)
#pragma unroll
        for (int r = 0; r < 4; ++r) {
          int oc = o0 + 32 * wr + 16 * ta + 4 * h + r;
          int p  = p0 + 64 * wc + 16 * tb + m;
          float v = acc[ta][tb][r] * scl[ta][r] + shf[ta][r];
          size_t o = ((size_t)b * Cout + oc) * P + p;
          if (MODE & 4) v += addbuf[o];
          if (MODE & 8) v = v > 0.f ? v : al * v;
          Y32[o] = v;
        }
  } else {
    ushort* Y16 = (ushort*)Yv;
    __syncthreads();
#pragma unroll
    for (int ta = 0; ta < 2; ++ta)
#pragma unroll
      for (int tb = 0; tb < 4; ++tb)
#pragma unroll
        for (int r = 0; r < 4; ++r) {
          float v = acc[ta][tb][r] * scl[ta][r] + shf[ta][r];
          if (MODE & 8) v = v > 0.f ? v : al * v;
          Es[32 * wr + 16 * ta + 4 * h + r][64 * wc + 16 * tb + m] = f2h(v);
        }
    __syncthreads();
    int row = tid >> 2, q = tid & 3;
    size_t gofs = ((size_t)b * Cout + o0 + row) * P + p0 + 32 * q;
#pragma unroll
    for (int u = 0; u < 4; ++u)
      *(f16x8*)&Y16[gofs + 8 * u] = *(const f16x8*)&Es[row][32 * q + 8 * u];
  }
}

// ---------------- axial attention, all-MFMA f16, dense emb layout ----------------
// Input qkvT layout: (b, ch, d1, i) — i (attended dim) contiguous.
// Output: out[((b*256+oc)*64 + d1)*64 + i].
__global__ void __launch_bounds__(256) axial_attn_kernel(
    const ushort* __restrict__ qkvT, const ushort* __restrict__ rel16,
    const float* __restrict__ bn_sim, const float* __restrict__ bn_out,
    ushort* __restrict__ out) {
  const int tid = threadIdx.x;
  int lin = blockIdx.x;                       // bijective XCD swizzle
  int wg = ((lin & 7) << 9) + (lin >> 3);
  const int g  = wg >> 8;
  const int bd = wg & 255;
  const int b  = bd >> 6;
  const int d1 = bd & 63;

  __shared__ __align__(16) char smem[34816];
  // relT [128][20] @0           (dead after P1)
  // QT   [64][20]  @5120        (dead after P1)
  // KT   [64][20]  @7680        (dead after P1)
  // QE   [64][72]  @10240       QE[i][kk] = q_emb[kk][i]   (dead after sv)
  // KE   [64][72]  @19456       KE[j][kk] = k_emb[kk][j]   (dead after P2)
  // VC   [16][64]  @28672 swz
  // RV   [16][128] @30720 swz
  // A2   [64][136] @0 overlay   (written at P4; overlays dead relT/QT/KT/QE)
#define RTA(d, c)  (smem + (d) * 40 + (c) * 2)
#define QTA(k2, c) (smem + 5120 + (k2) * 40 + (c) * 2)
#define KTA(k2, c) (smem + 7680 + (k2) * 40 + (c) * 2)
#define QEA(i, k)  (smem + 10240 + (i) * 144 + (k) * 2)
#define KEA(j, k)  (smem + 19456 + (j) * 144 + (k) * 2)
#define VCA(c, j)  (smem + 28672 + ((((c) * 128 + (j) * 2)) ^ (((c) & 7) << 4)))
#define RVA(c, d)  (smem + 30720 + ((((c) * 256 + (d) * 2)) ^ (((c) & 7) << 4)))
#define A2A(i, d)  (smem + (i) * 272 + (d) * 2)

  const int lane = tid & 63;
  const int wv   = tid >> 6;
  const int m    = lane & 15;
  const int h    = lane >> 4;

  // ---- P0a: issue qkv load early; zero QT/KT; fill relT + RV from rel16 ----
  const int c_ld = tid >> 3, i0_ld = (tid & 7) * 8;
  f16x8 vld = *(const f16x8*)&qkvT[((size_t)b * 512 + g * 32 + c_ld) * 4096 + d1 * 64 + i0_ld];
  {
    uint4 z = make_uint4(0u, 0u, 0u, 0u);
    ((uint4*)(smem + 5120))[tid] = z;                       // 4096 B
    if (tid < 64) ((uint4*)(smem + 5120 + 4096))[tid] = z;  // 1024 B
#pragma unroll
    for (int n = 0; n < 16; ++n) {
      int e = tid + n * 256;
      int c = e >> 7, d = e & 127;
      ushort val = (d < 127) ? rel16[c * 127 + d] : (ushort)0;
      if (c < 16) *(ushort*)RTA(d, c) = val;
      else        *(ushort*)RVA(c - 16, d) = val;
    }
  }
  __syncthreads();

  // ---- P0b: scatter q/k into QT/KT, v into VC ----
  {
    U16x8 u; u.v = vld;
    if (c_ld < 16) {
      char* base = (c_ld < 8) ? QTA(i0_ld, c_ld) : KTA(i0_ld, c_ld);
#pragma unroll
      for (int e = 0; e < 8; ++e) *(ushort*)(base + e * 40) = u.u[e];
    } else {
      *(f16x8*)VCA(c_ld - 16, i0_ld) = vld;
    }
  }
  __syncthreads();

  // ---- P1: emb GEMM via 16x16x16 MFMA; store DENSE contraction layout ----
  // dq[r] = G_q[d][n] = q_emb[n][i=n-d+63] -> QE[i][n]; dk likewise -> KE[i][n]
  {
#pragma unroll
    for (int t = 0; t < 2; ++t) {
      int dt = wv + 4 * t;
      f16x4 ar = *(const f16x4*)RTA(16 * dt + m, 4 * h);
#pragma unroll
      for (int nt = 0; nt < 4; ++nt) {
        f16x4 bq = *(const f16x4*)QTA(16 * nt + m, 4 * h);
        f16x4 bk = *(const f16x4*)KTA(16 * nt + m, 4 * h);
        f32x4 dq = __builtin_amdgcn_mfma_f32_16x16x16f16(ar, bq, (f32x4){0.f,0.f,0.f,0.f}, 0, 0, 0);
        f32x4 dk = __builtin_amdgcn_mfma_f32_16x16x16f16(ar, bk, (f32x4){0.f,0.f,0.f,0.f}, 0, 0, 0);
        int n = 16 * nt + m;
#pragma unroll
        for (int r = 0; r < 4; ++r) {
          int d = 16 * dt + 4 * h + r;
          int i = n - d + 63;
          if (i >= 0 && i < 64) {
            *(ushort*)QEA(i, n) = f2h(dq[r]);
            *(ushort*)KEA(i, n) = f2h(dk[r]);
          }
        }
      }
    }
  }
  __syncthreads();

  // ---- P2: sim = s_qk*(qk) + s_qe*q_emb + s_ke*k_emb + sh (all-b128 frags) ----
  f32x4 acc[4];
#pragma unroll
  for (int tj = 0; tj < 4; ++tj) acc[tj] = (f32x4){0.f, 0.f, 0.f, 0.f};
  {
    const int ia = 16 * wv + m;
    f16x8 af0 = *(const f16x8*)QEA(ia, 8 * h);        // A[ia][kk], kk = 8h..8h+7
    f16x8 af1 = *(const f16x8*)QEA(ia, 32 + 8 * h);   // kk = 32+8h..
#pragma unroll
    for (int tj = 0; tj < 4; ++tj) {
      int j = 16 * tj + m;
      f16x8 bf0 = *(const f16x8*)KEA(j, 8 * h);       // B[kk][j]
      f16x8 bf1 = *(const f16x8*)KEA(j, 32 + 8 * h);
      acc[tj] = __builtin_amdgcn_mfma_f32_16x16x32_f16(af0, bf0, acc[tj], 0, 0, 0);
      acc[tj] = __builtin_amdgcn_mfma_f32_16x16x32_f16(af1, bf1, acc[tj], 0, 0, 0);
    }
  }

  float s_qk = bn_sim[g]      * rsqrtf(bn_sim[144 + g] + EPS_F);
  float s_qe = bn_sim[16 + g] * rsqrtf(bn_sim[160 + g] + EPS_F);
  float s_ke = bn_sim[32 + g] * rsqrtf(bn_sim[176 + g] + EPS_F);
  float sh   = (bn_sim[48 + g] - bn_sim[96 + g]  * s_qk)
             + (bn_sim[64 + g] - bn_sim[112 + g] * s_qe)
             + (bn_sim[80 + g] - bn_sim[128 + g] * s_ke);

  const int ib = 16 * wv + 4 * h;
  float sv[4][4];
#pragma unroll
  for (int tj = 0; tj < 4; ++tj) {
    int j = 16 * tj + m;
    f16x4 qe4 = *(const f16x4*)QEA(j, ib);   // q_emb[i=ib+r][j]
    f16x4 ke4 = *(const f16x4*)KEA(j, ib);
#pragma unroll
    for (int r = 0; r < 4; ++r)
      sv[tj][r] = acc[tj][r] * s_qk + (float)qe4[r] * s_qe + (float)ke4[r] * s_ke + sh;
  }

  // ---- P3: softmax over j ----
  float p[4][4];
  {
    float mx[4];
#pragma unroll
    for (int r = 0; r < 4; ++r) {
      float v = fmaxf(fmaxf(sv[0][r], sv[1][r]), fmaxf(sv[2][r], sv[3][r]));
      v = fmaxf(v, __shfl_xor(v, 1));
      v = fmaxf(v, __shfl_xor(v, 2));
      v = fmaxf(v, __shfl_xor(v, 4));
      v = fmaxf(v, __shfl_xor(v, 8));
      mx[r] = v;
    }
#pragma unroll
    for (int r = 0; r < 4; ++r) {
      float ssum = 0.f;
#pragma unroll
      for (int tj = 0; tj < 4; ++tj) {
        p[tj][r] = __expf(sv[tj][r] - mx[r]);
        ssum += p[tj][r];
      }
      ssum += __shfl_xor(ssum, 1);
      ssum += __shfl_xor(ssum, 2);
      ssum += __shfl_xor(ssum, 4);
      ssum += __shfl_xor(ssum, 8);
      float inv = 1.f / ssum;
#pragma unroll
      for (int tj = 0; tj < 4; ++tj) p[tj][r] *= inv;
    }
  }

  // ---- P4: zero A2 (overlays dead relT/QT/KT/QE), scatter P diagonally ----
  __syncthreads();
  {
    uint4 z = make_uint4(0u, 0u, 0u, 0u);
    for (int u2 = tid; u2 < 1088; u2 += 256) ((uint4*)smem)[u2] = z;
  }
  __syncthreads();
#pragma unroll
  for (int tj = 0; tj < 4; ++tj) {
    int j = 16 * tj + m;
#pragma unroll
    for (int r = 0; r < 4; ++r) {
      int i = ib + r;
      *(ushort*)A2A(i, i - j + 63) = f2h(p[tj][r]);
    }
  }

  // ---- P5: att / att_e (wave reads only its own rows) ----
  f32x4 accA = (f32x4){0.f, 0.f, 0.f, 0.f};
  f32x4 accE = (f32x4){0.f, 0.f, 0.f, 0.f};
  {
    const int ia = 16 * wv + m;
#pragma unroll
    for (int ks = 0; ks < 2; ++ks) {
      U16x8 pa;
#pragma unroll
      for (int e = 0; e < 8; ++e) {
        int j = 32 * ks + 8 * h + e;
        pa.u[e] = *(ushort*)A2A(ia, ia - j + 63);
      }
      f16x8 vb = *(const f16x8*)VCA(m, 32 * ks + 8 * h);
      accA = __builtin_amdgcn_mfma_f32_16x16x32_f16(pa.v, vb, accA, 0, 0, 0);
    }
#pragma unroll
    for (int ks = 0; ks < 4; ++ks) {
      f16x8 pe = *(const f16x8*)A2A(ia, 32 * ks + 8 * h);
      f16x8 rv = *(const f16x8*)RVA(m, 32 * ks + 8 * h);
      accE = __builtin_amdgcn_mfma_f32_16x16x32_f16(pe, rv, accE, 0, 0, 0);
    }
  }

  // ---- P6: fold bn_out, f16 write ----
  {
    int oc = g * 16 + m;
    int c0 = 2 * oc, c1 = c0 + 1;
    float sc0 = bn_out[c0] * rsqrtf(bn_out[1536 + c0] + EPS_F);
    float sh0 = bn_out[512 + c0] - bn_out[1024 + c0] * sc0;
    float sc1 = bn_out[c1] * rsqrtf(bn_out[1536 + c1] + EPS_F);
    float sh1 = bn_out[512 + c1] - bn_out[1024 + c1] * sc1;
    ushort4 vo;
    vo.x = f2h(accA[0] * sc0 + accE[0] * sc1 + sh0 + sh1);
    vo.y = f2h(accA[1] * sc0 + accE[1] * sc1 + sh0 + sh1);
    vo.z = f2h(accA[2] * sc0 + accE[2] * sc1 + sh0 + sh1);
    vo.w = f2h(accA[3] * sc0 + accE[3] * sc1 + sh0 + sh1);
    size_t o = (((size_t)b * 256 + oc) * 64 + d1) * 64 + 16 * wv + 4 * h;
    *(ushort4*)&out[o] = vo;
  }
#undef RTA
#undef QTA
#undef KTA
#undef QEA
#undef KEA
#undef VCA
#undef RVA
#undef A2A
}

// ---------------- pools ----------------
__global__ void __launch_bounds__(256) pool16_kernel(
    const ushort* __restrict__ in, ushort* __restrict__ out, int total) {
  int idx = blockIdx.x * 256 + threadIdx.x;
  if (idx >= total) return;
  int j = idx & 31, i = (idx >> 5) & 31, bc = idx >> 10;
  const ushort* p = in + (size_t)bc * 4096 + i * 128 + j * 2;
  out[idx] = f2h(0.25f * (h2f(p[0]) + h2f(p[1]) + h2f(p[64]) + h2f(p[65])));
}

__global__ void __launch_bounds__(256) poolx_kernel(
    const float* __restrict__ in, ushort* __restrict__ out, int total) {
  int idx = blockIdx.x * 256 + threadIdx.x;
  if (idx >= total) return;
  int j = idx & 31, i = (idx >> 5) & 31, bc = idx >> 10;
  const float* p = in + (size_t)bc * 4096 + i * 128 + j * 2;
  out[idx] = f2h(0.25f * (p[0] + p[1] + p[64] + p[65]));
}

extern "C" void kernel_launch(void* const* d_in, const int* in_sizes, int n_in,
                              void* d_out, int out_size, void* d_ws, size_t ws_size,
                              hipStream_t stream) {
  const float* x         = (const float*)d_in[0];
  const float* latent    = (const float*)d_in[1];
  const float* w_in      = (const float*)d_in[2];
  const float* bn_in     = (const float*)d_in[3];
  const float* lin_in    = (const float*)d_in[4];
  const float* alpha_in  = (const float*)d_in[5];
  const float* a0_wqkv   = (const float*)d_in[6];
  const float* a0_bn_qkv = (const float*)d_in[7];
  const float* a0_bn_sim = (const float*)d_in[8];
  const float* a0_bn_out = (const float*)d_in[9];
  const float* a0_rel    = (const float*)d_in[10];
  const float* a1_wqkv   = (const float*)d_in[11];
  const float* a1_bn_qkv = (const float*)d_in[12];
  const float* a1_bn_sim = (const float*)d_in[13];
  const float* a1_bn_out = (const float*)d_in[14];
  const float* a1_rel    = (const float*)d_in[15];
  const float* w_out     = (const float*)d_in[16];
  const float* bn_outp   = (const float*)d_in[17];
  const float* lin_out   = (const float*)d_in[18];
  const float* w_res     = (const float*)d_in[19];
  const float* alpha_fin = (const float*)d_in[20];

  float* ws = (float*)d_ws;
  float* sb_in  = ws;                          // 2048 f
  float* sb_out = ws + 2048;                   // 2048 f
  ushort* w16   = (ushort*)(ws + 4096);        // 393216 u16
  ushort* rel16 = w16 + 393216;                // 8192 u16
  ushort* x16   = rel16 + 8192;                // 2097152 u16
  ushort* t0    = x16 + 2097152;               // 4194304 u16
  ushort* qkvb  = t0 + 4194304;                // 8388608 u16
  ushort* qkvT  = qkvb + 8388608;              // 8388608 u16
  ushort* pool_o = qkvT + 8388608;             // 1048576 u16
  ushort* pool_x = pool_o + 1048576;           // 524288 u16
  float* resb   = (float*)(pool_x + 524288);   // 1048576 f

  ushort* w_in16  = w16;
  ushort* a0w16   = w16 + 32768;
  ushort* a1w16   = w16 + 163840;
  ushort* w_out16 = w16 + 294912;
  ushort* w_res16 = w16 + 360448;
  ushort* rel16a  = rel16;
  ushort* rel16b  = rel16 + 4064;

  prep_kernel<<<1584, 256, 0, stream>>>(w_in, a0_wqkv, a1_wqkv, w_out, w_res,
                                        latent, lin_in, lin_out, a0_rel, a1_rel,
                                        w16, rel16, sb_in, sb_out);
  cvt_kernel<<<2048, 256, 0, stream>>>(x, x16, 524288);

  // conv_in + cbn + prelu -> t0 (f16, std (b,c,h,w))
  conv_mfma_kernel<11, false><<<dim3(32, 4, 4), 256, 0, stream>>>(
      x16, w_in16, t0, 128, 256, 4096, bn_in, sb_in, alpha_in, nullptr);

  // axial 0 over H: conv -> transpose -> attn (out (b,c,w,h))
  conv_mfma_kernel<1, false><<<dim3(32, 8, 4), 256, 0, stream>>>(
      t0, a0w16, qkvb, 256, 512, 4096, a0_bn_qkv, nullptr, nullptr, nullptr);
  transpose_kernel<<<2048, 256, 0, stream>>>(qkvb, qkvT);
  axial_attn_kernel<<<4096, 256, 0, stream>>>(
      qkvT, rel16a, a0_bn_sim, a0_bn_out, t0);

  // axial 1 over W: conv -> transpose -> attn (out (b,c,h,w) std)
  conv_mfma_kernel<1, false><<<dim3(32, 8, 4), 256, 0, stream>>>(
      t0, a1w16, qkvb, 256, 512, 4096, a1_bn_qkv, nullptr, nullptr, nullptr);
  transpose_kernel<<<2048, 256, 0, stream>>>(qkvb, qkvT);
  axial_attn_kernel<<<4096, 256, 0, stream>>>(
      qkvT, rel16b, a1_bn_sim, a1_bn_out, t0);

  // pools
  pool16_kernel<<<4096, 256, 0, stream>>>(t0, pool_o, 1048576);
  poolx_kernel<<<2048, 256, 0, stream>>>(x, pool_x, 524288);

  // residual conv (f32 out)
  conv_mfma_kernel<0, true><<<dim3(8, 4, 4), 256, 0, stream>>>(
      pool_x, w_res16, resb, 128, 256, 1024, nullptr, nullptr, nullptr, nullptr);

  // final conv + cbn + add res + prelu -> d_out (f32)
  conv_mfma_kernel<15, true><<<dim3(8, 4, 4), 256, 0, stream>>>(
      pool_o, w_out16, d_out, 256, 256, 1024, bn_outp, sb_out, alpha_fin, resb);
}

// Round 9
// 158.806 us; speedup vs baseline: 3.3320x; 1.4880x over previous
//
#include <hip/hip_runtime.h>
#include <hip/hip_bf16.h>

#define EPS_F 1e-5f

typedef __attribute__((ext_vector_type(8))) _Float16 f16x8;
typedef __attribute__((ext_vector_type(4))) _Float16 f16x4;
typedef __attribute__((ext_vector_type(4))) float f32x4;

union U16x8 { ushort u[8]; f16x8 v; };

static __device__ inline ushort f2h(float f) {
  _Float16 h = (_Float16)f;
  return __builtin_bit_cast(ushort, h);
}
static __device__ inline float h2f(ushort u) {
  return (float)__builtin_bit_cast(_Float16, u);
}

// ---------------- prep: weights+rel -> f16, sb = latent @ lin^T ----------------
__global__ void __launch_bounds__(256) prep_kernel(
    const float* __restrict__ w_in, const float* __restrict__ a0w,
    const float* __restrict__ a1w, const float* __restrict__ w_out,
    const float* __restrict__ w_res,
    const float* __restrict__ latent, const float* __restrict__ lin_in,
    const float* __restrict__ lin_out,
    const float* __restrict__ a0_rel, const float* __restrict__ a1_rel,
    ushort* __restrict__ w16, ushort* __restrict__ rel16,
    float* __restrict__ sb_in, float* __restrict__ sb_out) {
  int idx = blockIdx.x * 256 + threadIdx.x;
  if (idx < 393216) {
    const float* src; int off;
    if (idx < 32768)       { src = w_in;  off = 0; }
    else if (idx < 163840) { src = a0w;   off = 32768; }
    else if (idx < 294912) { src = a1w;   off = 163840; }
    else if (idx < 360448) { src = w_out; off = 294912; }
    else                   { src = w_res; off = 360448; }
    w16[idx] = f2h(src[idx - off]);
  } else if (idx < 397312) {
    int r = idx - 393216;
    int which = r >> 11;
    int rr = r & 2047;
    int b = rr >> 9, k = rr & 511;
    const float* lin = which ? lin_out : lin_in;
    const float* lv = latent + b * 256;
    const float* lr = lin + k * 256;
    float acc = 0.f;
#pragma unroll 8
    for (int l = 0; l < 256; ++l) acc += lv[l] * lr[l];
    (which ? sb_out : sb_in)[b * 512 + k] = acc;
  } else if (idx < 405440) {
    int r = idx - 397312;          // 0..8127
    int which = r >= 4064;
    int e = which ? r - 4064 : r;  // 0..4063
    rel16[which * 4064 + e] = f2h((which ? a1_rel : a0_rel)[e]);
  }
}

// ---------------- cvtT: x f32 (b,128,4096) -> x16 pixel-major (b,4096,128) ----------------
__global__ void __launch_bounds__(256) cvtT_kernel(
    const float* __restrict__ x, ushort* __restrict__ x16) {
  const int pt = blockIdx.x, ct = blockIdx.y, b = blockIdx.z;
  __shared__ ushort Lt[128][40];
  const int tid = threadIdx.x;
#pragma unroll
  for (int r = 0; r < 16; ++r) {
    int e = tid + 256 * r;
    int c = e >> 7, p = e & 127;
    Lt[p][c] = f2h(x[((size_t)(b * 128 + ct * 32 + c)) * 4096 + pt * 128 + p]);
  }
  __syncthreads();
#pragma unroll
  for (int r = 0; r < 2; ++r) {
    int e = tid + 256 * r;
    int p = e >> 2, q = e & 3;
    *(f16x8*)&x16[((size_t)b * 4096 + pt * 128 + p) * 128 + ct * 32 + 8 * q] =
        *(const f16x8*)&Lt[p][8 * q];
  }
}

// ---------------- poolx: x f32 (b,128,64,64) -> pool_x pixel-major (b,1024,128) f16 ----------------
__global__ void __launch_bounds__(256) poolx_kernel(
    const float* __restrict__ x, ushort* __restrict__ out16) {
  const int ip = blockIdx.x, ct = blockIdx.y, b = blockIdx.z;  // ip = i' row
  __shared__ float Lp[32][33];
  const int tid = threadIdx.x;
  {
    int c = tid >> 3, grp = tid & 7;
    const float* base = x + ((size_t)(b * 128 + ct * 32 + c)) * 4096 + (2 * ip) * 64 + 8 * grp;
    float4 a0 = *(const float4*)&base[0];
    float4 a1 = *(const float4*)&base[4];
    float4 b0 = *(const float4*)&base[64];
    float4 b1 = *(const float4*)&base[68];
    Lp[c][4 * grp + 0] = 0.25f * (a0.x + a0.y + b0.x + b0.y);
    Lp[c][4 * grp + 1] = 0.25f * (a0.z + a0.w + b0.z + b0.w);
    Lp[c][4 * grp + 2] = 0.25f * (a1.x + a1.y + b1.x + b1.y);
    Lp[c][4 * grp + 3] = 0.25f * (a1.z + a1.w + b1.z + b1.w);
  }
  __syncthreads();
  {
    int jp = tid >> 3, q = tid & 7;
    ushort4 o;
    o.x = f2h(Lp[4 * q + 0][jp]);
    o.y = f2h(Lp[4 * q + 1][jp]);
    o.z = f2h(Lp[4 * q + 2][jp]);
    o.w = f2h(Lp[4 * q + 3][jp]);
    *(ushort4*)&out16[((size_t)b * 1024 + ip * 32 + jp) * 128 + ct * 32 + 4 * q] = o;
  }
}

// ---------------- pool16: t0 pixel-major (b,4096,256) -> pool_o (b,1024,256) ----------------
__global__ void __launch_bounds__(256) pool16_kernel(
    const ushort* __restrict__ in, ushort* __restrict__ out) {
  int idx = blockIdx.x * 256 + threadIdx.x;   // 131072 total
  int oct = idx & 31, pp = (idx >> 5) & 1023, b = idx >> 15;
  int jp = pp & 31, ip = pp >> 5;
  size_t p00 = (size_t)b * 4096 + (2 * ip) * 64 + 2 * jp;
  const ushort* s0 = in + (p00)     * 256 + 8 * oct;
  const ushort* s1 = in + (p00 + 1) * 256 + 8 * oct;
  const ushort* s2 = in + (p00 + 64) * 256 + 8 * oct;
  const ushort* s3 = in + (p00 + 65) * 256 + 8 * oct;
  U16x8 a, bq, c, d, o;
  a.v = *(const f16x8*)s0; bq.v = *(const f16x8*)s1;
  c.v = *(const f16x8*)s2; d.v = *(const f16x8*)s3;
#pragma unroll
  for (int e = 0; e < 8; ++e)
    o.u[e] = f2h(0.25f * (h2f(a.u[e]) + h2f(bq.u[e]) + h2f(c.u[e]) + h2f(d.u[e])));
  *(f16x8*)&out[((size_t)b * 1024 + pp) * 256 + 8 * oct] = o.v;
}

// ---------------- MFMA f16 conv1x1, pixel-major X (BM=64 oc x BN=128 p, BK=64) ----------------
// X: (b, P, Cin) f16. W16: [oc][Cin]. OUT16: Y (b,P,Cout) f16. OUT32: Y (b,Cout,P) f32.
// MODE bits: 1 = bn affine, 2 = cbn, 4 = add addbuf(f32, chan-major), 8 = prelu
template <int MODE, bool OUT32>
__global__ void __launch_bounds__(256) conv_mfma_kernel(
    const ushort* __restrict__ X, const ushort* __restrict__ W16,
    void* __restrict__ Yv, int Cin, int Cout, int P,
    const float* __restrict__ bn, const float* __restrict__ sb,
    const float* __restrict__ alpha, const float* __restrict__ addbuf) {
  const int tid = threadIdx.x;
  const int p0 = blockIdx.x * 128;
  const int o0 = blockIdx.y * 64;
  const int b  = blockIdx.z;
  const int lane = tid & 63;
  const int wv = tid >> 6;
  const int m = lane & 15, h = lane >> 4;
  const int wr = wv >> 1, wc = wv & 1;

  __shared__ __align__(16) char smem[27648];
  ushort (*Xs)[72] = (ushort(*)[72])smem;             // [128][72]
  ushort (*Ws)[72] = (ushort(*)[72])(smem + 18432);   // [64][72]
  ushort (*Es)[72] = (ushort(*)[72])smem;             // epilogue overlay [128][72]

  f32x4 acc[2][4];
#pragma unroll
  for (int i = 0; i < 2; ++i)
#pragma unroll
    for (int j = 0; j < 4; ++j) acc[i][j] = (f32x4){0.f, 0.f, 0.f, 0.f};

  const ushort* Xb = X + (size_t)b * P * Cin;

  for (int k0 = 0; k0 < Cin; k0 += 64) {
    __syncthreads();
#pragma unroll
    for (int r = 0; r < 4; ++r) {
      int e = tid + 256 * r;
      int pp = e >> 3, ch = e & 7;
      *(f16x8*)&Xs[pp][8 * ch] =
          *(const f16x8*)&Xb[(size_t)(p0 + pp) * Cin + k0 + 8 * ch];
    }
#pragma unroll
    for (int r = 0; r < 2; ++r) {
      int e = tid + 256 * r;
      int oc = e >> 3, ch = e & 7;
      *(f16x8*)&Ws[oc][8 * ch] =
          *(const f16x8*)&W16[(size_t)(o0 + oc) * Cin + k0 + 8 * ch];
    }
    __syncthreads();
#pragma unroll
    for (int ks = 0; ks < 2; ++ks) {
      f16x8 af[2], bf[4];
#pragma unroll
      for (int t = 0; t < 2; ++t) af[t] = *(const f16x8*)&Ws[32 * wr + 16 * t + m][32 * ks + 8 * h];
#pragma unroll
      for (int t = 0; t < 4; ++t) bf[t] = *(const f16x8*)&Xs[64 * wc + 16 * t + m][32 * ks + 8 * h];
#pragma unroll
      for (int ta = 0; ta < 2; ++ta)
#pragma unroll
        for (int tb = 0; tb < 4; ++tb)
          acc[ta][tb] = __builtin_amdgcn_mfma_f32_16x16x32_f16(af[ta], bf[tb], acc[ta][tb], 0, 0, 0);
    }
  }

  float scl[2][4], shf[2][4];
#pragma unroll
  for (int ta = 0; ta < 2; ++ta)
#pragma unroll
    for (int r = 0; r < 4; ++r) {
      int oc = o0 + 32 * wr + 16 * ta + 4 * h + r;
      float scale = 1.f, shift = 0.f;
      if (MODE & 1) {
        float sc = bn[oc] * rsqrtf(bn[3 * Cout + oc] + EPS_F);
        scale = sc;
        shift = bn[Cout + oc] - bn[2 * Cout + oc] * sc;
      }
      if (MODE & 2) {
        float ss = sb[b * 2 * Cout + oc];
        float bb = sb[b * 2 * Cout + Cout + oc];
        scale *= ss;
        shift = shift * ss + bb;
      }
      scl[ta][r] = scale; shf[ta][r] = shift;
    }
  float al = (MODE & 8) ? *alpha : 0.f;

  if (OUT32) {
    float* Y32 = (float*)Yv;
#pragma unroll
    for (int ta = 0; ta < 2; ++ta)
#pragma unroll
      for (int tb = 0; tb < 4; ++tb)
#pragma unroll
        for (int r = 0; r < 4; ++r) {
          int oc = o0 + 32 * wr + 16 * ta + 4 * h + r;
          int p  = p0 + 64 * wc + 16 * tb + m;
          float v = acc[ta][tb][r] * scl[ta][r] + shf[ta][r];
          size_t o = ((size_t)b * Cout + oc) * P + p;
          if (MODE & 4) v += addbuf[o];
          if (MODE & 8) v = v > 0.f ? v : al * v;
          Y32[o] = v;
        }
  } else {
    ushort* Y16 = (ushort*)Yv;
    __syncthreads();
#pragma unroll
    for (int ta = 0; ta < 2; ++ta)
#pragma unroll
      for (int tb = 0; tb < 4; ++tb)
#pragma unroll
        for (int r = 0; r < 4; ++r) {
          float v = acc[ta][tb][r] * scl[ta][r] + shf[ta][r];
          if (MODE & 8) v = v > 0.f ? v : al * v;
          Es[64 * wc + 16 * tb + m][32 * wr + 16 * ta + 4 * h + r] = f2h(v);
        }
    __syncthreads();
#pragma unroll
    for (int r = 0; r < 4; ++r) {
      int e = tid + 256 * r;
      int pp = e >> 3, q = e & 7;
      *(f16x8*)&Y16[((size_t)b * P + p0 + pp) * Cout + o0 + 8 * q] =
          *(const f16x8*)&Es[pp][8 * q];
    }
  }
}

// ---------------- axial attention, all-MFMA f16, pixel-major in/out ----------------
// Input qkv (b, p, 512) with p = i*64 + d1 (i = attended dim).
// Output out (b, p', 256) with p' = d1*64 + i.
__global__ void __launch_bounds__(256) axial_attn_kernel(
    const ushort* __restrict__ qkv, const ushort* __restrict__ rel16,
    const float* __restrict__ bn_sim, const float* __restrict__ bn_out,
    ushort* __restrict__ out16) {
  const int tid = threadIdx.x;
  int lin = blockIdx.x;                       // bijective XCD swizzle
  int wg = ((lin & 7) << 9) + (lin >> 3);
  const int g  = wg >> 8;
  const int bd = wg & 255;
  const int b  = bd >> 6;
  const int d1 = bd & 63;

  __shared__ __align__(16) char smem[37888];
  // relQ [128][20] @0      (rel c0-7, zeros c8-15)      5120
  // relK [128][20] @5120   (zeros c0-7, rel c8-15)      5120
  // QK   [64][24]  @10240  (q c0-7, k c8-15)            3072
  // QE   [64][72]  @13312                                9216
  // KE   [64][72]  @22528                                9216
  // VC   [16][64]  @31744 swz                            2048
  // RV   [16][128] @33792 swz                            4096
  // A2   [64][136] @0 overlay (relQ/relK/QK/QE dead)    17408
#define RQA(d, c)  (smem + (d) * 40 + (c) * 2)
#define RKA(d, c)  (smem + 5120 + (d) * 40 + (c) * 2)
#define QKA(i, c)  (smem + 10240 + (i) * 48 + (c) * 2)
#define QEA(i, k)  (smem + 13312 + (i) * 144 + (k) * 2)
#define KEA(j, k)  (smem + 22528 + (j) * 144 + (k) * 2)
#define VCA(c, j)  (smem + 31744 + ((((c) * 128 + (j) * 2)) ^ (((c) & 7) << 4)))
#define RVA(c, d)  (smem + 33792 + ((((c) * 256 + (d) * 2)) ^ (((c) & 7) << 4)))
#define A2A(i, d)  (smem + (i) * 272 + (d) * 2)

  const int lane = tid & 63;
  const int wv   = tid >> 6;
  const int m    = lane & 15;
  const int h    = lane >> 4;

  // ---- P0a: issue qkv load (64B/pixel, 4 lanes each); fill relQ/relK/RV ----
  const int i_ld = tid >> 2, quad = tid & 3;
  f16x8 vld = *(const f16x8*)&qkv[((size_t)b * 4096 + i_ld * 64 + d1) * 512 + g * 32 + 8 * quad];
  {
#pragma unroll
    for (int n = 0; n < 16; ++n) {
      int e = tid + n * 256;
      int c = e >> 7, d = e & 127;
      ushort val = (d < 127) ? rel16[c * 127 + d] : (ushort)0;
      if (c < 8)       { *(ushort*)RQA(d, c) = val; *(ushort*)RKA(d, c) = 0; }
      else if (c < 16) { *(ushort*)RQA(d, c) = 0;  *(ushort*)RKA(d, c) = val; }
      else             { *(ushort*)RVA(c - 16, d) = val; }
    }
  }
  __syncthreads();

  // ---- P0b: QK direct copy; V scatter into VC ----
  if (quad < 2) {
    *(f16x8*)QKA(i_ld, 8 * quad) = vld;
  } else {
    U16x8 u; u.v = vld;
    int c0 = 8 * (quad - 2);
#pragma unroll
    for (int e = 0; e < 8; ++e) *(ushort*)VCA(c0 + e, i_ld) = u.u[e];
  }
  __syncthreads();

  // ---- P1: emb GEMM (relQ@QK, relK@QK) -> dense QE/KE ----
  {
#pragma unroll
    for (int t = 0; t < 2; ++t) {
      int dt = wv + 4 * t;
      f16x4 arQ = *(const f16x4*)RQA(16 * dt + m, 4 * h);
      f16x4 arK = *(const f16x4*)RKA(16 * dt + m, 4 * h);
#pragma unroll
      for (int nt = 0; nt < 4; ++nt) {
        f16x4 bqk = *(const f16x4*)QKA(16 * nt + m, 4 * h);
        f32x4 dq = __builtin_amdgcn_mfma_f32_16x16x16f16(arQ, bqk, (f32x4){0.f,0.f,0.f,0.f}, 0, 0, 0);
        f32x4 dk = __builtin_amdgcn_mfma_f32_16x16x16f16(arK, bqk, (f32x4){0.f,0.f,0.f,0.f}, 0, 0, 0);
        int n = 16 * nt + m;
#pragma unroll
        for (int r = 0; r < 4; ++r) {
          int d = 16 * dt + 4 * h + r;
          int i = n - d + 63;
          if ((unsigned)i < 64u) {
            *(ushort*)QEA(i, n) = f2h(dq[r]);
            *(ushort*)KEA(i, n) = f2h(dk[r]);
          }
        }
      }
    }
  }
  __syncthreads();

  // ---- P2: sim = s_qk*(qk) + s_qe*q_emb + s_ke*k_emb + sh ----
  f32x4 acc[4];
#pragma unroll
  for (int tj = 0; tj < 4; ++tj) acc[tj] = (f32x4){0.f, 0.f, 0.f, 0.f};
  {
    const int ia = 16 * wv + m;
    f16x8 af0 = *(const f16x8*)QEA(ia, 8 * h);
    f16x8 af1 = *(const f16x8*)QEA(ia, 32 + 8 * h);
#pragma unroll
    for (int tj = 0; tj < 4; ++tj) {
      int j = 16 * tj + m;
      f16x8 bf0 = *(const f16x8*)KEA(j, 8 * h);
      f16x8 bf1 = *(const f16x8*)KEA(j, 32 + 8 * h);
      acc[tj] = __builtin_amdgcn_mfma_f32_16x16x32_f16(af0, bf0, acc[tj], 0, 0, 0);
      acc[tj] = __builtin_amdgcn_mfma_f32_16x16x32_f16(af1, bf1, acc[tj], 0, 0, 0);
    }
  }

  float s_qk = bn_sim[g]      * rsqrtf(bn_sim[144 + g] + EPS_F);
  float s_qe = bn_sim[16 + g] * rsqrtf(bn_sim[160 + g] + EPS_F);
  float s_ke = bn_sim[32 + g] * rsqrtf(bn_sim[176 + g] + EPS_F);
  float sh   = (bn_sim[48 + g] - bn_sim[96 + g]  * s_qk)
             + (bn_sim[64 + g] - bn_sim[112 + g] * s_qe)
             + (bn_sim[80 + g] - bn_sim[128 + g] * s_ke);

  const int ib = 16 * wv + 4 * h;
  float sv[4][4];
#pragma unroll
  for (int tj = 0; tj < 4; ++tj) {
    int j = 16 * tj + m;
    f16x4 qe4 = *(const f16x4*)QEA(j, ib);
    f16x4 ke4 = *(const f16x4*)KEA(j, ib);
#pragma unroll
    for (int r = 0; r < 4; ++r)
      sv[tj][r] = acc[tj][r] * s_qk + (float)qe4[r] * s_qe + (float)ke4[r] * s_ke + sh;
  }

  // ---- P3: softmax over j ----
  float p[4][4];
  {
    float mx[4];
#pragma unroll
    for (int r = 0; r < 4; ++r) {
      float v = fmaxf(fmaxf(sv[0][r], sv[1][r]), fmaxf(sv[2][r], sv[3][r]));
      v = fmaxf(v, __shfl_xor(v, 1));
      v = fmaxf(v, __shfl_xor(v, 2));
      v = fmaxf(v, __shfl_xor(v, 4));
      v = fmaxf(v, __shfl_xor(v, 8));
      mx[r] = v;
    }
#pragma unroll
    for (int r = 0; r < 4; ++r) {
      float ssum = 0.f;
#pragma unroll
      for (int tj = 0; tj < 4; ++tj) {
        p[tj][r] = __expf(sv[tj][r] - mx[r]);
        ssum += p[tj][r];
      }
      ssum += __shfl_xor(ssum, 1);
      ssum += __shfl_xor(ssum, 2);
      ssum += __shfl_xor(ssum, 4);
      ssum += __shfl_xor(ssum, 8);
      float inv = 1.f / ssum;
#pragma unroll
      for (int tj = 0; tj < 4; ++tj) p[tj][r] *= inv;
    }
  }

  // ---- P4: zero A2 (overlay), scatter P diagonally ----
  __syncthreads();
  {
    uint4 z = make_uint4(0u, 0u, 0u, 0u);
    for (int u2 = tid; u2 < 1088; u2 += 256) ((uint4*)smem)[u2] = z;
  }
  __syncthreads();
#pragma unroll
  for (int tj = 0; tj < 4; ++tj) {
    int j = 16 * tj + m;
#pragma unroll
    for (int r = 0; r < 4; ++r) {
      int i = ib + r;
      *(ushort*)A2A(i, i - j + 63) = f2h(p[tj][r]);
    }
  }

  // ---- P5: att / att_e ----
  f32x4 accA = (f32x4){0.f, 0.f, 0.f, 0.f};
  f32x4 accE = (f32x4){0.f, 0.f, 0.f, 0.f};
  {
    const int ia = 16 * wv + m;
#pragma unroll
    for (int ks = 0; ks < 2; ++ks) {
      U16x8 pa;
#pragma unroll
      for (int e = 0; e < 8; ++e) {
        int j = 32 * ks + 8 * h + e;
        pa.u[e] = *(ushort*)A2A(ia, ia - j + 63);
      }
      f16x8 vb = *(const f16x8*)VCA(m, 32 * ks + 8 * h);
      accA = __builtin_amdgcn_mfma_f32_16x16x32_f16(pa.v, vb, accA, 0, 0, 0);
    }
#pragma unroll
    for (int ks = 0; ks < 4; ++ks) {
      f16x8 pe = *(const f16x8*)A2A(ia, 32 * ks + 8 * h);
      f16x8 rv = *(const f16x8*)RVA(m, 32 * ks + 8 * h);
      accE = __builtin_amdgcn_mfma_f32_16x16x32_f16(pe, rv, accE, 0, 0, 0);
    }
  }

  // ---- P6: fold bn_out, pixel-major write ----
  {
    int oc = g * 16 + m;
    int c0 = 2 * oc, c1 = c0 + 1;
    float sc0 = bn_out[c0] * rsqrtf(bn_out[1536 + c0] + EPS_F);
    float sh0 = bn_out[512 + c0] - bn_out[1024 + c0] * sc0;
    float sc1 = bn_out[c1] * rsqrtf(bn_out[1536 + c1] + EPS_F);
    float sh1 = bn_out[512 + c1] - bn_out[1024 + c1] * sc1;
    float vv[4];
    vv[0] = accA[0] * sc0 + accE[0] * sc1 + sh0 + sh1;
    vv[1] = accA[1] * sc0 + accE[1] * sc1 + sh0 + sh1;
    vv[2] = accA[2] * sc0 + accE[2] * sc1 + sh0 + sh1;
    vv[3] = accA[3] * sc0 + accE[3] * sc1 + sh0 + sh1;
    size_t base = ((size_t)b * 4096 + (size_t)d1 * 64 + ib) * 256 + oc;
#pragma unroll
    for (int r = 0; r < 4; ++r)
      out16[base + (size_t)r * 256] = f2h(vv[r]);
  }
#undef RQA
#undef RKA
#undef QKA
#undef QEA
#undef KEA
#undef VCA
#undef RVA
#undef A2A
}

extern "C" void kernel_launch(void* const* d_in, const int* in_sizes, int n_in,
                              void* d_out, int out_size, void* d_ws, size_t ws_size,
                              hipStream_t stream) {
  const float* x         = (const float*)d_in[0];
  const float* latent    = (const float*)d_in[1];
  const float* w_in      = (const float*)d_in[2];
  const float* bn_in     = (const float*)d_in[3];
  const float* lin_in    = (const float*)d_in[4];
  const float* alpha_in  = (const float*)d_in[5];
  const float* a0_wqkv   = (const float*)d_in[6];
  const float* a0_bn_qkv = (const float*)d_in[7];
  const float* a0_bn_sim = (const float*)d_in[8];
  const float* a0_bn_out = (const float*)d_in[9];
  const float* a0_rel    = (const float*)d_in[10];
  const float* a1_wqkv   = (const float*)d_in[11];
  const float* a1_bn_qkv = (const float*)d_in[12];
  const float* a1_bn_sim = (const float*)d_in[13];
  const float* a1_bn_out = (const float*)d_in[14];
  const float* a1_rel    = (const float*)d_in[15];
  const float* w_out     = (const float*)d_in[16];
  const float* bn_outp   = (const float*)d_in[17];
  const float* lin_out   = (const float*)d_in[18];
  const float* w_res     = (const float*)d_in[19];
  const float* alpha_fin = (const float*)d_in[20];

  float* ws = (float*)d_ws;
  float* sb_in  = ws;                          // 2048 f
  float* sb_out = ws + 2048;                   // 2048 f
  ushort* w16   = (ushort*)(ws + 4096);        // 393216 u16
  ushort* rel16 = w16 + 393216;                // 8192 u16
  ushort* x16   = rel16 + 8192;                // 2097152 u16 (b,4096,128)
  ushort* t0    = x16 + 2097152;               // 4194304 u16 (b,4096,256)
  ushort* qkvb  = t0 + 4194304;                // 8388608 u16 (b,4096,512)
  ushort* pool_o = qkvb + 8388608;             // 1048576 u16 (b,1024,256)
  ushort* pool_x = pool_o + 1048576;           // 524288 u16  (b,1024,128)
  float* resb   = (float*)(pool_x + 524288);   // 1048576 f   (b,256,1024)

  ushort* w_in16  = w16;
  ushort* a0w16   = w16 + 32768;
  ushort* a1w16   = w16 + 163840;
  ushort* w_out16 = w16 + 294912;
  ushort* w_res16 = w16 + 360448;
  ushort* rel16a  = rel16;
  ushort* rel16b  = rel16 + 4064;

  prep_kernel<<<1584, 256, 0, stream>>>(w_in, a0_wqkv, a1_wqkv, w_out, w_res,
                                        latent, lin_in, lin_out, a0_rel, a1_rel,
                                        w16, rel16, sb_in, sb_out);
  cvtT_kernel<<<dim3(32, 4, 4), 256, 0, stream>>>(x, x16);

  // conv_in + cbn + prelu -> t0 (pixel-major, p = h*64+w)
  conv_mfma_kernel<11, false><<<dim3(32, 4, 4), 256, 0, stream>>>(
      x16, w_in16, t0, 128, 256, 4096, bn_in, sb_in, alpha_in, nullptr);

  // axial 0 over H (i=h, d1=w): out p = w*64+h
  conv_mfma_kernel<1, false><<<dim3(32, 8, 4), 256, 0, stream>>>(
      t0, a0w16, qkvb, 256, 512, 4096, a0_bn_qkv, nullptr, nullptr, nullptr);
  axial_attn_kernel<<<4096, 256, 0, stream>>>(
      qkvb, rel16a, a0_bn_sim, a0_bn_out, t0);

  // axial 1 over W (i=w, d1=h): out p = h*64+w (std)
  conv_mfma_kernel<1, false><<<dim3(32, 8, 4), 256, 0, stream>>>(
      t0, a1w16, qkvb, 256, 512, 4096, a1_bn_qkv, nullptr, nullptr, nullptr);
  axial_attn_kernel<<<4096, 256, 0, stream>>>(
      qkvb, rel16b, a1_bn_sim, a1_bn_out, t0);

  // pools
  pool16_kernel<<<512, 256, 0, stream>>>(t0, pool_o);
  poolx_kernel<<<dim3(32, 4, 4), 256, 0, stream>>>(x, pool_x);

  // residual conv (f32 chan-major out)
  conv_mfma_kernel<0, true><<<dim3(8, 4, 4), 256, 0, stream>>>(
      pool_x, w_res16, resb, 128, 256, 1024, nullptr, nullptr, nullptr, nullptr);

  // final conv + cbn + add res + prelu -> d_out (f32 chan-major)
  conv_mfma_kernel<15, true><<<dim3(8, 4, 4), 256, 0, stream>>>(
      pool_o, w_out16, d_out, 256, 256, 1024, bn_outp, sb_out, alpha_fin, resb);
}

// Round 10
// 144.645 us; speedup vs baseline: 3.6582x; 1.0979x over previous
//
#include <hip/hip_runtime.h>
#include <hip/hip_bf16.h>

#define EPS_F 1e-5f

typedef __attribute__((ext_vector_type(8))) _Float16 f16x8;
typedef __attribute__((ext_vector_type(4))) _Float16 f16x4;
typedef __attribute__((ext_vector_type(4))) float f32x4;

union U16x8 { ushort u[8]; f16x8 v; };

static __device__ inline ushort f2h(float f) {
  _Float16 h = (_Float16)f;
  return __builtin_bit_cast(ushort, h);
}
static __device__ inline float h2f(ushort u) {
  return (float)__builtin_bit_cast(_Float16, u);
}

// ---------------- prep: weights -> f16, sb, rel LDS-images ----------------
// relimg layout per dir (7168 u16 = 14336 B):
//   [0,5120)B    relQ image [128][20]: c<8 = rel rows 0-7, else 0
//   [5120,10240) relK image [128][20]: c in 8..15 = rel rows 8-15, else 0
//   [10240,14336) RV image, swizzled: byte pos = (c*256+d*2)^((c&7)<<4), rel rows 16-31
__global__ void __launch_bounds__(256) prep_kernel(
    const float* __restrict__ w_in, const float* __restrict__ a0w,
    const float* __restrict__ a1w, const float* __restrict__ w_out,
    const float* __restrict__ w_res,
    const float* __restrict__ latent, const float* __restrict__ lin_in,
    const float* __restrict__ lin_out,
    const float* __restrict__ a0_rel, const float* __restrict__ a1_rel,
    ushort* __restrict__ w16, ushort* __restrict__ relimg,
    float* __restrict__ sb_in, float* __restrict__ sb_out) {
  int idx = blockIdx.x * 256 + threadIdx.x;
  if (idx < 393216) {
    const float* src; int off;
    if (idx < 32768)       { src = w_in;  off = 0; }
    else if (idx < 163840) { src = a0w;   off = 32768; }
    else if (idx < 294912) { src = a1w;   off = 163840; }
    else if (idx < 360448) { src = w_out; off = 294912; }
    else                   { src = w_res; off = 360448; }
    w16[idx] = f2h(src[idx - off]);
  } else if (idx < 397312) {
    int r = idx - 393216;
    int which = r >> 11;
    int rr = r & 2047;
    int b = rr >> 9, k = rr & 511;
    const float* lin = which ? lin_out : lin_in;
    const float* lv = latent + b * 256;
    const float* lr = lin + k * 256;
    float acc = 0.f;
#pragma unroll 8
    for (int l = 0; l < 256; ++l) acc += lv[l] * lr[l];
    (which ? sb_out : sb_in)[b * 512 + k] = acc;
  } else if (idx < 411648) {
    int e = idx - 397312;            // 0..14335
    int which = e >= 7168;
    int s = which ? e - 7168 : e;    // 0..7167 (u16 index in image)
    const float* rel = which ? a1_rel : a0_rel;
    ushort val = 0;
    if (s < 2560) {                  // relQ
      int d = s / 20, c = s % 20;
      if (c < 8 && d < 127) val = f2h(rel[c * 127 + d]);
    } else if (s < 5120) {           // relK
      int s2 = s - 2560;
      int d = s2 / 20, c = s2 % 20;
      if (c >= 8 && c < 16 && d < 127) val = f2h(rel[c * 127 + d]);
    } else {                         // RV swizzled
      int pos = (s - 5120) * 2;
      int c = pos >> 8;
      int inner = (pos & 255) ^ ((c & 7) << 4);
      int d = inner >> 1;
      if (d < 127) val = f2h(rel[(16 + c) * 127 + d]);
    }
    relimg[which * 7168 + s] = val;
  }
}

// ---------------- cvtT: x f32 (b,128,4096) -> x16 pixel-major (b,4096,128) ----------------
__global__ void __launch_bounds__(256) cvtT_kernel(
    const float* __restrict__ x, ushort* __restrict__ x16) {
  const int pt = blockIdx.x, ct = blockIdx.y, b = blockIdx.z;
  __shared__ ushort Lt[128][40];
  const int tid = threadIdx.x;
#pragma unroll
  for (int r = 0; r < 16; ++r) {
    int e = tid + 256 * r;
    int c = e >> 7, p = e & 127;
    Lt[p][c] = f2h(x[((size_t)(b * 128 + ct * 32 + c)) * 4096 + pt * 128 + p]);
  }
  __syncthreads();
#pragma unroll
  for (int r = 0; r < 2; ++r) {
    int e = tid + 256 * r;
    int p = e >> 2, q = e & 3;
    *(f16x8*)&x16[((size_t)b * 4096 + pt * 128 + p) * 128 + ct * 32 + 8 * q] =
        *(const f16x8*)&Lt[p][8 * q];
  }
}

// ---------------- poolx: x f32 (b,128,64,64) -> pool_x pixel-major (b,1024,128) f16 ----------------
__global__ void __launch_bounds__(256) poolx_kernel(
    const float* __restrict__ x, ushort* __restrict__ out16) {
  const int ip = blockIdx.x, ct = blockIdx.y, b = blockIdx.z;
  __shared__ float Lp[32][33];
  const int tid = threadIdx.x;
  {
    int c = tid >> 3, grp = tid & 7;
    const float* base = x + ((size_t)(b * 128 + ct * 32 + c)) * 4096 + (2 * ip) * 64 + 8 * grp;
    float4 a0 = *(const float4*)&base[0];
    float4 a1 = *(const float4*)&base[4];
    float4 b0 = *(const float4*)&base[64];
    float4 b1 = *(const float4*)&base[68];
    Lp[c][4 * grp + 0] = 0.25f * (a0.x + a0.y + b0.x + b0.y);
    Lp[c][4 * grp + 1] = 0.25f * (a0.z + a0.w + b0.z + b0.w);
    Lp[c][4 * grp + 2] = 0.25f * (a1.x + a1.y + b1.x + b1.y);
    Lp[c][4 * grp + 3] = 0.25f * (a1.z + a1.w + b1.z + b1.w);
  }
  __syncthreads();
  {
    int jp = tid >> 3, q = tid & 7;
    ushort4 o;
    o.x = f2h(Lp[4 * q + 0][jp]);
    o.y = f2h(Lp[4 * q + 1][jp]);
    o.z = f2h(Lp[4 * q + 2][jp]);
    o.w = f2h(Lp[4 * q + 3][jp]);
    *(ushort4*)&out16[((size_t)b * 1024 + ip * 32 + jp) * 128 + ct * 32 + 4 * q] = o;
  }
}

// ---------------- pool16: t0 pixel-major (b,4096,256) -> pool_o (b,1024,256) ----------------
__global__ void __launch_bounds__(256) pool16_kernel(
    const ushort* __restrict__ in, ushort* __restrict__ out) {
  int idx = blockIdx.x * 256 + threadIdx.x;   // 131072 total
  int oct = idx & 31, pp = (idx >> 5) & 1023, b = idx >> 15;
  int jp = pp & 31, ip = pp >> 5;
  size_t p00 = (size_t)b * 4096 + (2 * ip) * 64 + 2 * jp;
  const ushort* s0 = in + (p00)     * 256 + 8 * oct;
  const ushort* s1 = in + (p00 + 1) * 256 + 8 * oct;
  const ushort* s2 = in + (p00 + 64) * 256 + 8 * oct;
  const ushort* s3 = in + (p00 + 65) * 256 + 8 * oct;
  U16x8 a, bq, c, d, o;
  a.v = *(const f16x8*)s0; bq.v = *(const f16x8*)s1;
  c.v = *(const f16x8*)s2; d.v = *(const f16x8*)s3;
#pragma unroll
  for (int e = 0; e < 8; ++e)
    o.u[e] = f2h(0.25f * (h2f(a.u[e]) + h2f(bq.u[e]) + h2f(c.u[e]) + h2f(d.u[e])));
  *(f16x8*)&out[((size_t)b * 1024 + pp) * 256 + 8 * oct] = o.v;
}

// ---------------- MFMA f16 conv1x1, pixel-major X (BM=64 oc x BN=128 p, BK=64) ----------------
// MODE bits: 1 = bn affine, 2 = cbn, 4 = add addbuf(f32, chan-major), 8 = prelu
template <int MODE, bool OUT32>
__global__ void __launch_bounds__(256) conv_mfma_kernel(
    const ushort* __restrict__ X, const ushort* __restrict__ W16,
    void* __restrict__ Yv, int Cin, int Cout, int P,
    const float* __restrict__ bn, const float* __restrict__ sb,
    const float* __restrict__ alpha, const float* __restrict__ addbuf) {
  const int tid = threadIdx.x;
  const int p0 = blockIdx.x * 128;
  const int o0 = blockIdx.y * 64;
  const int b  = blockIdx.z;
  const int lane = tid & 63;
  const int wv = tid >> 6;
  const int m = lane & 15, h = lane >> 4;
  const int wr = wv >> 1, wc = wv & 1;

  __shared__ __align__(16) char smem[27648];
  ushort (*Xs)[72] = (ushort(*)[72])smem;             // [128][72]
  ushort (*Ws)[72] = (ushort(*)[72])(smem + 18432);   // [64][72]
  ushort (*Es)[72] = (ushort(*)[72])smem;             // epilogue overlay [128][72]

  f32x4 acc[2][4];
#pragma unroll
  for (int i = 0; i < 2; ++i)
#pragma unroll
    for (int j = 0; j < 4; ++j) acc[i][j] = (f32x4){0.f, 0.f, 0.f, 0.f};

  const ushort* Xb = X + (size_t)b * P * Cin;

  for (int k0 = 0; k0 < Cin; k0 += 64) {
    __syncthreads();
#pragma unroll
    for (int r = 0; r < 4; ++r) {
      int e = tid + 256 * r;
      int pp = e >> 3, ch = e & 7;
      *(f16x8*)&Xs[pp][8 * ch] =
          *(const f16x8*)&Xb[(size_t)(p0 + pp) * Cin + k0 + 8 * ch];
    }
#pragma unroll
    for (int r = 0; r < 2; ++r) {
      int e = tid + 256 * r;
      int oc = e >> 3, ch = e & 7;
      *(f16x8*)&Ws[oc][8 * ch] =
          *(const f16x8*)&W16[(size_t)(o0 + oc) * Cin + k0 + 8 * ch];
    }
    __syncthreads();
#pragma unroll
    for (int ks = 0; ks < 2; ++ks) {
      f16x8 af[2], bf[4];
#pragma unroll
      for (int t = 0; t < 2; ++t) af[t] = *(const f16x8*)&Ws[32 * wr + 16 * t + m][32 * ks + 8 * h];
#pragma unroll
      for (int t = 0; t < 4; ++t) bf[t] = *(const f16x8*)&Xs[64 * wc + 16 * t + m][32 * ks + 8 * h];
#pragma unroll
      for (int ta = 0; ta < 2; ++ta)
#pragma unroll
        for (int tb = 0; tb < 4; ++tb)
          acc[ta][tb] = __builtin_amdgcn_mfma_f32_16x16x32_f16(af[ta], bf[tb], acc[ta][tb], 0, 0, 0);
    }
  }

  float scl[2][4], shf[2][4];
#pragma unroll
  for (int ta = 0; ta < 2; ++ta)
#pragma unroll
    for (int r = 0; r < 4; ++r) {
      int oc = o0 + 32 * wr + 16 * ta + 4 * h + r;
      float scale = 1.f, shift = 0.f;
      if (MODE & 1) {
        float sc = bn[oc] * rsqrtf(bn[3 * Cout + oc] + EPS_F);
        scale = sc;
        shift = bn[Cout + oc] - bn[2 * Cout + oc] * sc;
      }
      if (MODE & 2) {
        float ss = sb[b * 2 * Cout + oc];
        float bb = sb[b * 2 * Cout + Cout + oc];
        scale *= ss;
        shift = shift * ss + bb;
      }
      scl[ta][r] = scale; shf[ta][r] = shift;
    }
  float al = (MODE & 8) ? *alpha : 0.f;

  if (OUT32) {
    float* Y32 = (float*)Yv;
#pragma unroll
    for (int ta = 0; ta < 2; ++ta)
#pragma unroll
      for (int tb = 0; tb < 4; ++tb)
#pragma unroll
        for (int r = 0; r < 4; ++r) {
          int oc = o0 + 32 * wr + 16 * ta + 4 * h + r;
          int p  = p0 + 64 * wc + 16 * tb + m;
          float v = acc[ta][tb][r] * scl[ta][r] + shf[ta][r];
          size_t o = ((size_t)b * Cout + oc) * P + p;
          if (MODE & 4) v += addbuf[o];
          if (MODE & 8) v = v > 0.f ? v : al * v;
          Y32[o] = v;
        }
  } else {
    ushort* Y16 = (ushort*)Yv;
    __syncthreads();
#pragma unroll
    for (int ta = 0; ta < 2; ++ta)
#pragma unroll
      for (int tb = 0; tb < 4; ++tb)
#pragma unroll
        for (int r = 0; r < 4; ++r) {
          float v = acc[ta][tb][r] * scl[ta][r] + shf[ta][r];
          if (MODE & 8) v = v > 0.f ? v : al * v;
          Es[64 * wc + 16 * tb + m][32 * wr + 16 * ta + 4 * h + r] = f2h(v);
        }
    __syncthreads();
#pragma unroll
    for (int r = 0; r < 4; ++r) {
      int e = tid + 256 * r;
      int pp = e >> 3, q = e & 7;
      *(f16x8*)&Y16[((size_t)b * P + p0 + pp) * Cout + o0 + 8 * q] =
          *(const f16x8*)&Es[pp][8 * q];
    }
  }
}

// ---------------- axial attention, all-MFMA f16, pixel-major in/out ----------------
// Input qkv (b, p, 512) with p = i*64 + d1 (i = attended dim).
// Output out (b, p', 256) with p' = d1*64 + i.
__global__ void __launch_bounds__(256) axial_attn_kernel(
    const ushort* __restrict__ qkv, const ushort* __restrict__ relimg,
    const float* __restrict__ bn_sim, const float* __restrict__ bn_out,
    ushort* __restrict__ out16) {
  const int tid = threadIdx.x;
  int lin = blockIdx.x;                       // bijective XCD swizzle
  int wg = ((lin & 7) << 9) + (lin >> 3);
  const int g  = wg >> 8;
  const int bd = wg & 255;
  const int b  = bd >> 6;
  const int d1 = bd & 63;

  __shared__ __align__(16) char smem[37888];
  // relQ [128][20] @0 | relK [128][20] @5120 | QK [64][24] @10240
  // QE [64][72] @13312 | KE [64][72] @22528 | VC [16][64] swz @31744
  // RV [16][128] swz @33792 | A2 [64][136] @0 overlay
#define RQA(d, c)  (smem + (d) * 40 + (c) * 2)
#define RKA(d, c)  (smem + 5120 + (d) * 40 + (c) * 2)
#define QKA(i, c)  (smem + 10240 + (i) * 48 + (c) * 2)
#define QEA(i, k)  (smem + 13312 + (i) * 144 + (k) * 2)
#define KEA(j, k)  (smem + 22528 + (j) * 144 + (k) * 2)
#define VCA(c, j)  (smem + 31744 + ((((c) * 128 + (j) * 2)) ^ (((c) & 7) << 4)))
#define RVA(c, d)  (smem + 33792 + ((((c) * 256 + (d) * 2)) ^ (((c) & 7) << 4)))
#define A2A(i, d)  (smem + (i) * 272 + (d) * 2)

  const int lane = tid & 63;
  const int wv   = tid >> 6;
  const int m    = lane & 15;
  const int h    = lane >> 4;

  // ---- P0a: issue qkv load; linear copy of precomputed rel images ----
  const int i_ld = tid >> 2, quad = tid & 3;
  f16x8 vld = *(const f16x8*)&qkv[((size_t)b * 4096 + i_ld * 64 + d1) * 512 + g * 32 + 8 * quad];
  {
    const uint4* img = (const uint4*)relimg;
    for (int u = tid; u < 640; u += 256) ((uint4*)smem)[u] = img[u];          // relQ+relK
    ((uint4*)(smem + 33792))[tid] = img[640 + tid];                           // RV
  }
  __syncthreads();

  // ---- P0b: QK direct copy; V scatter into VC ----
  if (quad < 2) {
    *(f16x8*)QKA(i_ld, 8 * quad) = vld;
  } else {
    U16x8 u; u.v = vld;
    int c0 = 8 * (quad - 2);
#pragma unroll
    for (int e = 0; e < 8; ++e) *(ushort*)VCA(c0 + e, i_ld) = u.u[e];
  }
  __syncthreads();

  // ---- P1: band-restricted emb GEMM -> dense QE/KE ----
  // wave wv owns n-tile nt=wv; valid tiles dt = nt+k, k in [0,4]
  {
    const int nt = wv;
    const int n = 16 * nt + m;
    f16x4 bqk = *(const f16x4*)QKA(n, 4 * h);
#pragma unroll
    for (int k = 0; k < 5; ++k) {
      int dt = nt + k;
      f16x4 arQ = *(const f16x4*)RQA(16 * dt + m, 4 * h);
      f16x4 arK = *(const f16x4*)RKA(16 * dt + m, 4 * h);
      f32x4 dq = __builtin_amdgcn_mfma_f32_16x16x16f16(arQ, bqk, (f32x4){0.f,0.f,0.f,0.f}, 0, 0, 0);
      f32x4 dk = __builtin_amdgcn_mfma_f32_16x16x16f16(arK, bqk, (f32x4){0.f,0.f,0.f,0.f}, 0, 0, 0);
#pragma unroll
      for (int r = 0; r < 4; ++r) {
        int d = 16 * dt + 4 * h + r;
        int i = n - d + 63;
        if (k == 0 || k == 4) {
          if ((unsigned)i < 64u) {
            *(ushort*)QEA(i, n) = f2h(dq[r]);
            *(ushort*)KEA(i, n) = f2h(dk[r]);
          }
        } else {
          *(ushort*)QEA(i, n) = f2h(dq[r]);
          *(ushort*)KEA(i, n) = f2h(dk[r]);
        }
      }
    }
  }
  __syncthreads();

  // ---- P2: sim = s_qk*(qk) + s_qe*q_emb + s_ke*k_emb + sh ----
  f32x4 acc[4];
#pragma unroll
  for (int tj = 0; tj < 4; ++tj) acc[tj] = (f32x4){0.f, 0.f, 0.f, 0.f};
  {
    const int ia = 16 * wv + m;
    f16x8 af0 = *(const f16x8*)QEA(ia, 8 * h);
    f16x8 af1 = *(const f16x8*)QEA(ia, 32 + 8 * h);
#pragma unroll
    for (int tj = 0; tj < 4; ++tj) {
      int j = 16 * tj + m;
      f16x8 bf0 = *(const f16x8*)KEA(j, 8 * h);
      f16x8 bf1 = *(const f16x8*)KEA(j, 32 + 8 * h);
      acc[tj] = __builtin_amdgcn_mfma_f32_16x16x32_f16(af0, bf0, acc[tj], 0, 0, 0);
      acc[tj] = __builtin_amdgcn_mfma_f32_16x16x32_f16(af1, bf1, acc[tj], 0, 0, 0);
    }
  }

  float s_qk = bn_sim[g]      * rsqrtf(bn_sim[144 + g] + EPS_F);
  float s_qe = bn_sim[16 + g] * rsqrtf(bn_sim[160 + g] + EPS_F);
  float s_ke = bn_sim[32 + g] * rsqrtf(bn_sim[176 + g] + EPS_F);
  float sh   = (bn_sim[48 + g] - bn_sim[96 + g]  * s_qk)
             + (bn_sim[64 + g] - bn_sim[112 + g] * s_qe)
             + (bn_sim[80 + g] - bn_sim[128 + g] * s_ke);

  const int ib = 16 * wv + 4 * h;
  float sv[4][4];
#pragma unroll
  for (int tj = 0; tj < 4; ++tj) {
    int j = 16 * tj + m;
    f16x4 qe4 = *(const f16x4*)QEA(j, ib);
    f16x4 ke4 = *(const f16x4*)KEA(j, ib);
#pragma unroll
    for (int r = 0; r < 4; ++r)
      sv[tj][r] = acc[tj][r] * s_qk + (float)qe4[r] * s_qe + (float)ke4[r] * s_ke + sh;
  }

  // ---- P3: softmax over j ----
  float p[4][4];
  {
    float mx[4];
#pragma unroll
    for (int r = 0; r < 4; ++r) {
      float v = fmaxf(fmaxf(sv[0][r], sv[1][r]), fmaxf(sv[2][r], sv[3][r]));
      v = fmaxf(v, __shfl_xor(v, 1));
      v = fmaxf(v, __shfl_xor(v, 2));
      v = fmaxf(v, __shfl_xor(v, 4));
      v = fmaxf(v, __shfl_xor(v, 8));
      mx[r] = v;
    }
#pragma unroll
    for (int r = 0; r < 4; ++r) {
      float ssum = 0.f;
#pragma unroll
      for (int tj = 0; tj < 4; ++tj) {
        p[tj][r] = __expf(sv[tj][r] - mx[r]);
        ssum += p[tj][r];
      }
      ssum += __shfl_xor(ssum, 1);
      ssum += __shfl_xor(ssum, 2);
      ssum += __shfl_xor(ssum, 4);
      ssum += __shfl_xor(ssum, 8);
      float inv = 1.f / ssum;
#pragma unroll
      for (int tj = 0; tj < 4; ++tj) p[tj][r] *= inv;
    }
  }

  // ---- P4: zero A2 (overlay), scatter P diagonally ----
  __syncthreads();
  {
    uint4 z = make_uint4(0u, 0u, 0u, 0u);
    for (int u2 = tid; u2 < 1088; u2 += 256) ((uint4*)smem)[u2] = z;
  }
  __syncthreads();
#pragma unroll
  for (int tj = 0; tj < 4; ++tj) {
    int j = 16 * tj + m;
#pragma unroll
    for (int r = 0; r < 4; ++r) {
      int i = ib + r;
      *(ushort*)A2A(i, i - j + 63) = f2h(p[tj][r]);
    }
  }

  // ---- P5: att / att_e ----
  f32x4 accA = (f32x4){0.f, 0.f, 0.f, 0.f};
  f32x4 accE = (f32x4){0.f, 0.f, 0.f, 0.f};
  {
    const int ia = 16 * wv + m;
#pragma unroll
    for (int ks = 0; ks < 2; ++ks) {
      U16x8 pa;
#pragma unroll
      for (int e = 0; e < 8; ++e) {
        int j = 32 * ks + 8 * h + e;
        pa.u[e] = *(ushort*)A2A(ia, ia - j + 63);
      }
      f16x8 vb = *(const f16x8*)VCA(m, 32 * ks + 8 * h);
      accA = __builtin_amdgcn_mfma_f32_16x16x32_f16(pa.v, vb, accA, 0, 0, 0);
    }
#pragma unroll
    for (int ks = 0; ks < 4; ++ks) {
      f16x8 pe = *(const f16x8*)A2A(ia, 32 * ks + 8 * h);
      f16x8 rv = *(const f16x8*)RVA(m, 32 * ks + 8 * h);
      accE = __builtin_amdgcn_mfma_f32_16x16x32_f16(pe, rv, accE, 0, 0, 0);
    }
  }

  // ---- P6: fold bn_out, pixel-major write ----
  {
    int oc = g * 16 + m;
    int c0 = 2 * oc, c1 = c0 + 1;
    float sc0 = bn_out[c0] * rsqrtf(bn_out[1536 + c0] + EPS_F);
    float sh0 = bn_out[512 + c0] - bn_out[1024 + c0] * sc0;
    float sc1 = bn_out[c1] * rsqrtf(bn_out[1536 + c1] + EPS_F);
    float sh1 = bn_out[512 + c1] - bn_out[1024 + c1] * sc1;
    float vv[4];
    vv[0] = accA[0] * sc0 + accE[0] * sc1 + sh0 + sh1;
    vv[1] = accA[1] * sc0 + accE[1] * sc1 + sh0 + sh1;
    vv[2] = accA[2] * sc0 + accE[2] * sc1 + sh0 + sh1;
    vv[3] = accA[3] * sc0 + accE[3] * sc1 + sh0 + sh1;
    size_t base = ((size_t)b * 4096 + (size_t)d1 * 64 + ib) * 256 + oc;
#pragma unroll
    for (int r = 0; r < 4; ++r)
      out16[base + (size_t)r * 256] = f2h(vv[r]);
  }
#undef RQA
#undef RKA
#undef QKA
#undef QEA
#undef KEA
#undef VCA
#undef RVA
#undef A2A
}

extern "C" void kernel_launch(void* const* d_in, const int* in_sizes, int n_in,
                              void* d_out, int out_size, void* d_ws, size_t ws_size,
                              hipStream_t stream) {
  const float* x         = (const float*)d_in[0];
  const float* latent    = (const float*)d_in[1];
  const float* w_in      = (const float*)d_in[2];
  const float* bn_in     = (const float*)d_in[3];
  const float* lin_in    = (const float*)d_in[4];
  const float* alpha_in  = (const float*)d_in[5];
  const float* a0_wqkv   = (const float*)d_in[6];
  const float* a0_bn_qkv = (const float*)d_in[7];
  const float* a0_bn_sim = (const float*)d_in[8];
  const float* a0_bn_out = (const float*)d_in[9];
  const float* a0_rel    = (const float*)d_in[10];
  const float* a1_wqkv   = (const float*)d_in[11];
  const float* a1_bn_qkv = (const float*)d_in[12];
  const float* a1_bn_sim = (const float*)d_in[13];
  const float* a1_bn_out = (const float*)d_in[14];
  const float* a1_rel    = (const float*)d_in[15];
  const float* w_out     = (const float*)d_in[16];
  const float* bn_outp   = (const float*)d_in[17];
  const float* lin_out   = (const float*)d_in[18];
  const float* w_res     = (const float*)d_in[19];
  const float* alpha_fin = (const float*)d_in[20];

  float* ws = (float*)d_ws;
  float* sb_in  = ws;                          // 2048 f
  float* sb_out = ws + 2048;                   // 2048 f
  ushort* w16   = (ushort*)(ws + 4096);        // 393216 u16
  ushort* relimg = w16 + 393216;               // 14336 u16 (2 x 7168)
  ushort* x16   = relimg + 14336;              // 2097152 u16 (b,4096,128)
  ushort* t0    = x16 + 2097152;               // 4194304 u16 (b,4096,256)
  ushort* qkvb  = t0 + 4194304;                // 8388608 u16 (b,4096,512)
  ushort* pool_o = qkvb + 8388608;             // 1048576 u16 (b,1024,256)
  ushort* pool_x = pool_o + 1048576;           // 524288 u16  (b,1024,128)
  float* resb   = (float*)(pool_x + 524288);   // 1048576 f   (b,256,1024)

  ushort* w_in16  = w16;
  ushort* a0w16   = w16 + 32768;
  ushort* a1w16   = w16 + 163840;
  ushort* w_out16 = w16 + 294912;
  ushort* w_res16 = w16 + 360448;
  ushort* rimg_a  = relimg;
  ushort* rimg_b  = relimg + 7168;

  prep_kernel<<<1608, 256, 0, stream>>>(w_in, a0_wqkv, a1_wqkv, w_out, w_res,
                                        latent, lin_in, lin_out, a0_rel, a1_rel,
                                        w16, relimg, sb_in, sb_out);
  cvtT_kernel<<<dim3(32, 4, 4), 256, 0, stream>>>(x, x16);

  // conv_in + cbn + prelu -> t0 (pixel-major, p = h*64+w)
  conv_mfma_kernel<11, false><<<dim3(32, 4, 4), 256, 0, stream>>>(
      x16, w_in16, t0, 128, 256, 4096, bn_in, sb_in, alpha_in, nullptr);

  // axial 0 over H (i=h, d1=w): out p = w*64+h
  conv_mfma_kernel<1, false><<<dim3(32, 8, 4), 256, 0, stream>>>(
      t0, a0w16, qkvb, 256, 512, 4096, a0_bn_qkv, nullptr, nullptr, nullptr);
  axial_attn_kernel<<<4096, 256, 0, stream>>>(
      qkvb, rimg_a, a0_bn_sim, a0_bn_out, t0);

  // axial 1 over W (i=w, d1=h): out p = h*64+w (std)
  conv_mfma_kernel<1, false><<<dim3(32, 8, 4), 256, 0, stream>>>(
      t0, a1w16, qkvb, 256, 512, 4096, a1_bn_qkv, nullptr, nullptr, nullptr);
  axial_attn_kernel<<<4096, 256, 0, stream>>>(
      qkvb, rimg_b, a1_bn_sim, a1_bn_out, t0);

  // pools
  pool16_kernel<<<512, 256, 0, stream>>>(t0, pool_o);
  poolx_kernel<<<dim3(32, 4, 4), 256, 0, stream>>>(x, pool_x);

  // residual conv (f32 chan-major out)
  conv_mfma_kernel<0, true><<<dim3(8, 4, 4), 256, 0, stream>>>(
      pool_x, w_res16, resb, 128, 256, 1024, nullptr, nullptr, nullptr, nullptr);

  // final conv + cbn + add res + prelu -> d_out (f32 chan-major)
  conv_mfma_kernel<15, true><<<dim3(8, 4, 4), 256, 0, stream>>>(
      pool_o, w_out16, d_out, 256, 256, 1024, bn_outp, sb_out, alpha_fin, resb);
}

// Round 11
// 140.804 us; speedup vs baseline: 3.7580x; 1.0273x over previous
//
#include <hip/hip_runtime.h>
#include <hip/hip_bf16.h>

#define EPS_F 1e-5f

typedef __attribute__((ext_vector_type(8))) _Float16 f16x8;
typedef __attribute__((ext_vector_type(4))) _Float16 f16x4;
typedef __attribute__((ext_vector_type(4))) float f32x4;

union U16x8 { ushort u[8]; _Float16 h[8]; f16x8 v; };

static __device__ inline ushort f2h(float f) {
  _Float16 h = (_Float16)f;
  return __builtin_bit_cast(ushort, h);
}
static __device__ inline float h2f(ushort u) {
  return (float)__builtin_bit_cast(_Float16, u);
}

// ---------------- prep: weights->f16, sb, rel images, cvtT(x), poolx(x) ----------------
// grid: [0,1608) weights/sb/relimg ; [1608,2120) cvtT ; [2120,2632) poolx
__global__ void __launch_bounds__(256) prep_kernel(
    const float* __restrict__ w_in, const float* __restrict__ a0w,
    const float* __restrict__ a1w, const float* __restrict__ w_out,
    const float* __restrict__ w_res,
    const float* __restrict__ latent, const float* __restrict__ lin_in,
    const float* __restrict__ lin_out,
    const float* __restrict__ a0_rel, const float* __restrict__ a1_rel,
    const float* __restrict__ x,
    ushort* __restrict__ w16, ushort* __restrict__ relimg,
    float* __restrict__ sb_in, float* __restrict__ sb_out,
    ushort* __restrict__ x16, ushort* __restrict__ pool_x) {
  const int gid = blockIdx.x;
  const int tid = threadIdx.x;
  __shared__ __align__(16) char lsm[10240];

  if (gid < 1608) {
    int idx = gid * 256 + tid;
    if (idx < 393216) {
      const float* src; int off;
      if (idx < 32768)       { src = w_in;  off = 0; }
      else if (idx < 163840) { src = a0w;   off = 32768; }
      else if (idx < 294912) { src = a1w;   off = 163840; }
      else if (idx < 360448) { src = w_out; off = 294912; }
      else                   { src = w_res; off = 360448; }
      w16[idx] = f2h(src[idx - off]);
    } else if (idx < 397312) {
      int r = idx - 393216;
      int which = r >> 11;
      int rr = r & 2047;
      int b = rr >> 9, k = rr & 511;
      const float* lin = which ? lin_out : lin_in;
      const float* lv = latent + b * 256;
      const float* lr = lin + k * 256;
      float acc = 0.f;
#pragma unroll 8
      for (int l = 0; l < 256; ++l) acc += lv[l] * lr[l];
      (which ? sb_out : sb_in)[b * 512 + k] = acc;
    } else if (idx < 411648) {
      int e = idx - 397312;
      int which = e >= 7168;
      int s = which ? e - 7168 : e;
      const float* rel = which ? a1_rel : a0_rel;
      ushort val = 0;
      if (s < 2560) {                  // relQ image [128][20], c<8
        int d = s / 20, c = s % 20;
        if (c < 8 && d < 127) val = f2h(rel[c * 127 + d]);
      } else if (s < 5120) {           // relK image, c in 8..15
        int s2 = s - 2560;
        int d = s2 / 20, c = s2 % 20;
        if (c >= 8 && c < 16 && d < 127) val = f2h(rel[c * 127 + d]);
      } else {                         // RV swizzled image
        int pos = (s - 5120) * 2;
        int c = pos >> 8;
        int inner = (pos & 255) ^ ((c & 7) << 4);
        int d = inner >> 1;
        if (d < 127) val = f2h(rel[(16 + c) * 127 + d]);
      }
      relimg[which * 7168 + s] = val;
    }
  } else if (gid < 2120) {
    // cvtT: x f32 (b,128,4096) -> x16 (b,4096,128)
    int e = gid - 1608;
    int pt = e & 31, ct = (e >> 5) & 3, b = e >> 7;
    ushort (*Lt)[40] = (ushort(*)[40])lsm;
#pragma unroll
    for (int r = 0; r < 16; ++r) {
      int e2 = tid + 256 * r;
      int c = e2 >> 7, p = e2 & 127;
      Lt[p][c] = f2h(x[((size_t)(b * 128 + ct * 32 + c)) * 4096 + pt * 128 + p]);
    }
    __syncthreads();
#pragma unroll
    for (int r = 0; r < 2; ++r) {
      int e2 = tid + 256 * r;
      int p = e2 >> 2, q = e2 & 3;
      *(f16x8*)&x16[((size_t)b * 4096 + pt * 128 + p) * 128 + ct * 32 + 8 * q] =
          *(const f16x8*)&Lt[p][8 * q];
    }
  } else {
    // poolx: x f32 -> pool_x (b,1024,128) f16
    int e = gid - 2120;
    int ip = e & 31, ct = (e >> 5) & 3, b = e >> 7;
    float (*Lp)[33] = (float(*)[33])lsm;
    {
      int c = tid >> 3, grp = tid & 7;
      const float* base = x + ((size_t)(b * 128 + ct * 32 + c)) * 4096 + (2 * ip) * 64 + 8 * grp;
      float4 a0 = *(const float4*)&base[0];
      float4 a1 = *(const float4*)&base[4];
      float4 b0 = *(const float4*)&base[64];
      float4 b1 = *(const float4*)&base[68];
      Lp[c][4 * grp + 0] = 0.25f * (a0.x + a0.y + b0.x + b0.y);
      Lp[c][4 * grp + 1] = 0.25f * (a0.z + a0.w + b0.z + b0.w);
      Lp[c][4 * grp + 2] = 0.25f * (a1.x + a1.y + b1.x + b1.y);
      Lp[c][4 * grp + 3] = 0.25f * (a1.z + a1.w + b1.z + b1.w);
    }
    __syncthreads();
    {
      int jp = tid >> 3, q = tid & 7;
      ushort4 o;
      o.x = f2h(Lp[4 * q + 0][jp]);
      o.y = f2h(Lp[4 * q + 1][jp]);
      o.z = f2h(Lp[4 * q + 2][jp]);
      o.w = f2h(Lp[4 * q + 3][jp]);
      *(ushort4*)&pool_x[((size_t)b * 1024 + ip * 32 + jp) * 128 + ct * 32 + 4 * q] = o;
    }
  }
}

// ---------------- MFMA f16 conv1x1, pixel-major X (BM=64 oc x BN=128 p, BK=64) ----------------
// MODE bits: 1 = bn affine, 2 = cbn, 8 = prelu
template <int MODE>
__global__ void __launch_bounds__(256) conv_mfma_kernel(
    const ushort* __restrict__ X, const ushort* __restrict__ W16,
    ushort* __restrict__ Y16, int Cin, int Cout, int P,
    const float* __restrict__ bn, const float* __restrict__ sb,
    const float* __restrict__ alpha) {
  const int tid = threadIdx.x;
  const int p0 = blockIdx.x * 128;
  const int o0 = blockIdx.y * 64;
  const int b  = blockIdx.z;
  const int lane = tid & 63;
  const int wv = tid >> 6;
  const int m = lane & 15, h = lane >> 4;
  const int wr = wv >> 1, wc = wv & 1;

  __shared__ __align__(16) char smem[27648];
  ushort (*Xs)[72] = (ushort(*)[72])smem;             // [128][72]
  ushort (*Ws)[72] = (ushort(*)[72])(smem + 18432);   // [64][72]
  ushort (*Es)[72] = (ushort(*)[72])smem;             // epilogue overlay

  f32x4 acc[2][4];
#pragma unroll
  for (int i = 0; i < 2; ++i)
#pragma unroll
    for (int j = 0; j < 4; ++j) acc[i][j] = (f32x4){0.f, 0.f, 0.f, 0.f};

  const ushort* Xb = X + (size_t)b * P * Cin;

  for (int k0 = 0; k0 < Cin; k0 += 64) {
    __syncthreads();
#pragma unroll
    for (int r = 0; r < 4; ++r) {
      int e = tid + 256 * r;
      int pp = e >> 3, ch = e & 7;
      *(f16x8*)&Xs[pp][8 * ch] =
          *(const f16x8*)&Xb[(size_t)(p0 + pp) * Cin + k0 + 8 * ch];
    }
#pragma unroll
    for (int r = 0; r < 2; ++r) {
      int e = tid + 256 * r;
      int oc = e >> 3, ch = e & 7;
      *(f16x8*)&Ws[oc][8 * ch] =
          *(const f16x8*)&W16[(size_t)(o0 + oc) * Cin + k0 + 8 * ch];
    }
    __syncthreads();
#pragma unroll
    for (int ks = 0; ks < 2; ++ks) {
      f16x8 af[2], bf[4];
#pragma unroll
      for (int t = 0; t < 2; ++t) af[t] = *(const f16x8*)&Ws[32 * wr + 16 * t + m][32 * ks + 8 * h];
#pragma unroll
      for (int t = 0; t < 4; ++t) bf[t] = *(const f16x8*)&Xs[64 * wc + 16 * t + m][32 * ks + 8 * h];
#pragma unroll
      for (int ta = 0; ta < 2; ++ta)
#pragma unroll
        for (int tb = 0; tb < 4; ++tb)
          acc[ta][tb] = __builtin_amdgcn_mfma_f32_16x16x32_f16(af[ta], bf[tb], acc[ta][tb], 0, 0, 0);
    }
  }

  float scl[2][4], shf[2][4];
#pragma unroll
  for (int ta = 0; ta < 2; ++ta)
#pragma unroll
    for (int r = 0; r < 4; ++r) {
      int oc = o0 + 32 * wr + 16 * ta + 4 * h + r;
      float scale = 1.f, shift = 0.f;
      if (MODE & 1) {
        float sc = bn[oc] * rsqrtf(bn[3 * Cout + oc] + EPS_F);
        scale = sc;
        shift = bn[Cout + oc] - bn[2 * Cout + oc] * sc;
      }
      if (MODE & 2) {
        float ss = sb[b * 2 * Cout + oc];
        float bb = sb[b * 2 * Cout + Cout + oc];
        scale *= ss;
        shift = shift * ss + bb;
      }
      scl[ta][r] = scale; shf[ta][r] = shift;
    }
  float al = (MODE & 8) ? *alpha : 0.f;

  __syncthreads();
#pragma unroll
  for (int ta = 0; ta < 2; ++ta)
#pragma unroll
    for (int tb = 0; tb < 4; ++tb)
#pragma unroll
      for (int r = 0; r < 4; ++r) {
        float v = acc[ta][tb][r] * scl[ta][r] + shf[ta][r];
        if (MODE & 8) v = v > 0.f ? v : al * v;
        Es[64 * wc + 16 * tb + m][32 * wr + 16 * ta + 4 * h + r] = f2h(v);
      }
  __syncthreads();
#pragma unroll
  for (int r = 0; r < 4; ++r) {
    int e = tid + 256 * r;
    int pp = e >> 3, q = e & 7;
    *(f16x8*)&Y16[((size_t)b * P + p0 + pp) * Cout + o0 + 8 * q] =
        *(const f16x8*)&Es[pp][8 * q];
  }
}

// ---------------- fused final: pool(t0)·W_out (cbn) + pool_x·W_res, prelu, f32 out ----------------
// grid (8, 4, 4). Output d_out (b,256,1024) f32 chan-major.
__global__ void __launch_bounds__(256) final_fused_kernel(
    const ushort* __restrict__ t0, const ushort* __restrict__ pool_x,
    const ushort* __restrict__ Wo, const ushort* __restrict__ Wr,
    float* __restrict__ Y32,
    const float* __restrict__ bn, const float* __restrict__ sb,
    const float* __restrict__ alpha) {
  const int tid = threadIdx.x;
  const int p0 = blockIdx.x * 128;
  const int o0 = blockIdx.y * 64;
  const int b  = blockIdx.z;
  const int lane = tid & 63;
  const int wv = tid >> 6;
  const int m = lane & 15, h = lane >> 4;
  const int wr = wv >> 1, wc = wv & 1;

  __shared__ __align__(16) char smem[27648];
  ushort (*Xs)[72] = (ushort(*)[72])smem;
  ushort (*Ws)[72] = (ushort(*)[72])(smem + 18432);

  f32x4 acc1[2][4], acc2[2][4];
#pragma unroll
  for (int i = 0; i < 2; ++i)
#pragma unroll
    for (int j = 0; j < 4; ++j) {
      acc1[i][j] = (f32x4){0.f, 0.f, 0.f, 0.f};
      acc2[i][j] = (f32x4){0.f, 0.f, 0.f, 0.f};
    }

  // ---- phase A: pooled t0 (Cin=256) @ W_out -> acc1 ----
  for (int k0 = 0; k0 < 256; k0 += 64) {
    __syncthreads();
#pragma unroll
    for (int r = 0; r < 4; ++r) {
      int e = tid + 256 * r;
      int pp = e >> 3, ch = e & 7;
      int pg = p0 + pp;                       // pooled pixel in [0,1024)
      int ip = pg >> 5, jp = pg & 31;
      size_t tb = ((size_t)b * 4096 + ip * 128 + jp * 2) * 256 + k0 + 8 * ch;
      U16x8 a, bb, c, d, o;
      a.v  = *(const f16x8*)&t0[tb];
      bb.v = *(const f16x8*)&t0[tb + 256];
      c.v  = *(const f16x8*)&t0[tb + 64 * 256];
      d.v  = *(const f16x8*)&t0[tb + 65 * 256];
#pragma unroll
      for (int e2 = 0; e2 < 8; ++e2)
        o.h[e2] = ((a.h[e2] + bb.h[e2]) + (c.h[e2] + d.h[e2])) * (_Float16)0.25f;
      *(f16x8*)&Xs[pp][8 * ch] = o.v;
    }
#pragma unroll
    for (int r = 0; r < 2; ++r) {
      int e = tid + 256 * r;
      int oc = e >> 3, ch = e & 7;
      *(f16x8*)&Ws[oc][8 * ch] = *(const f16x8*)&Wo[(size_t)(o0 + oc) * 256 + k0 + 8 * ch];
    }
    __syncthreads();
#pragma unroll
    for (int ks = 0; ks < 2; ++ks) {
      f16x8 af[2], bf[4];
#pragma unroll
      for (int t = 0; t < 2; ++t) af[t] = *(const f16x8*)&Ws[32 * wr + 16 * t + m][32 * ks + 8 * h];
#pragma unroll
      for (int t = 0; t < 4; ++t) bf[t] = *(const f16x8*)&Xs[64 * wc + 16 * t + m][32 * ks + 8 * h];
#pragma unroll
      for (int ta = 0; ta < 2; ++ta)
#pragma unroll
        for (int tb2 = 0; tb2 < 4; ++tb2)
          acc1[ta][tb2] = __builtin_amdgcn_mfma_f32_16x16x32_f16(af[ta], bf[tb2], acc1[ta][tb2], 0, 0, 0);
    }
  }

  // ---- phase B: pool_x (Cin=128) @ W_res -> acc2 ----
  for (int k0 = 0; k0 < 128; k0 += 64) {
    __syncthreads();
#pragma unroll
    for (int r = 0; r < 4; ++r) {
      int e = tid + 256 * r;
      int pp = e >> 3, ch = e & 7;
      *(f16x8*)&Xs[pp][8 * ch] =
          *(const f16x8*)&pool_x[((size_t)b * 1024 + p0 + pp) * 128 + k0 + 8 * ch];
    }
#pragma unroll
    for (int r = 0; r < 2; ++r) {
      int e = tid + 256 * r;
      int oc = e >> 3, ch = e & 7;
      *(f16x8*)&Ws[oc][8 * ch] = *(const f16x8*)&Wr[(size_t)(o0 + oc) * 128 + k0 + 8 * ch];
    }
    __syncthreads();
#pragma unroll
    for (int ks = 0; ks < 2; ++ks) {
      f16x8 af[2], bf[4];
#pragma unroll
      for (int t = 0; t < 2; ++t) af[t] = *(const f16x8*)&Ws[32 * wr + 16 * t + m][32 * ks + 8 * h];
#pragma unroll
      for (int t = 0; t < 4; ++t) bf[t] = *(const f16x8*)&Xs[64 * wc + 16 * t + m][32 * ks + 8 * h];
#pragma unroll
      for (int ta = 0; ta < 2; ++ta)
#pragma unroll
        for (int tb2 = 0; tb2 < 4; ++tb2)
          acc2[ta][tb2] = __builtin_amdgcn_mfma_f32_16x16x32_f16(af[ta], bf[tb2], acc2[ta][tb2], 0, 0, 0);
    }
  }

  // ---- epilogue: cbn(acc1) + acc2, prelu, f32 chan-major ----
  const float al = *alpha;
#pragma unroll
  for (int ta = 0; ta < 2; ++ta)
#pragma unroll
    for (int r = 0; r < 4; ++r) {
      int oc = o0 + 32 * wr + 16 * ta + 4 * h + r;
      float sc = bn[oc] * rsqrtf(bn[768 + oc] + EPS_F);
      float shift = bn[256 + oc] - bn[512 + oc] * sc;
      float ss = sb[b * 512 + oc];
      float bb = sb[b * 512 + 256 + oc];
      float scale = sc * ss;
      shift = shift * ss + bb;
#pragma unroll
      for (int tb2 = 0; tb2 < 4; ++tb2) {
        int p = p0 + 64 * wc + 16 * tb2 + m;
        float v = acc1[ta][tb2][r] * scale + shift + acc2[ta][tb2][r];
        v = v > 0.f ? v : al * v;
        Y32[((size_t)b * 256 + oc) * 1024 + p] = v;
      }
    }
}

// ---------------- axial attention, all-MFMA f16, pixel-major, 3 barriers ----------------
// Input qkv (b, p, 512) with p = i*64 + d1. Output out (b, p', 256), p' = d1*64 + i.
__global__ void __launch_bounds__(256) axial_attn_kernel(
    const ushort* __restrict__ qkv, const ushort* __restrict__ relimg,
    const float* __restrict__ bn_sim, const float* __restrict__ bn_out,
    ushort* __restrict__ out16) {
  const int tid = threadIdx.x;
  int lin = blockIdx.x;                       // bijective XCD swizzle
  int wg = ((lin & 7) << 9) + (lin >> 3);
  const int g  = wg >> 8;
  const int bd = wg & 255;
  const int b  = bd >> 6;
  const int d1 = bd & 63;

  __shared__ __align__(16) char smem[37888];
#define RQA(d, c)  (smem + (d) * 40 + (c) * 2)
#define RKA(d, c)  (smem + 5120 + (d) * 40 + (c) * 2)
#define QKA(i, c)  (smem + 10240 + (i) * 48 + (c) * 2)
#define QEA(i, k)  (smem + 13312 + (i) * 144 + (k) * 2)
#define KEA(j, k)  (smem + 22528 + (j) * 144 + (k) * 2)
#define VCA(c, j)  (smem + 31744 + ((((c) * 128 + (j) * 2)) ^ (((c) & 7) << 4)))
#define RVA(c, d)  (smem + 33792 + ((((c) * 256 + (d) * 2)) ^ (((c) & 7) << 4)))
#define A2A(i, d)  (smem + (i) * 272 + (d) * 2)

  const int lane = tid & 63;
  const int wv   = tid >> 6;
  const int m    = lane & 15;
  const int h    = lane >> 4;

  // ---- P0: issue qkv load; copy rel images; scatter qkv (disjoint regions, no barrier) ----
  const int i_ld = tid >> 2, quad = tid & 3;
  f16x8 vld = *(const f16x8*)&qkv[((size_t)b * 4096 + i_ld * 64 + d1) * 512 + g * 32 + 8 * quad];
  {
    const uint4* img = (const uint4*)relimg;
    for (int u = tid; u < 640; u += 256) ((uint4*)smem)[u] = img[u];   // relQ+relK+QK-gap safe: relQ/relK only (640*16=10240)
    ((uint4*)(smem + 33792))[tid] = img[640 + tid];                    // RV
  }
  if (quad < 2) {
    *(f16x8*)QKA(i_ld, 8 * quad) = vld;
  } else {
    U16x8 u; u.v = vld;
    int c0 = 8 * (quad - 2);
#pragma unroll
    for (int e = 0; e < 8; ++e) *(ushort*)VCA(c0 + e, i_ld) = u.u[e];
  }
  __syncthreads();   // barrier A

  // ---- P1: band-restricted emb GEMM -> dense QE/KE ----
  {
    const int nt = wv;
    const int n = 16 * nt + m;
    f16x4 bqk = *(const f16x4*)QKA(n, 4 * h);
#pragma unroll
    for (int k = 0; k < 5; ++k) {
      int dt = nt + k;
      f16x4 arQ = *(const f16x4*)RQA(16 * dt + m, 4 * h);
      f16x4 arK = *(const f16x4*)RKA(16 * dt + m, 4 * h);
      f32x4 dq = __builtin_amdgcn_mfma_f32_16x16x16f16(arQ, bqk, (f32x4){0.f,0.f,0.f,0.f}, 0, 0, 0);
      f32x4 dk = __builtin_amdgcn_mfma_f32_16x16x16f16(arK, bqk, (f32x4){0.f,0.f,0.f,0.f}, 0, 0, 0);
#pragma unroll
      for (int r = 0; r < 4; ++r) {
        int d = 16 * dt + 4 * h + r;
        int i = n - d + 63;
        if (k == 0 || k == 4) {
          if ((unsigned)i < 64u) {
            *(ushort*)QEA(i, n) = f2h(dq[r]);
            *(ushort*)KEA(i, n) = f2h(dk[r]);
          }
        } else {
          *(ushort*)QEA(i, n) = f2h(dq[r]);
          *(ushort*)KEA(i, n) = f2h(dk[r]);
        }
      }
    }
  }
  __syncthreads();   // barrier B

  // ---- P2: sim ----
  f32x4 acc[4];
#pragma unroll
  for (int tj = 0; tj < 4; ++tj) acc[tj] = (f32x4){0.f, 0.f, 0.f, 0.f};
  {
    const int ia = 16 * wv + m;
    f16x8 af0 = *(const f16x8*)QEA(ia, 8 * h);
    f16x8 af1 = *(const f16x8*)QEA(ia, 32 + 8 * h);
#pragma unroll
    for (int tj = 0; tj < 4; ++tj) {
      int j = 16 * tj + m;
      f16x8 bf0 = *(const f16x8*)KEA(j, 8 * h);
      f16x8 bf1 = *(const f16x8*)KEA(j, 32 + 8 * h);
      acc[tj] = __builtin_amdgcn_mfma_f32_16x16x32_f16(af0, bf0, acc[tj], 0, 0, 0);
      acc[tj] = __builtin_amdgcn_mfma_f32_16x16x32_f16(af1, bf1, acc[tj], 0, 0, 0);
    }
  }

  float s_qk = bn_sim[g]      * rsqrtf(bn_sim[144 + g] + EPS_F);
  float s_qe = bn_sim[16 + g] * rsqrtf(bn_sim[160 + g] + EPS_F);
  float s_ke = bn_sim[32 + g] * rsqrtf(bn_sim[176 + g] + EPS_F);
  float sh   = (bn_sim[48 + g] - bn_sim[96 + g]  * s_qk)
             + (bn_sim[64 + g] - bn_sim[112 + g] * s_qe)
             + (bn_sim[80 + g] - bn_sim[128 + g] * s_ke);

  const int ib = 16 * wv + 4 * h;
  float sv[4][4];
#pragma unroll
  for (int tj = 0; tj < 4; ++tj) {
    int j = 16 * tj + m;
    f16x4 qe4 = *(const f16x4*)QEA(j, ib);
    f16x4 ke4 = *(const f16x4*)KEA(j, ib);
#pragma unroll
    for (int r = 0; r < 4; ++r)
      sv[tj][r] = acc[tj][r] * s_qk + (float)qe4[r] * s_qe + (float)ke4[r] * s_ke + sh;
  }

  // ---- P3: softmax over j ----
  float p[4][4];
  {
    float mx[4];
#pragma unroll
    for (int r = 0; r < 4; ++r) {
      float v = fmaxf(fmaxf(sv[0][r], sv[1][r]), fmaxf(sv[2][r], sv[3][r]));
      v = fmaxf(v, __shfl_xor(v, 1));
      v = fmaxf(v, __shfl_xor(v, 2));
      v = fmaxf(v, __shfl_xor(v, 4));
      v = fmaxf(v, __shfl_xor(v, 8));
      mx[r] = v;
    }
#pragma unroll
    for (int r = 0; r < 4; ++r) {
      float ssum = 0.f;
#pragma unroll
      for (int tj = 0; tj < 4; ++tj) {
        p[tj][r] = __expf(sv[tj][r] - mx[r]);
        ssum += p[tj][r];
      }
      ssum += __shfl_xor(ssum, 1);
      ssum += __shfl_xor(ssum, 2);
      ssum += __shfl_xor(ssum, 4);
      ssum += __shfl_xor(ssum, 8);
      float inv = 1.f / ssum;
#pragma unroll
      for (int tj = 0; tj < 4; ++tj) p[tj][r] *= inv;
    }
  }

  __syncthreads();   // barrier C (QE/KE reads done before A2 overlay)

  // ---- P4: wave-private zero of A2 rows [16wv,16wv+16), then scatter (no barrier) ----
  {
    uint4 z = make_uint4(0u, 0u, 0u, 0u);
    uint4* base = (uint4*)(smem + wv * 4352);   // 16 rows * 272 B = 4352 B = 272 uint4
#pragma unroll
    for (int u = 0; u < 4; ++u) base[lane + 64 * u] = z;
    if (lane < 16) base[lane + 256] = z;
  }
#pragma unroll
  for (int tj = 0; tj < 4; ++tj) {
    int j = 16 * tj + m;
#pragma unroll
    for (int r = 0; r < 4; ++r) {
      int i = ib + r;
      *(ushort*)A2A(i, i - j + 63) = f2h(p[tj][r]);
    }
  }

  // ---- P5: att / att_e (reads only wave-own A2 rows) ----
  f32x4 accA = (f32x4){0.f, 0.f, 0.f, 0.f};
  f32x4 accE = (f32x4){0.f, 0.f, 0.f, 0.f};
  {
    const int ia = 16 * wv + m;
#pragma unroll
    for (int ks = 0; ks < 2; ++ks) {
      U16x8 pa;
#pragma unroll
      for (int e = 0; e < 8; ++e) {
        int j = 32 * ks + 8 * h + e;
        pa.u[e] = *(ushort*)A2A(ia, ia - j + 63);
      }
      f16x8 vb = *(const f16x8*)VCA(m, 32 * ks + 8 * h);
      accA = __builtin_amdgcn_mfma_f32_16x16x32_f16(pa.v, vb, accA, 0, 0, 0);
    }
#pragma unroll
    for (int ks = 0; ks < 4; ++ks) {
      f16x8 pe = *(const f16x8*)A2A(ia, 32 * ks + 8 * h);
      f16x8 rv = *(const f16x8*)RVA(m, 32 * ks + 8 * h);
      accE = __builtin_amdgcn_mfma_f32_16x16x32_f16(pe, rv, accE, 0, 0, 0);
    }
  }

  // ---- P6: fold bn_out, pixel-major write ----
  {
    int oc = g * 16 + m;
    int c0 = 2 * oc, c1 = c0 + 1;
    float sc0 = bn_out[c0] * rsqrtf(bn_out[1536 + c0] + EPS_F);
    float sh0 = bn_out[512 + c0] - bn_out[1024 + c0] * sc0;
    float sc1 = bn_out[c1] * rsqrtf(bn_out[1536 + c1] + EPS_F);
    float sh1 = bn_out[512 + c1] - bn_out[1024 + c1] * sc1;
    float vv[4];
    vv[0] = accA[0] * sc0 + accE[0] * sc1 + sh0 + sh1;
    vv[1] = accA[1] * sc0 + accE[1] * sc1 + sh0 + sh1;
    vv[2] = accA[2] * sc0 + accE[2] * sc1 + sh0 + sh1;
    vv[3] = accA[3] * sc0 + accE[3] * sc1 + sh0 + sh1;
    size_t base = ((size_t)b * 4096 + (size_t)d1 * 64 + ib) * 256 + oc;
#pragma unroll
    for (int r = 0; r < 4; ++r)
      out16[base + (size_t)r * 256] = f2h(vv[r]);
  }
#undef RQA
#undef RKA
#undef QKA
#undef QEA
#undef KEA
#undef VCA
#undef RVA
#undef A2A
}

extern "C" void kernel_launch(void* const* d_in, const int* in_sizes, int n_in,
                              void* d_out, int out_size, void* d_ws, size_t ws_size,
                              hipStream_t stream) {
  const float* x         = (const float*)d_in[0];
  const float* latent    = (const float*)d_in[1];
  const float* w_in      = (const float*)d_in[2];
  const float* bn_in     = (const float*)d_in[3];
  const float* lin_in    = (const float*)d_in[4];
  const float* alpha_in  = (const float*)d_in[5];
  const float* a0_wqkv   = (const float*)d_in[6];
  const float* a0_bn_qkv = (const float*)d_in[7];
  const float* a0_bn_sim = (const float*)d_in[8];
  const float* a0_bn_out = (const float*)d_in[9];
  const float* a0_rel    = (const float*)d_in[10];
  const float* a1_wqkv   = (const float*)d_in[11];
  const float* a1_bn_qkv = (const float*)d_in[12];
  const float* a1_bn_sim = (const float*)d_in[13];
  const float* a1_bn_out = (const float*)d_in[14];
  const float* a1_rel    = (const float*)d_in[15];
  const float* w_out     = (const float*)d_in[16];
  const float* bn_outp   = (const float*)d_in[17];
  const float* lin_out   = (const float*)d_in[18];
  const float* w_res     = (const float*)d_in[19];
  const float* alpha_fin = (const float*)d_in[20];

  float* ws = (float*)d_ws;
  float* sb_in  = ws;                          // 2048 f
  float* sb_out = ws + 2048;                   // 2048 f
  ushort* w16   = (ushort*)(ws + 4096);        // 393216 u16
  ushort* relimg = w16 + 393216;               // 14336 u16
  ushort* x16   = relimg + 14336;              // 2097152 u16 (b,4096,128)
  ushort* t0    = x16 + 2097152;               // 4194304 u16 (b,4096,256)
  ushort* qkvb  = t0 + 4194304;                // 8388608 u16 (b,4096,512)
  ushort* pool_x = qkvb + 8388608;             // 524288 u16  (b,1024,128)

  ushort* w_in16  = w16;
  ushort* a0w16   = w16 + 32768;
  ushort* a1w16   = w16 + 163840;
  ushort* w_out16 = w16 + 294912;
  ushort* w_res16 = w16 + 360448;
  ushort* rimg_a  = relimg;
  ushort* rimg_b  = relimg + 7168;

  // prep: weights/sb/relimg + cvtT(x) + poolx(x)
  prep_kernel<<<2632, 256, 0, stream>>>(w_in, a0_wqkv, a1_wqkv, w_out, w_res,
                                        latent, lin_in, lin_out, a0_rel, a1_rel,
                                        x, w16, relimg, sb_in, sb_out, x16, pool_x);

  // conv_in + cbn + prelu -> t0 (pixel-major, p = h*64+w)
  conv_mfma_kernel<11><<<dim3(32, 4, 4), 256, 0, stream>>>(
      x16, w_in16, t0, 128, 256, 4096, bn_in, sb_in, alpha_in);

  // axial 0 over H (i=h, d1=w): out p = w*64+h
  conv_mfma_kernel<1><<<dim3(32, 8, 4), 256, 0, stream>>>(
      t0, a0w16, qkvb, 256, 512, 4096, a0_bn_qkv, nullptr, nullptr);
  axial_attn_kernel<<<4096, 256, 0, stream>>>(
      qkvb, rimg_a, a0_bn_sim, a0_bn_out, t0);

  // axial 1 over W (i=w, d1=h): out p = h*64+w (std)
  conv_mfma_kernel<1><<<dim3(32, 8, 4), 256, 0, stream>>>(
      t0, a1w16, qkvb, 256, 512, 4096, a1_bn_qkv, nullptr, nullptr);
  axial_attn_kernel<<<4096, 256, 0, stream>>>(
      qkvb, rimg_b, a1_bn_sim, a1_bn_out, t0);

  // fused: pool(t0)@W_out (cbn) + pool_x@W_res, prelu -> d_out (f32 chan-major)
  final_fused_kernel<<<dim3(8, 4, 4), 256, 0, stream>>>(
      t0, pool_x, w_out16, w_res16, (float*)d_out, bn_outp, sb_out, alpha_fin);
}

// Round 13
// 133.296 us; speedup vs baseline: 3.9696x; 1.0563x over previous
//
#include <hip/hip_runtime.h>
#include <hip/hip_bf16.h>

#define EPS_F 1e-5f

typedef __attribute__((ext_vector_type(8))) _Float16 f16x8;
typedef __attribute__((ext_vector_type(4))) _Float16 f16x4;
typedef __attribute__((ext_vector_type(4))) float f32x4;

union U16x8 { ushort u[8]; _Float16 h[8]; f16x8 v; };
union U16x4 { ushort u[4]; f16x4 v; };

static __device__ inline ushort f2h(float f) {
  _Float16 h = (_Float16)f;
  return __builtin_bit_cast(ushort, h);
}
static __device__ inline float h2f(ushort u) {
  return (float)__builtin_bit_cast(_Float16, u);
}

// ---------------- prep: weights->f16, sb, rel images, cvtT(x), poolx(x) ----------------
// grid: [0,1608) weights/sb/relimg ; [1608,2120) cvtT ; [2120,2632) poolx
__global__ void __launch_bounds__(256) prep_kernel(
    const float* __restrict__ w_in, const float* __restrict__ a0w,
    const float* __restrict__ a1w, const float* __restrict__ w_out,
    const float* __restrict__ w_res,
    const float* __restrict__ latent, const float* __restrict__ lin_in,
    const float* __restrict__ lin_out,
    const float* __restrict__ a0_rel, const float* __restrict__ a1_rel,
    const float* __restrict__ x,
    ushort* __restrict__ w16, ushort* __restrict__ relimg,
    float* __restrict__ sb_in, float* __restrict__ sb_out,
    ushort* __restrict__ x16, ushort* __restrict__ pool_x) {
  const int gid = blockIdx.x;
  const int tid = threadIdx.x;
  __shared__ __align__(16) char lsm[10240];

  if (gid < 1608) {
    int idx = gid * 256 + tid;
    if (idx < 393216) {
      const float* src; int off;
      if (idx < 32768)       { src = w_in;  off = 0; }
      else if (idx < 163840) { src = a0w;   off = 32768; }
      else if (idx < 294912) { src = a1w;   off = 163840; }
      else if (idx < 360448) { src = w_out; off = 294912; }
      else                   { src = w_res; off = 360448; }
      w16[idx] = f2h(src[idx - off]);
    } else if (idx < 397312) {
      int r = idx - 393216;
      int which = r >> 11;
      int rr = r & 2047;
      int b = rr >> 9, k = rr & 511;
      const float* lin = which ? lin_out : lin_in;
      const float* lv = latent + b * 256;
      const float* lr = lin + k * 256;
      float acc = 0.f;
#pragma unroll 8
      for (int l = 0; l < 256; ++l) acc += lv[l] * lr[l];
      (which ? sb_out : sb_in)[b * 512 + k] = acc;
    } else if (idx < 411648) {
      int e = idx - 397312;
      int which = e >= 7168;
      int s = which ? e - 7168 : e;
      const float* rel = which ? a1_rel : a0_rel;
      ushort val = 0;
      if (s < 2560) {                  // relQ image [128][20], c<8
        int d = s / 20, c = s % 20;
        if (c < 8 && d < 127) val = f2h(rel[c * 127 + d]);
      } else if (s < 5120) {           // relK image, c in 8..15
        int s2 = s - 2560;
        int d = s2 / 20, c = s2 % 20;
        if (c >= 8 && c < 16 && d < 127) val = f2h(rel[c * 127 + d]);
      } else {                         // RV swizzled image
        int pos = (s - 5120) * 2;
        int c = pos >> 8;
        int inner = (pos & 255) ^ ((c & 7) << 4);
        int d = inner >> 1;
        if (d < 127) val = f2h(rel[(16 + c) * 127 + d]);
      }
      relimg[which * 7168 + s] = val;
    }
  } else if (gid < 2120) {
    // cvtT: x f32 (b,128,4096) -> x16 (b,4096,128)
    int e = gid - 1608;
    int pt = e & 31, ct = (e >> 5) & 3, b = e >> 7;
    ushort (*Lt)[40] = (ushort(*)[40])lsm;
#pragma unroll
    for (int r = 0; r < 16; ++r) {
      int e2 = tid + 256 * r;
      int c = e2 >> 7, p = e2 & 127;
      Lt[p][c] = f2h(x[((size_t)(b * 128 + ct * 32 + c)) * 4096 + pt * 128 + p]);
    }
    __syncthreads();
#pragma unroll
    for (int r = 0; r < 2; ++r) {
      int e2 = tid + 256 * r;
      int p = e2 >> 2, q = e2 & 3;
      *(f16x8*)&x16[((size_t)b * 4096 + pt * 128 + p) * 128 + ct * 32 + 8 * q] =
          *(const f16x8*)&Lt[p][8 * q];
    }
  } else {
    // poolx: x f32 -> pool_x (b,1024,128) f16
    int e = gid - 2120;
    int ip = e & 31, ct = (e >> 5) & 3, b = e >> 7;
    float (*Lp)[33] = (float(*)[33])lsm;
    {
      int c = tid >> 3, grp = tid & 7;
      const float* base = x + ((size_t)(b * 128 + ct * 32 + c)) * 4096 + (2 * ip) * 64 + 8 * grp;
      float4 a0 = *(const float4*)&base[0];
      float4 a1 = *(const float4*)&base[4];
      float4 b0 = *(const float4*)&base[64];
      float4 b1 = *(const float4*)&base[68];
      Lp[c][4 * grp + 0] = 0.25f * (a0.x + a0.y + b0.x + b0.y);
      Lp[c][4 * grp + 1] = 0.25f * (a0.z + a0.w + b0.z + b0.w);
      Lp[c][4 * grp + 2] = 0.25f * (a1.x + a1.y + b1.x + b1.y);
      Lp[c][4 * grp + 3] = 0.25f * (a1.z + a1.w + b1.z + b1.w);
    }
    __syncthreads();
    {
      int jp = tid >> 3, q = tid & 7;
      ushort4 o;
      o.x = f2h(Lp[4 * q + 0][jp]);
      o.y = f2h(Lp[4 * q + 1][jp]);
      o.z = f2h(Lp[4 * q + 2][jp]);
      o.w = f2h(Lp[4 * q + 3][jp]);
      *(ushort4*)&pool_x[((size_t)b * 1024 + ip * 32 + jp) * 128 + ct * 32 + 4 * q] = o;
    }
  }
}

// ---------------- MFMA f16 conv1x1, pixel-major (conv_in only) ----------------
// MODE bits: 1 = bn affine, 2 = cbn, 8 = prelu
template <int MODE>
__global__ void __launch_bounds__(256) conv_mfma_kernel(
    const ushort* __restrict__ X, const ushort* __restrict__ W16,
    ushort* __restrict__ Y16, int Cin, int Cout, int P,
    const float* __restrict__ bn, const float* __restrict__ sb,
    const float* __restrict__ alpha) {
  const int tid = threadIdx.x;
  const int p0 = blockIdx.x * 128;
  const int o0 = blockIdx.y * 64;
  const int b  = blockIdx.z;
  const int lane = tid & 63;
  const int wv = tid >> 6;
  const int m = lane & 15, h = lane >> 4;
  const int wr = wv >> 1, wc = wv & 1;

  __shared__ __align__(16) char smem[27648];
  ushort (*Xs)[72] = (ushort(*)[72])smem;
  ushort (*Ws)[72] = (ushort(*)[72])(smem + 18432);
  ushort (*Es)[72] = (ushort(*)[72])smem;

  f32x4 acc[2][4];
#pragma unroll
  for (int i = 0; i < 2; ++i)
#pragma unroll
    for (int j = 0; j < 4; ++j) acc[i][j] = (f32x4){0.f, 0.f, 0.f, 0.f};

  const ushort* Xb = X + (size_t)b * P * Cin;

  for (int k0 = 0; k0 < Cin; k0 += 64) {
    __syncthreads();
#pragma unroll
    for (int r = 0; r < 4; ++r) {
      int e = tid + 256 * r;
      int pp = e >> 3, ch = e & 7;
      *(f16x8*)&Xs[pp][8 * ch] =
          *(const f16x8*)&Xb[(size_t)(p0 + pp) * Cin + k0 + 8 * ch];
    }
#pragma unroll
    for (int r = 0; r < 2; ++r) {
      int e = tid + 256 * r;
      int oc = e >> 3, ch = e & 7;
      *(f16x8*)&Ws[oc][8 * ch] =
          *(const f16x8*)&W16[(size_t)(o0 + oc) * Cin + k0 + 8 * ch];
    }
    __syncthreads();
#pragma unroll
    for (int ks = 0; ks < 2; ++ks) {
      f16x8 af[2], bf[4];
#pragma unroll
      for (int t = 0; t < 2; ++t) af[t] = *(const f16x8*)&Ws[32 * wr + 16 * t + m][32 * ks + 8 * h];
#pragma unroll
      for (int t = 0; t < 4; ++t) bf[t] = *(const f16x8*)&Xs[64 * wc + 16 * t + m][32 * ks + 8 * h];
#pragma unroll
      for (int ta = 0; ta < 2; ++ta)
#pragma unroll
        for (int tb = 0; tb < 4; ++tb)
          acc[ta][tb] = __builtin_amdgcn_mfma_f32_16x16x32_f16(af[ta], bf[tb], acc[ta][tb], 0, 0, 0);
    }
  }

  float scl[2][4], shf[2][4];
#pragma unroll
  for (int ta = 0; ta < 2; ++ta)
#pragma unroll
    for (int r = 0; r < 4; ++r) {
      int oc = o0 + 32 * wr + 16 * ta + 4 * h + r;
      float scale = 1.f, shift = 0.f;
      if (MODE & 1) {
        float sc = bn[oc] * rsqrtf(bn[3 * Cout + oc] + EPS_F);
        scale = sc;
        shift = bn[Cout + oc] - bn[2 * Cout + oc] * sc;
      }
      if (MODE & 2) {
        float ss = sb[b * 2 * Cout + oc];
        float bb = sb[b * 2 * Cout + Cout + oc];
        scale *= ss;
        shift = shift * ss + bb;
      }
      scl[ta][r] = scale; shf[ta][r] = shift;
    }
  float al = (MODE & 8) ? *alpha : 0.f;

  __syncthreads();
#pragma unroll
  for (int ta = 0; ta < 2; ++ta)
#pragma unroll
    for (int tb = 0; tb < 4; ++tb)
#pragma unroll
      for (int r = 0; r < 4; ++r) {
        float v = acc[ta][tb][r] * scl[ta][r] + shf[ta][r];
        if (MODE & 8) v = v > 0.f ? v : al * v;
        Es[64 * wc + 16 * tb + m][32 * wr + 16 * ta + 4 * h + r] = f2h(v);
      }
  __syncthreads();
#pragma unroll
  for (int r = 0; r < 4; ++r) {
    int e = tid + 256 * r;
    int pp = e >> 3, q = e & 7;
    *(f16x8*)&Y16[((size_t)b * P + p0 + pp) * Cout + o0 + 8 * q] =
        *(const f16x8*)&Es[pp][8 * q];
  }
}

// ---------------- fused final: pool(t0)·W_out (cbn) + pool_x·W_res, prelu, f32 out ----------------
__global__ void __launch_bounds__(256) final_fused_kernel(
    const ushort* __restrict__ t0, const ushort* __restrict__ pool_x,
    const ushort* __restrict__ Wo, const ushort* __restrict__ Wr,
    float* __restrict__ Y32,
    const float* __restrict__ bn, const float* __restrict__ sb,
    const float* __restrict__ alpha) {
  const int tid = threadIdx.x;
  const int p0 = blockIdx.x * 128;
  const int o0 = blockIdx.y * 64;
  const int b  = blockIdx.z;
  const int lane = tid & 63;
  const int wv = tid >> 6;
  const int m = lane & 15, h = lane >> 4;
  const int wr = wv >> 1, wc = wv & 1;

  __shared__ __align__(16) char smem[27648];
  ushort (*Xs)[72] = (ushort(*)[72])smem;
  ushort (*Ws)[72] = (ushort(*)[72])(smem + 18432);

  f32x4 acc1[2][4], acc2[2][4];
#pragma unroll
  for (int i = 0; i < 2; ++i)
#pragma unroll
    for (int j = 0; j < 4; ++j) {
      acc1[i][j] = (f32x4){0.f, 0.f, 0.f, 0.f};
      acc2[i][j] = (f32x4){0.f, 0.f, 0.f, 0.f};
    }

  // phase A: pooled t0 (Cin=256) @ W_out -> acc1
  for (int k0 = 0; k0 < 256; k0 += 64) {
    __syncthreads();
#pragma unroll
    for (int r = 0; r < 4; ++r) {
      int e = tid + 256 * r;
      int pp = e >> 3, ch = e & 7;
      int pg = p0 + pp;
      int ip = pg >> 5, jp = pg & 31;
      size_t tb = ((size_t)b * 4096 + ip * 128 + jp * 2) * 256 + k0 + 8 * ch;
      U16x8 a, bb, c, d, o;
      a.v  = *(const f16x8*)&t0[tb];
      bb.v = *(const f16x8*)&t0[tb + 256];
      c.v  = *(const f16x8*)&t0[tb + 64 * 256];
      d.v  = *(const f16x8*)&t0[tb + 65 * 256];
#pragma unroll
      for (int e2 = 0; e2 < 8; ++e2)
        o.h[e2] = ((a.h[e2] + bb.h[e2]) + (c.h[e2] + d.h[e2])) * (_Float16)0.25f;
      *(f16x8*)&Xs[pp][8 * ch] = o.v;
    }
#pragma unroll
    for (int r = 0; r < 2; ++r) {
      int e = tid + 256 * r;
      int oc = e >> 3, ch = e & 7;
      *(f16x8*)&Ws[oc][8 * ch] = *(const f16x8*)&Wo[(size_t)(o0 + oc) * 256 + k0 + 8 * ch];
    }
    __syncthreads();
#pragma unroll
    for (int ks = 0; ks < 2; ++ks) {
      f16x8 af[2], bf[4];
#pragma unroll
      for (int t = 0; t < 2; ++t) af[t] = *(const f16x8*)&Ws[32 * wr + 16 * t + m][32 * ks + 8 * h];
#pragma unroll
      for (int t = 0; t < 4; ++t) bf[t] = *(const f16x8*)&Xs[64 * wc + 16 * t + m][32 * ks + 8 * h];
#pragma unroll
      for (int ta = 0; ta < 2; ++ta)
#pragma unroll
        for (int tb2 = 0; tb2 < 4; ++tb2)
          acc1[ta][tb2] = __builtin_amdgcn_mfma_f32_16x16x32_f16(af[ta], bf[tb2], acc1[ta][tb2], 0, 0, 0);
    }
  }

  // phase B: pool_x (Cin=128) @ W_res -> acc2
  for (int k0 = 0; k0 < 128; k0 += 64) {
    __syncthreads();
#pragma unroll
    for (int r = 0; r < 4; ++r) {
      int e = tid + 256 * r;
      int pp = e >> 3, ch = e & 7;
      *(f16x8*)&Xs[pp][8 * ch] =
          *(const f16x8*)&pool_x[((size_t)b * 1024 + p0 + pp) * 128 + k0 + 8 * ch];
    }
#pragma unroll
    for (int r = 0; r < 2; ++r) {
      int e = tid + 256 * r;
      int oc = e >> 3, ch = e & 7;
      *(f16x8*)&Ws[oc][8 * ch] = *(const f16x8*)&Wr[(size_t)(o0 + oc) * 128 + k0 + 8 * ch];
    }
    __syncthreads();
#pragma unroll
    for (int ks = 0; ks < 2; ++ks) {
      f16x8 af[2], bf[4];
#pragma unroll
      for (int t = 0; t < 2; ++t) af[t] = *(const f16x8*)&Ws[32 * wr + 16 * t + m][32 * ks + 8 * h];
#pragma unroll
      for (int t = 0; t < 4; ++t) bf[t] = *(const f16x8*)&Xs[64 * wc + 16 * t + m][32 * ks + 8 * h];
#pragma unroll
      for (int ta = 0; ta < 2; ++ta)
#pragma unroll
        for (int tb2 = 0; tb2 < 4; ++tb2)
          acc2[ta][tb2] = __builtin_amdgcn_mfma_f32_16x16x32_f16(af[ta], bf[tb2], acc2[ta][tb2], 0, 0, 0);
    }
  }

  const float al = *alpha;
#pragma unroll
  for (int ta = 0; ta < 2; ++ta)
#pragma unroll
    for (int r = 0; r < 4; ++r) {
      int oc = o0 + 32 * wr + 16 * ta + 4 * h + r;
      float sc = bn[oc] * rsqrtf(bn[768 + oc] + EPS_F);
      float shift = bn[256 + oc] - bn[512 + oc] * sc;
      float ss = sb[b * 512 + oc];
      float bb = sb[b * 512 + 256 + oc];
      float scale = sc * ss;
      shift = shift * ss + bb;
#pragma unroll
      for (int tb2 = 0; tb2 < 4; ++tb2) {
        int p = p0 + 64 * wc + 16 * tb2 + m;
        float v = acc1[ta][tb2][r] * scale + shift + acc2[ta][tb2][r];
        v = v > 0.f ? v : al * v;
        Y32[((size_t)b * 256 + oc) * 1024 + p] = v;
      }
    }
}

// ---------------- axial attention + FUSED qkv conv, all-MFMA f16 ----------------
// Input tin (b, p, 256) with p = i*64 + d1 (i = attended dim).
// Output tout (b, p', 256) with p' = d1*64 + i.  tin != tout (ping-pong).
__global__ void __launch_bounds__(256) axial_attn_kernel(
    const ushort* __restrict__ t0in, const ushort* __restrict__ wqkv,
    const float* __restrict__ bn_qkv,
    const ushort* __restrict__ relimg,
    const float* __restrict__ bn_sim, const float* __restrict__ bn_out,
    ushort* __restrict__ out16) {
  const int tid = threadIdx.x;
  int lin = blockIdx.x;                       // bijective XCD swizzle, bd-major chunks
  int wg = ((lin & 7) << 9) + (lin >> 3);
  const int g  = wg & 15;
  const int bd = wg >> 4;
  const int b  = bd >> 6;
  const int d1 = bd & 63;

  __shared__ __align__(16) char smem[37888];
  // relQ [128][20] @0 | relK @5120 | QK [64][24] @10240
  // QE [64][72] @13312 (= conv Xs staging) | KE @22528 | VC swz @31744
  // RV swz @33792 | A2 [64][136] @0 overlay
#define RQA(d, c)  (smem + (d) * 40 + (c) * 2)
#define RKA(d, c)  (smem + 5120 + (d) * 40 + (c) * 2)
#define QKA(i, c)  (smem + 10240 + (i) * 48 + (c) * 2)
#define XSA(i, k)  (smem + 13312 + (i) * 144 + (k) * 2)
#define QEA(i, k)  (smem + 13312 + (i) * 144 + (k) * 2)
#define KEA(j, k)  (smem + 22528 + (j) * 144 + (k) * 2)
#define VCA(c, j)  (smem + 31744 + ((((c) * 128 + (j) * 2)) ^ (((c) & 7) << 4)))
#define RVA(c, d)  (smem + 33792 + ((((c) * 256 + (d) * 2)) ^ (((c) & 7) << 4)))
#define A2A(i, d)  (smem + (i) * 272 + (d) * 2)

  const int lane = tid & 63;
  const int wv   = tid >> 6;
  const int m    = lane & 15;
  const int h    = lane >> 4;
  const int wr   = wv >> 1, wc = wv & 1;

  // ---- P0: copy rel images (disjoint from conv staging regions) ----
  {
    const uint4* img = (const uint4*)relimg;
    for (int u = tid; u < 640; u += 256) ((uint4*)smem)[u] = img[u];   // relQ+relK
    ((uint4*)(smem + 33792))[tid] = img[640 + tid];                    // RV
  }

  // ---- C0: fused qkv conv: ch g*32..g*32+32 at pixels p=i*64+d1 ----
  f32x4 cacc[2];
  cacc[0] = (f32x4){0.f, 0.f, 0.f, 0.f};
  cacc[1] = (f32x4){0.f, 0.f, 0.f, 0.f};
  {
    const ushort* Xb = t0in + ((size_t)b * 4096 + d1) * 256;
    const ushort* Wg = wqkv + ((size_t)(g * 32 + 16 * wr + m)) * 256;
    for (int k0 = 0; k0 < 256; k0 += 64) {
      __syncthreads();
#pragma unroll
      for (int r = 0; r < 2; ++r) {
        int e = tid + 256 * r;
        int i = e >> 3, sub = e & 7;
        *(f16x8*)XSA(i, 8 * sub) = *(const f16x8*)&Xb[(size_t)i * 16384 + k0 + 8 * sub];
      }
      __syncthreads();
#pragma unroll
      for (int ks = 0; ks < 2; ++ks) {
        f16x8 af = *(const f16x8*)&Wg[k0 + 32 * ks + 8 * h];
#pragma unroll
        for (int tb = 0; tb < 2; ++tb) {
          f16x8 bf = *(const f16x8*)XSA(32 * wc + 16 * tb + m, 32 * ks + 8 * h);
          cacc[tb] = __builtin_amdgcn_mfma_f32_16x16x32_f16(af, bf, cacc[tb], 0, 0, 0);
        }
      }
    }
  }
  // C1: epilogue — fold bn_qkv, write QK (wr=0: c=4h+r) / VC (wr=1: c-16=4h+r)
  {
    float scl[4], shf[4];
#pragma unroll
    for (int r = 0; r < 4; ++r) {
      int ch = g * 32 + 16 * wr + 4 * h + r;
      float sc = bn_qkv[ch] * rsqrtf(bn_qkv[1536 + ch] + EPS_F);
      scl[r] = sc;
      shf[r] = bn_qkv[512 + ch] - bn_qkv[1024 + ch] * sc;
    }
    if (wr == 0) {
#pragma unroll
      for (int tb = 0; tb < 2; ++tb) {
        int i = 32 * wc + 16 * tb + m;
        U16x4 o;
#pragma unroll
        for (int r = 0; r < 4; ++r) o.u[r] = f2h(cacc[tb][r] * scl[r] + shf[r]);
        *(f16x4*)QKA(i, 4 * h) = o.v;
      }
    } else {
#pragma unroll
      for (int tb = 0; tb < 2; ++tb) {
        int i = 32 * wc + 16 * tb + m;
#pragma unroll
        for (int r = 0; r < 4; ++r)
          *(ushort*)VCA(4 * h + r, i) = f2h(cacc[tb][r] * scl[r] + shf[r]);
      }
    }
  }
  __syncthreads();   // barrier A

  // ---- P1: band-restricted emb GEMM -> dense QE/KE ----
  {
    const int nt = wv;
    const int n = 16 * nt + m;
    f16x4 bqk = *(const f16x4*)QKA(n, 4 * h);
#pragma unroll
    for (int k = 0; k < 5; ++k) {
      int dt = nt + k;
      f16x4 arQ = *(const f16x4*)RQA(16 * dt + m, 4 * h);
      f16x4 arK = *(const f16x4*)RKA(16 * dt + m, 4 * h);
      f32x4 dq = __builtin_amdgcn_mfma_f32_16x16x16f16(arQ, bqk, (f32x4){0.f,0.f,0.f,0.f}, 0, 0, 0);
      f32x4 dk = __builtin_amdgcn_mfma_f32_16x16x16f16(arK, bqk, (f32x4){0.f,0.f,0.f,0.f}, 0, 0, 0);
#pragma unroll
      for (int r = 0; r < 4; ++r) {
        int d = 16 * dt + 4 * h + r;
        int i = n - d + 63;
        if (k == 0 || k == 4) {
          if ((unsigned)i < 64u) {
            *(ushort*)QEA(i, n) = f2h(dq[r]);
            *(ushort*)KEA(i, n) = f2h(dk[r]);
          }
        } else {
          *(ushort*)QEA(i, n) = f2h(dq[r]);
          *(ushort*)KEA(i, n) = f2h(dk[r]);
        }
      }
    }
  }
  __syncthreads();   // barrier B

  // ---- P2: sim ----
  f32x4 acc[4];
#pragma unroll
  for (int tj = 0; tj < 4; ++tj) acc[tj] = (f32x4){0.f, 0.f, 0.f, 0.f};
  {
    const int ia = 16 * wv + m;
    f16x8 af0 = *(const f16x8*)QEA(ia, 8 * h);
    f16x8 af1 = *(const f16x8*)QEA(ia, 32 + 8 * h);
#pragma unroll
    for (int tj = 0; tj < 4; ++tj) {
      int j = 16 * tj + m;
      f16x8 bf0 = *(const f16x8*)KEA(j, 8 * h);
      f16x8 bf1 = *(const f16x8*)KEA(j, 32 + 8 * h);
      acc[tj] = __builtin_amdgcn_mfma_f32_16x16x32_f16(af0, bf0, acc[tj], 0, 0, 0);
      acc[tj] = __builtin_amdgcn_mfma_f32_16x16x32_f16(af1, bf1, acc[tj], 0, 0, 0);
    }
  }

  float s_qk = bn_sim[g]      * rsqrtf(bn_sim[144 + g] + EPS_F);
  float s_qe = bn_sim[16 + g] * rsqrtf(bn_sim[160 + g] + EPS_F);
  float s_ke = bn_sim[32 + g] * rsqrtf(bn_sim[176 + g] + EPS_F);
  float sh   = (bn_sim[48 + g] - bn_sim[96 + g]  * s_qk)
             + (bn_sim[64 + g] - bn_sim[112 + g] * s_qe)
             + (bn_sim[80 + g] - bn_sim[128 + g] * s_ke);

  const int ib = 16 * wv + 4 * h;
  float sv[4][4];
#pragma unroll
  for (int tj = 0; tj < 4; ++tj) {
    int j = 16 * tj + m;
    f16x4 qe4 = *(const f16x4*)QEA(j, ib);
    f16x4 ke4 = *(const f16x4*)KEA(j, ib);
#pragma unroll
    for (int r = 0; r < 4; ++r)
      sv[tj][r] = acc[tj][r] * s_qk + (float)qe4[r] * s_qe + (float)ke4[r] * s_ke + sh;
  }

  // ---- P3: softmax over j ----
  float p[4][4];
  {
    float mx[4];
#pragma unroll
    for (int r = 0; r < 4; ++r) {
      float v = fmaxf(fmaxf(sv[0][r], sv[1][r]), fmaxf(sv[2][r], sv[3][r]));
      v = fmaxf(v, __shfl_xor(v, 1));
      v = fmaxf(v, __shfl_xor(v, 2));
      v = fmaxf(v, __shfl_xor(v, 4));
      v = fmaxf(v, __shfl_xor(v, 8));
      mx[r] = v;
    }
#pragma unroll
    for (int r = 0; r < 4; ++r) {
      float ssum = 0.f;
#pragma unroll
      for (int tj = 0; tj < 4; ++tj) {
        p[tj][r] = __expf(sv[tj][r] - mx[r]);
        ssum += p[tj][r];
      }
      ssum += __shfl_xor(ssum, 1);
      ssum += __shfl_xor(ssum, 2);
      ssum += __shfl_xor(ssum, 4);
      ssum += __shfl_xor(ssum, 8);
      float inv = 1.f / ssum;
#pragma unroll
      for (int tj = 0; tj < 4; ++tj) p[tj][r] *= inv;
    }
  }

  __syncthreads();   // barrier C

  // ---- P4: wave-private zero of A2 rows [16wv,16wv+16), then scatter ----
  {
    uint4 z = make_uint4(0u, 0u, 0u, 0u);
    uint4* base = (uint4*)(smem + wv * 4352);
#pragma unroll
    for (int u = 0; u < 4; ++u) base[lane + 64 * u] = z;
    if (lane < 16) base[lane + 256] = z;
  }
#pragma unroll
  for (int tj = 0; tj < 4; ++tj) {
    int j = 16 * tj + m;
#pragma unroll
    for (int r = 0; r < 4; ++r) {
      int i = ib + r;
      *(ushort*)A2A(i, i - j + 63) = f2h(p[tj][r]);
    }
  }

  // ---- P5: att / att_e ----
  f32x4 accA = (f32x4){0.f, 0.f, 0.f, 0.f};
  f32x4 accE = (f32x4){0.f, 0.f, 0.f, 0.f};
  {
    const int ia = 16 * wv + m;
#pragma unroll
    for (int ks = 0; ks < 2; ++ks) {
      U16x8 pa;
#pragma unroll
      for (int e = 0; e < 8; ++e) {
        int j = 32 * ks + 8 * h + e;
        pa.u[e] = *(ushort*)A2A(ia, ia - j + 63);
      }
      f16x8 vb = *(const f16x8*)VCA(m, 32 * ks + 8 * h);
      accA = __builtin_amdgcn_mfma_f32_16x16x32_f16(pa.v, vb, accA, 0, 0, 0);
    }
#pragma unroll
    for (int ks = 0; ks < 4; ++ks) {
      f16x8 pe = *(const f16x8*)A2A(ia, 32 * ks + 8 * h);
      f16x8 rv = *(const f16x8*)RVA(m, 32 * ks + 8 * h);
      accE = __builtin_amdgcn_mfma_f32_16x16x32_f16(pe, rv, accE, 0, 0, 0);
    }
  }

  // ---- P6: fold bn_out, pixel-major write ----
  {
    int oc = g * 16 + m;
    int c0 = 2 * oc, c1 = c0 + 1;
    float sc0 = bn_out[c0] * rsqrtf(bn_out[1536 + c0] + EPS_F);
    float sh0 = bn_out[512 + c0] - bn_out[1024 + c0] * sc0;
    float sc1 = bn_out[c1] * rsqrtf(bn_out[1536 + c1] + EPS_F);
    float sh1 = bn_out[512 + c1] - bn_out[1024 + c1] * sc1;
    float vv[4];
    vv[0] = accA[0] * sc0 + accE[0] * sc1 + sh0 + sh1;
    vv[1] = accA[1] * sc0 + accE[1] * sc1 + sh0 + sh1;
    vv[2] = accA[2] * sc0 + accE[2] * sc1 + sh0 + sh1;
    vv[3] = accA[3] * sc0 + accE[3] * sc1 + sh0 + sh1;
    size_t base = ((size_t)b * 4096 + (size_t)d1 * 64 + ib) * 256 + oc;
#pragma unroll
    for (int r = 0; r < 4; ++r)
      out16[base + (size_t)r * 256] = f2h(vv[r]);
  }
#undef RQA
#undef RKA
#undef QKA
#undef XSA
#undef QEA
#undef KEA
#undef VCA
#undef RVA
#undef A2A
}

extern "C" void kernel_launch(void* const* d_in, const int* in_sizes, int n_in,
                              void* d_out, int out_size, void* d_ws, size_t ws_size,
                              hipStream_t stream) {
  const float* x         = (const float*)d_in[0];
  const float* latent    = (const float*)d_in[1];
  const float* w_in      = (const float*)d_in[2];
  const float* bn_in     = (const float*)d_in[3];
  const float* lin_in    = (const float*)d_in[4];
  const float* alpha_in  = (const float*)d_in[5];
  const float* a0_wqkv   = (const float*)d_in[6];
  const float* a0_bn_qkv = (const float*)d_in[7];
  const float* a0_bn_sim = (const float*)d_in[8];
  const float* a0_bn_out = (const float*)d_in[9];
  const float* a0_rel    = (const float*)d_in[10];
  const float* a1_wqkv   = (const float*)d_in[11];
  const float* a1_bn_qkv = (const float*)d_in[12];
  const float* a1_bn_sim = (const float*)d_in[13];
  const float* a1_bn_out = (const float*)d_in[14];
  const float* a1_rel    = (const float*)d_in[15];
  const float* w_out     = (const float*)d_in[16];
  const float* bn_outp   = (const float*)d_in[17];
  const float* lin_out   = (const float*)d_in[18];
  const float* w_res     = (const float*)d_in[19];
  const float* alpha_fin = (const float*)d_in[20];

  float* ws = (float*)d_ws;
  float* sb_in  = ws;                          // 2048 f
  float* sb_out = ws + 2048;                   // 2048 f
  ushort* w16   = (ushort*)(ws + 4096);        // 393216 u16
  ushort* relimg = w16 + 393216;               // 14336 u16
  ushort* x16   = relimg + 14336;              // 2097152 u16 (b,4096,128)
  ushort* t0    = x16 + 2097152;               // 4194304 u16 (b,4096,256)
  ushort* t1    = t0 + 4194304;                // 4194304 u16 (b,4096,256) ping-pong
  ushort* pool_x = t1 + 4194304;               // 524288 u16  (b,1024,128)

  ushort* w_in16  = w16;
  ushort* a0w16   = w16 + 32768;
  ushort* a1w16   = w16 + 163840;
  ushort* w_out16 = w16 + 294912;
  ushort* w_res16 = w16 + 360448;
  ushort* rimg_a  = relimg;
  ushort* rimg_b  = relimg + 7168;

  // prep: weights/sb/relimg + cvtT(x) + poolx(x)
  prep_kernel<<<2632, 256, 0, stream>>>(w_in, a0_wqkv, a1_wqkv, w_out, w_res,
                                        latent, lin_in, lin_out, a0_rel, a1_rel,
                                        x, w16, relimg, sb_in, sb_out, x16, pool_x);

  // conv_in + cbn + prelu -> t0 (pixel-major, p = h*64+w)
  conv_mfma_kernel<11><<<dim3(32, 4, 4), 256, 0, stream>>>(
      x16, w_in16, t0, 128, 256, 4096, bn_in, sb_in, alpha_in);

  // axial 0 over H (i=h, d1=w), fused qkv conv: t0 -> t1 (out p = w*64+h)
  axial_attn_kernel<<<4096, 256, 0, stream>>>(
      t0, a0w16, a0_bn_qkv, rimg_a, a0_bn_sim, a0_bn_out, t1);

  // axial 1 over W (i=w, d1=h), fused qkv conv: t1 -> t0 (out p = h*64+w, std)
  axial_attn_kernel<<<4096, 256, 0, stream>>>(
      t1, a1w16, a1_bn_qkv, rimg_b, a1_bn_sim, a1_bn_out, t0);

  // fused: pool(t0)@W_out (cbn) + pool_x@W_res, prelu -> d_out (f32 chan-major)
  final_fused_kernel<<<dim3(8, 4, 4), 256, 0, stream>>>(
      t0, pool_x, w_out16, w_res16, (float*)d_out, bn_outp, sb_out, alpha_fin);
}